// Round 2
// baseline (2324.279 us; speedup 1.0000x reference)
//
#include <hip/hip_runtime.h>

__constant__ float c_anchors[10] = {2.f,4.f,5.f,6.f,8.f,9.f,10.f,12.f,14.f,16.f};

// ---------------- generic k=3 pad=1 conv over length 768 ----------------
// in: fp32 [CI][768], w: fp32 [CO][CI][3]
// partial out: fp32 [S][CO][768]
// grid: (CO/128, 768/64, S), block 256
__global__ __launch_bounds__(256) void conv3_kernel(const float* __restrict__ in,
                                                    const float* __restrict__ w,
                                                    float* __restrict__ part,
                                                    int CI, int CO, int S) {
    __shared__ __align__(16) float inT[8][68];
    __shared__ __align__(16) float wT[8][3][128];
    int tid = threadIdx.x;
    int tx = tid & 15;   // l group
    int ty = tid >> 4;   // co group 0..15
    int co0 = blockIdx.x * 128;
    int l0 = blockIdx.y * 64;
    int s = blockIdx.z;
    int ciPer = CI / S;
    int ciStart = s * ciPer;

    float acc[8][4];
#pragma unroll
    for (int i = 0; i < 8; i++)
#pragma unroll
        for (int j = 0; j < 4; j++) acc[i][j] = 0.f;

    for (int cb = 0; cb < ciPer; cb += 8) {
        int cib = ciStart + cb;
        // stage input: rows cib..cib+7, cols l0-1 .. l0+64 (66 values)
        for (int idx = tid; idx < 528; idx += 256) {
            int r = idx / 66, c = idx - (idx / 66) * 66;
            int gl = l0 - 1 + c;
            float v = 0.f;
            if ((unsigned)gl < 768u) v = in[(size_t)(cib + r) * 768 + gl];
            inT[r][c] = v;
        }
        // stage weights: wT[ci][t][co]; 2 threads per co row, 12 floats each
        {
            int cop = tid >> 1;      // 0..127
            int q = tid & 1;
            const float* wp = w + ((size_t)(co0 + cop) * CI + cib) * 3 + q * 12;
#pragma unroll
            for (int u = 0; u < 12; u++) {
                int e = q * 12 + u;
                wT[e / 3][e % 3][cop] = wp[u];
            }
        }
        __syncthreads();
#pragma unroll
        for (int ci = 0; ci < 8; ci++) {
            float4 a = *(const float4*)&inT[ci][tx * 4];
            float2 b2 = *(const float2*)&inT[ci][tx * 4 + 4];
            float v[6] = {a.x, a.y, a.z, a.w, b2.x, b2.y};
#pragma unroll
            for (int t = 0; t < 3; t++) {
                float4 w0 = *(const float4*)&wT[ci][t][ty * 8];
                float4 w1 = *(const float4*)&wT[ci][t][ty * 8 + 4];
                float wv[8] = {w0.x, w0.y, w0.z, w0.w, w1.x, w1.y, w1.z, w1.w};
#pragma unroll
                for (int i = 0; i < 8; i++)
#pragma unroll
                    for (int j = 0; j < 4; j++)
                        acc[i][j] = fmaf(wv[i], v[j + t], acc[i][j]);
            }
        }
        __syncthreads();
    }
#pragma unroll
    for (int i = 0; i < 8; i++) {
        int co = co0 + ty * 8 + i;
        float4 o = {acc[i][0], acc[i][1], acc[i][2], acc[i][3]};
        *(float4*)&part[((size_t)s * CO + co) * 768 + l0 + tx * 4] = o;
    }
}

// ---------------- finalize: sum splits + bias (+relu) ----------------
__global__ __launch_bounds__(256) void finalize_kernel(const float* __restrict__ part,
                                                       float* __restrict__ out,
                                                       const float* __restrict__ bias,
                                                       int RPAD, int R, int NCOLS, int S, int relu) {
    int i = blockIdx.x * 256 + threadIdx.x;
    int total = R * NCOLS;
    if (i >= total) return;
    int r = i / NCOLS;
    int c = i - r * NCOLS;
    float v = 0.f;
    for (int s = 0; s < S; s++) v += part[((size_t)s * RPAD + r) * NCOLS + c];
    v += bias[r];
    if (relu) v = fmaxf(v, 0.f);
    out[i] = v;
}

// ---------------- gather-GEMM: C[r][col] = sum_k W[r][k] * B(k,col) ----------------
// MODE 0: B(k,col) = B[k*LDB + col]
// MODE 1: (len-7 conv gather, pad 1) k=ci*3+t: l=col%7+t-1; in-range? B[ci*896 + col + t-1] : 0
// MODE 2: (fc1 reshape) k=co*7+b: B[co*896 + col*7 + b]
// EPI 0: fp32 (S==1: bias+relu store; S>1: raw partial [s][R][NCOLS])
// EPI 1: obj_cls head -> out[512 + col*21 + r]
// EPI 2: obj_off head -> out[3200 + col*40 + r]
template <int MODE, int EPI>
__global__ __launch_bounds__(256) void gemm_kernel(const float* __restrict__ W,
                                                   const float* __restrict__ B,
                                                   const float* __restrict__ bias,
                                                   float* __restrict__ outF,
                                                   int R, int K, int NCOLS, int LDB, int S, int relu) {
    __shared__ __align__(16) float Bt[16][68];
    __shared__ __align__(16) float Wt[16][68];
    int tid = threadIdx.x;
    int tx = tid & 15, ty = tid >> 4;
    int r0 = blockIdx.x * 64, c0 = blockIdx.y * 64, s = blockIdx.z;
    int kPer = K / S;
    int k0s = s * kPer;
    float acc[4][4] = {};
    for (int kb = 0; kb < kPer; kb += 16) {
        int k0 = k0s + kb;
        // stage W: 4 threads per row, float4 each
        {
            int rr = r0 + (tid >> 2);
            int q = tid & 3;
            float4 wv4 = {0.f, 0.f, 0.f, 0.f};
            if (rr < R) wv4 = *(const float4*)(W + (size_t)rr * K + k0 + q * 4);
            Wt[q * 4 + 0][tid >> 2] = wv4.x;
            Wt[q * 4 + 1][tid >> 2] = wv4.y;
            Wt[q * 4 + 2][tid >> 2] = wv4.z;
            Wt[q * 4 + 3][tid >> 2] = wv4.w;
        }
        // stage B
#pragma unroll
        for (int p = 0; p < 4; p++) {
            int kk = p * 4 + (tid >> 6);
            int c = tid & 63;
            int k = k0 + kk;
            int col = c0 + c;
            float v;
            if (MODE == 0) {
                v = B[(size_t)k * LDB + col];
            } else if (MODE == 1) {
                int ci = k / 3;
                int t = k - ci * 3;
                int lc = (col % 7) + t - 1;
                v = ((unsigned)lc < 7u) ? B[(size_t)ci * 896 + col + t - 1] : 0.f;
            } else {
                int co = k / 7;
                int b7 = k - co * 7;
                v = B[(size_t)co * 896 + col * 7 + b7];
            }
            Bt[kk][c] = v;
        }
        __syncthreads();
#pragma unroll
        for (int kk = 0; kk < 16; kk++) {
            float4 bv = *(const float4*)&Bt[kk][tx * 4];
            float4 wv = *(const float4*)&Wt[kk][ty * 4];
            float bb[4] = {bv.x, bv.y, bv.z, bv.w};
            float ww[4] = {wv.x, wv.y, wv.z, wv.w};
#pragma unroll
            for (int i = 0; i < 4; i++)
#pragma unroll
                for (int j = 0; j < 4; j++)
                    acc[i][j] = fmaf(ww[i], bb[j], acc[i][j]);
        }
        __syncthreads();
    }
    if (EPI == 0) {
        if (S > 1) {
#pragma unroll
            for (int i = 0; i < 4; i++) {
                int r = r0 + ty * 4 + i;
                float4 o = {acc[i][0], acc[i][1], acc[i][2], acc[i][3]};
                *(float4*)&outF[((size_t)s * R + r) * NCOLS + c0 + tx * 4] = o;
            }
        } else {
#pragma unroll
            for (int i = 0; i < 4; i++) {
                int r = r0 + ty * 4 + i;
                if (r < R) {
                    float bv = bias[r];
#pragma unroll
                    for (int j = 0; j < 4; j++) {
                        float v = acc[i][j] + bv;
                        if (relu) v = fmaxf(v, 0.f);
                        outF[(size_t)r * NCOLS + c0 + tx * 4 + j] = v;
                    }
                }
            }
        }
    } else {
#pragma unroll
        for (int i = 0; i < 4; i++) {
            int r = r0 + ty * 4 + i;
            if (r < R) {
                float bv = bias[r];
#pragma unroll
                for (int j = 0; j < 4; j++) {
                    int col = c0 + tx * 4 + j;
                    float v = acc[i][j] + bv;
                    if (EPI == 1) outF[512 + col * 21 + r] = v;
                    else outF[3200 + col * 40 + r] = v;
                }
            }
        }
    }
}

// ---------------- proposals: softmax, anchor decode ----------------
__global__ __launch_bounds__(256) void proposal_kernel(const float* __restrict__ clsS,
                                                       const float* __restrict__ segS,
                                                       float* __restrict__ cls2, float* __restrict__ off2,
                                                       float* __restrict__ scores,
                                                       float* __restrict__ sArr, float* __restrict__ eArr) {
    int i = blockIdx.x * 256 + threadIdx.x;
    if (i >= 7680) return;
    int l = i / 10;
    int a = i - l * 10;
    float c0 = clsS[(a * 2 + 0) * 768 + l];
    float c1 = clsS[(a * 2 + 1) * 768 + l];
    cls2[i * 2] = c0;
    cls2[i * 2 + 1] = c1;
    float m = fmaxf(c0, c1);
    float e0 = expf(c0 - m), e1 = expf(c1 - m);
    scores[i] = e1 / (e0 + e1);
    float o0 = segS[(a * 2 + 0) * 768 + l];
    float o1 = segS[(a * 2 + 1) * 768 + l];
    off2[i * 2] = o0;
    off2[i * 2 + 1] = o1;
    float ah = c_anchors[a] * 0.5f;
    float ac = (float)l + 0.5f;
    float c = ac + o0 * (2.f * ah);
    float hl = ah * expf(o1);
    sArr[i] = fminf(fmaxf(c - hl, 0.f), 768.f);
    eArr[i] = fminf(fmaxf(c + hl, 0.f), 768.f);
}

// ---------------- full bitonic sort of 8192 keys, keep top 1024 ----------------
__global__ __launch_bounds__(1024) void sort_kernel(const float* __restrict__ scores,
                                                    const float* __restrict__ sArr, const float* __restrict__ eArr,
                                                    int* __restrict__ topI,
                                                    float* __restrict__ ss, float* __restrict__ ee) {
    __shared__ unsigned long long kk[8192];
    int tid = threadIdx.x;
#pragma unroll
    for (int m = 0; m < 8; m++) {
        int i = tid + m * 1024;
        unsigned long long key = 0ull;
        if (i < 7680) {
            unsigned int sb = __float_as_uint(scores[i]);
            key = ((unsigned long long)sb << 32) | (unsigned long long)(0xFFFFFFFFu - (unsigned)i);
        }
        kk[i] = key;
    }
    __syncthreads();
    for (int k = 2; k <= 8192; k <<= 1) {
        for (int j = k >> 1; j > 0; j >>= 1) {
#pragma unroll 1
            for (int m = 0; m < 8; m++) {
                int i = tid + m * 1024;
                int ixj = i ^ j;
                if (ixj > i) {
                    unsigned long long a = kk[i], b = kk[ixj];
                    bool descend = ((i & k) == 0);
                    if (descend ? (a < b) : (a > b)) { kk[i] = b; kk[ixj] = a; }
                }
            }
            __syncthreads();
        }
    }
    // slots 0..1023 = top-1024 descending (ties: smaller original index first)
    int idx = (int)(0xFFFFFFFFu - (unsigned int)(kk[tid] & 0xFFFFFFFFull));
    topI[tid] = idx;
    ss[tid] = sArr[idx];
    ee[tid] = eArr[idx];
}

// ---------------- NMS suppression bitmask ----------------
__global__ __launch_bounds__(256) void nms_mask_kernel(const float* __restrict__ ss, const float* __restrict__ ee,
                                                       unsigned long long* __restrict__ mask) {
    int g = blockIdx.x * 256 + threadIdx.x;  // 0..16383
    int i = g >> 4, w = g & 15;
    float si = ss[i], ei = ee[i];
    unsigned long long bits = 0ull;
#pragma unroll 1
    for (int jj = 0; jj < 64; jj++) {
        int j = w * 64 + jj;
        if (j > i) {
            float sj = ss[j], ej = ee[j];
            float inter = fmaxf(0.f, fminf(ei, ej) - fmaxf(si, sj));
            float uni = (ej - sj) + (ei - si) - inter;
            float iou = inter / fmaxf(uni, 1e-8f);
            if (iou > 0.7f) bits |= (1ull << jj);
        }
    }
    mask[(size_t)i * 16 + w] = bits;
}

// ---------------- sequential NMS scan + stable partition + gather ----------------
__global__ __launch_bounds__(1024) void nms_select_kernel(const unsigned long long* __restrict__ mask,
                                                          const int* __restrict__ topI,
                                                          const float* __restrict__ ss, const float* __restrict__ ee,
                                                          const float* __restrict__ cls2, const float* __restrict__ off2,
                                                          int* __restrict__ stA, int* __restrict__ enA,
                                                          float* __restrict__ out) {
    __shared__ unsigned long long keepW[16];
    __shared__ int scan[1024];
    int tid = threadIdx.x;
    if (tid < 64) {
        unsigned long long remv = 0ull;
        for (int i = 0; i < 1024; i++) {
            unsigned long long wv = __shfl(remv, i >> 6);
            if (!((wv >> (i & 63)) & 1ull)) {
                if (tid < 16) remv |= mask[(size_t)i * 16 + tid];
            }
        }
        if (tid < 16) keepW[tid] = ~remv;
    }
    __syncthreads();
    int keep = (int)((keepW[tid >> 6] >> (tid & 63)) & 1ull);
    scan[tid] = keep;
    __syncthreads();
    for (int off = 1; off < 1024; off <<= 1) {
        int v = (tid >= off) ? scan[tid - off] : 0;
        __syncthreads();
        scan[tid] += v;
        __syncthreads();
    }
    int total = scan[1023];
    int excl = scan[tid] - keep;
    int pos = keep ? excl : (total + tid - excl);
    if (pos < 128) {
        int orig = topI[tid];
        float ps = ss[tid], pe = ee[tid];
        out[pos * 2 + 0] = cls2[orig * 2 + 0];
        out[pos * 2 + 1] = cls2[orig * 2 + 1];
        out[256 + pos * 2 + 0] = off2[orig * 2 + 0];
        out[256 + pos * 2 + 1] = off2[orig * 2 + 1];
        float bc = (ps + pe) * 0.5f, bh = (pe - ps) * 0.5f;
        int st = (int)fminf(fmaxf(floorf(bc - bh), 0.f), 767.f);
        int en = (int)fminf(fmaxf(ceilf(bc + bh), 0.f), 767.f);
        if (en < st) en = st;
        stA[pos] = st;
        enA[pos] = en;
    }
}

// ---------------- ROI max pool: spp[ci][n*7+bin] ----------------
__global__ __launch_bounds__(256) void roi_kernel(const float* __restrict__ f,
                                                  const int* __restrict__ stA, const int* __restrict__ enA,
                                                  float* __restrict__ spp) {
    int n = blockIdx.x;
    int c = blockIdx.y * 256 + threadIdx.x;
    int st = stA[n], en = enA[n];
    int ln = en - st + 1;
    const float* row = f + (size_t)c * 768;
#pragma unroll 1
    for (int b = 0; b < 7; b++) {
        int bs = st + (b * ln) / 7;
        int be = st + ((b + 1) * ln + 6) / 7 - 1;
        float m = row[bs];
        for (int t = bs + 1; t <= be; t++) m = fmaxf(m, row[t]);
        spp[(size_t)c * 896 + n * 7 + b] = m;
    }
}

extern "C" void kernel_launch(void* const* d_in, const int* in_sizes, int n_in,
                              void* d_out, int out_size, void* d_ws, size_t ws_size,
                              hipStream_t stream) {
    const float* IN[39];
    for (int i = 0; i < 39; i++) IN[i] = (const float*)d_in[i];
    const float* feature = IN[0];
    const float *b1f = IN[1], *b2f = IN[2], *b3 = IN[3], *b4 = IN[4], *b5 = IN[5], *b6 = IN[6];
    const float *bc1 = IN[7], *bc2 = IN[8], *boxb = IN[9], *boxw = IN[10];
    const float *clsb = IN[11], *clsw = IN[12];
    const float *fc1b = IN[13], *fc1w = IN[14], *fc2b = IN[15], *fc2w = IN[16];
    const float *fc3b = IN[17], *fc3w = IN[18];
    const float *sp1b = IN[19], *sp1w = IN[20], *sp2b = IN[21], *sp2w = IN[22];
    const float *sp3b = IN[23], *sp3w = IN[24], *sp4b = IN[25], *sp4w = IN[26];
    const float *spcb = IN[27], *spcw = IN[28], *spsb = IN[29], *spsw = IN[30];
    const float *w1f = IN[31], *w2f = IN[32], *w3w = IN[33], *w4w = IN[34];
    const float *w5w = IN[35], *w6w = IN[36], *wc1 = IN[37], *wc2 = IN[38];
    float* out = (float*)d_out;

    char* base = (char*)d_ws;
    size_t off = 0;
    auto allocF = [&](size_t n) { float* p = (float*)(base + off); off += n * 4; return p; };
    float* f1    = allocF((size_t)2048 * 768);
    float* fbuf  = allocF((size_t)2048 * 768);
    float* xbuf  = allocF((size_t)512 * 768);
    float* hA    = allocF((size_t)512 * 768);
    float* hB    = allocF((size_t)512 * 768);
    float* clsS  = allocF((size_t)20 * 768);
    float* segS  = allocF((size_t)20 * 768);
    float* cls2  = allocF((size_t)7680 * 2);
    float* off2  = allocF((size_t)7680 * 2);
    float* scores = allocF(7680);
    float* sArr  = allocF(7680);
    float* eArr  = allocF(7680);
    float* ssS   = allocF(1024);
    float* eeS   = allocF(1024);
    float* spp   = allocF((size_t)2048 * 896);
    float* yA    = allocF((size_t)512 * 896);
    float* yB    = allocF((size_t)512 * 896);
    float* g1    = allocF((size_t)512 * 128);
    float* g2    = allocF((size_t)256 * 128);
    float* g3    = allocF((size_t)128 * 128);
    float* part  = allocF((size_t)2 * 2048 * 768);
    unsigned long long* mask = (unsigned long long*)(base + off); off += (size_t)16384 * 8;
    int* topI = (int*)(base + off); off += 1024 * 4;
    int* stA = (int*)(base + off); off += 128 * 4;
    int* enA = (int*)(base + off); off += 128 * 4;

    dim3 blk(256);

    // 1. f1 = conv(feature, w1f) + b1f
    conv3_kernel<<<dim3(16, 12, 2), blk, 0, stream>>>(feature, w1f, part, 2048, 2048, 2);
    finalize_kernel<<<6144, blk, 0, stream>>>(part, f1, b1f, 2048, 2048, 768, 2, 0);

    // 2. fbuf = conv(f1, w2f) + b2f   (kept for ROI)
    conv3_kernel<<<dim3(16, 12, 2), blk, 0, stream>>>(f1, w2f, part, 2048, 2048, 2);
    finalize_kernel<<<6144, blk, 0, stream>>>(part, fbuf, b2f, 2048, 2048, 768, 2, 0);

    // 3. xbuf = wc1 . fbuf + bc1
    gemm_kernel<0, 0><<<dim3(8, 12, 4), blk, 0, stream>>>(wc1, fbuf, bc1, part, 512, 2048, 768, 768, 4, 0);
    finalize_kernel<<<1536, blk, 0, stream>>>(part, xbuf, bc1, 512, 512, 768, 4, 0);

    // 4. sp1..sp4
    conv3_kernel<<<dim3(4, 12, 4), blk, 0, stream>>>(xbuf, sp1w, part, 512, 512, 4);
    finalize_kernel<<<1536, blk, 0, stream>>>(part, hA, sp1b, 512, 512, 768, 4, 0);
    conv3_kernel<<<dim3(4, 12, 4), blk, 0, stream>>>(hA, sp2w, part, 512, 512, 4);
    finalize_kernel<<<1536, blk, 0, stream>>>(part, hB, sp2b, 512, 512, 768, 4, 0);
    conv3_kernel<<<dim3(4, 12, 4), blk, 0, stream>>>(hB, sp3w, part, 512, 512, 4);
    finalize_kernel<<<1536, blk, 0, stream>>>(part, hA, sp3b, 512, 512, 768, 4, 0);
    conv3_kernel<<<dim3(4, 12, 4), blk, 0, stream>>>(hA, sp4w, part, 512, 512, 4);
    finalize_kernel<<<1536, blk, 0, stream>>>(part, hB, sp4b, 512, 512, 768, 4, 1);  // relu

    // 5. heads: cls_score, seg_pred (S=1, direct epilogue)
    gemm_kernel<0, 0><<<dim3(1, 12, 1), blk, 0, stream>>>(spcw, hB, spcb, clsS, 20, 512, 768, 768, 1, 0);
    gemm_kernel<0, 0><<<dim3(1, 12, 1), blk, 0, stream>>>(spsw, hB, spsb, segS, 20, 512, 768, 768, 1, 0);

    // 6. proposal decode
    proposal_kernel<<<30, blk, 0, stream>>>(clsS, segS, cls2, off2, scores, sArr, eArr);

    // 7. sort (top-1024, exact lax.top_k tie semantics)
    sort_kernel<<<1, 1024, 0, stream>>>(scores, sArr, eArr, topI, ssS, eeS);

    // 8. NMS
    nms_mask_kernel<<<64, blk, 0, stream>>>(ssS, eeS, mask);
    nms_select_kernel<<<1, 1024, 0, stream>>>(mask, topI, ssS, eeS, cls2, off2, stA, enA, out);

    // 9. ROI pool -> spp [2048][896]
    roi_kernel<<<dim3(128, 8), blk, 0, stream>>>(fbuf, stA, enA, spp);

    // 10. yA = wc2 . spp + bc2
    gemm_kernel<0, 0><<<dim3(8, 14, 4), blk, 0, stream>>>(wc2, spp, bc2, part, 512, 2048, 896, 896, 4, 0);
    finalize_kernel<<<1792, blk, 0, stream>>>(part, yA, bc2, 512, 512, 896, 4, 0);

    // 11. w3..w6 (len-7 convs via gather-GEMM)
    gemm_kernel<1, 0><<<dim3(8, 14, 4), blk, 0, stream>>>(w3w, yA, b3, part, 512, 1536, 896, 896, 4, 0);
    finalize_kernel<<<1792, blk, 0, stream>>>(part, yB, b3, 512, 512, 896, 4, 0);
    gemm_kernel<1, 0><<<dim3(8, 14, 4), blk, 0, stream>>>(w4w, yB, b4, part, 512, 1536, 896, 896, 4, 0);
    finalize_kernel<<<1792, blk, 0, stream>>>(part, yA, b4, 512, 512, 896, 4, 1);  // relu
    gemm_kernel<1, 0><<<dim3(8, 14, 4), blk, 0, stream>>>(w5w, yA, b5, part, 512, 1536, 896, 896, 4, 0);
    finalize_kernel<<<1792, blk, 0, stream>>>(part, yB, b5, 512, 512, 896, 4, 0);
    gemm_kernel<1, 0><<<dim3(8, 14, 4), blk, 0, stream>>>(w6w, yB, b6, part, 512, 1536, 896, 896, 4, 0);
    finalize_kernel<<<1792, blk, 0, stream>>>(part, yA, b6, 512, 512, 896, 4, 1);  // relu

    // 12. fc1 (relu)
    gemm_kernel<2, 0><<<dim3(8, 2, 28), blk, 0, stream>>>(fc1w, yA, fc1b, part, 512, 3584, 128, 128, 28, 0);
    finalize_kernel<<<256, blk, 0, stream>>>(part, g1, fc1b, 512, 512, 128, 28, 1);

    // 13. fc2, fc3
    gemm_kernel<0, 0><<<dim3(4, 2, 4), blk, 0, stream>>>(fc2w, g1, fc2b, part, 256, 512, 128, 128, 4, 0);
    finalize_kernel<<<128, blk, 0, stream>>>(part, g2, fc2b, 256, 256, 128, 4, 0);
    gemm_kernel<0, 0><<<dim3(2, 2, 2), blk, 0, stream>>>(fc3w, g2, fc3b, part, 128, 256, 128, 128, 2, 0);
    finalize_kernel<<<64, blk, 0, stream>>>(part, g3, fc3b, 128, 128, 128, 2, 0);

    // 14. output heads -> d_out (fp32)
    gemm_kernel<0, 1><<<dim3(1, 2, 1), blk, 0, stream>>>(clsw, g3, clsb, out, 21, 128, 128, 128, 1, 0);
    gemm_kernel<0, 2><<<dim3(1, 2, 1), blk, 0, stream>>>(boxw, g3, boxb, out, 40, 128, 128, 128, 1, 0);
}

// Round 3
// 1519.732 us; speedup vs baseline: 1.5294x; 1.5294x over previous
//
#include <hip/hip_runtime.h>

typedef __attribute__((ext_vector_type(8))) short short8;
typedef __attribute__((ext_vector_type(4))) float float4v;

__device__ __forceinline__ float bf(unsigned short u) {
    return __uint_as_float(((unsigned int)u) << 16);
}
__device__ __forceinline__ unsigned short f2b(float f) {
    unsigned int u = __float_as_uint(f);
    unsigned int r = (u + 0x7FFFu + ((u >> 16) & 1u)) >> 16;
    return (unsigned short)r;
}

__constant__ float c_anchors[10] = {2.f,4.f,5.f,6.f,8.f,9.f,10.f,12.f,14.f,16.f};

// ============ Xt helpers: transposed bf16 hi/lo slab [770][CI], planes h/l ============
__global__ __launch_bounds__(256) void zeroXt_kernel(unsigned short* __restrict__ Xt, int CI) {
    int i = blockIdx.x * 256 + threadIdx.x;
    if (i < 2 * CI) {
        int row = (i >= CI) ? 769 : 0;
        int co = (i >= CI) ? (i - CI) : i;
        Xt[(size_t)row * CI + co] = 0;
        Xt[(size_t)770 * CI + (size_t)row * CI + co] = 0;
    }
}

// src fp32 [CI][768] -> Xt rows 1..768 (row l+1 = X[:,l]), hi/lo planes
__global__ __launch_bounds__(256) void decomp_kernel(const float* __restrict__ src,
                                                     unsigned short* __restrict__ Xt, int CI) {
    __shared__ float T[32][33];
    int l0 = blockIdx.x * 32, ci0 = blockIdx.y * 32;
    int tid = threadIdx.x;
#pragma unroll
    for (int i = 0; i < 4; i++) {
        int slot = tid + 256 * i;
        int r = slot >> 5, c = slot & 31;
        T[r][c] = src[(size_t)(ci0 + r) * 768 + l0 + c];
    }
    __syncthreads();
    unsigned short* Xh = Xt;
    unsigned short* Xl = Xt + (size_t)770 * CI;
#pragma unroll
    for (int i = 0; i < 4; i++) {
        int slot = tid + 256 * i;
        int li = slot >> 5, cc = slot & 31;
        float v = T[cc][li];
        unsigned short h = f2b(v);
        float lo = v - bf(h);
        size_t o = (size_t)(l0 + li + 1) * CI + ci0 + cc;
        Xh[o] = h;
        Xl[o] = f2b(lo);
    }
}

// ============ MFMA conv-as-GEMM: G[z][co][l] = sum_ci Wt[co][ci] * X[ci][l+t-1] ============
// W fp32 [CO][CI][3]; Xt bf16 hi/lo [770][CI]; grid (CO/64, 768/128, 3*S); z = t*S + s
__global__ __launch_bounds__(512) void convmm_kernel(const float* __restrict__ W,
                                                     const unsigned short* __restrict__ Xt,
                                                     float* __restrict__ G,
                                                     int CO, int CI, int S) {
    __shared__ unsigned short At[2][64 * 40];
    __shared__ unsigned short Bt[2][130 * 40];
    int tid = threadIdx.x;
    int lane = tid & 63, wid = tid >> 6;
    int q = lane >> 4, ln = lane & 15;
    int co0 = blockIdx.x * 64;
    int l0 = blockIdx.y * 128;
    int z = blockIdx.z;
    int t = z / S, s = z - t * S;
    int kPer = CI / S, cis = s * kPer;
    const unsigned short* Xh = Xt;
    const unsigned short* Xl = Xt + (size_t)770 * CI;

    float4v zero4 = {0.f, 0.f, 0.f, 0.f};
    float4v acc[2][2];
    acc[0][0] = zero4; acc[0][1] = zero4; acc[1][0] = zero4; acc[1][1] = zero4;

    int wave_m = (wid >> 2) * 32;
    int wave_n = (wid & 3) * 32;

    for (int kb = 0; kb < kPer; kb += 32) {
        int cib = cis + kb;
        // stage A: 64 rows x 32 ci, fp32 stride-3 load + hi/lo decompose
#pragma unroll
        for (int i = 0; i < 4; i++) {
            int slot = tid + 512 * i;  // 0..2047
            int row = slot >> 5, ci = slot & 31;
            float v = W[((size_t)(co0 + row) * CI + (cib + ci)) * 3 + t];
            unsigned short h = f2b(v);
            float lo = v - bf(h);
            At[0][row * 40 + ci] = h;
            At[1][row * 40 + ci] = f2b(lo);
        }
        // stage B slab: rows l0..l0+129, 32 ci, both planes, 16B chunks
#pragma unroll
        for (int i = 0; i < 3; i++) {
            int slot = tid + 512 * i;
            if (slot < 1040) {
                int p = slot >= 520 ? 1 : 0;
                int rem = slot - p * 520;
                int r = rem >> 2, qq = rem & 3;
                const unsigned short* src = (p ? Xl : Xh) + (size_t)(l0 + r) * CI + cib + qq * 8;
                short8 v = *(const short8*)src;
                *(short8*)&Bt[p][r * 40 + qq * 8] = v;
            }
        }
        __syncthreads();
        short8 bh[2], bl[2];
#pragma unroll
        for (int nf = 0; nf < 2; nf++) {
            int rrow = wave_n + nf * 16 + ln + t;  // shift folded into slab row
            bh[nf] = *(const short8*)&Bt[0][rrow * 40 + q * 8];
            bl[nf] = *(const short8*)&Bt[1][rrow * 40 + q * 8];
        }
#pragma unroll
        for (int mf = 0; mf < 2; mf++) {
            int mrow = wave_m + mf * 16 + ln;
            short8 ah = *(const short8*)&At[0][mrow * 40 + q * 8];
            short8 al = *(const short8*)&At[1][mrow * 40 + q * 8];
#pragma unroll
            for (int nf = 0; nf < 2; nf++) {
                acc[mf][nf] = __builtin_amdgcn_mfma_f32_16x16x32_bf16(ah, bh[nf], acc[mf][nf], 0, 0, 0);
                acc[mf][nf] = __builtin_amdgcn_mfma_f32_16x16x32_bf16(ah, bl[nf], acc[mf][nf], 0, 0, 0);
                acc[mf][nf] = __builtin_amdgcn_mfma_f32_16x16x32_bf16(al, bh[nf], acc[mf][nf], 0, 0, 0);
            }
        }
        __syncthreads();
    }
    float* Gz = G + (size_t)z * CO * 768;
#pragma unroll
    for (int mf = 0; mf < 2; mf++)
#pragma unroll
        for (int nf = 0; nf < 2; nf++) {
            int col = l0 + wave_n + nf * 16 + ln;
            int rowb = co0 + wave_m + mf * 16 + q * 4;
#pragma unroll
            for (int r = 0; r < 4; r++)
                Gz[(size_t)(rowb + r) * 768 + col] = acc[mf][nf][r];
        }
}

// finalize: sum P planes + bias -> transposed bf16 hi/lo Xt (rows 1..768)
__global__ __launch_bounds__(256) void finsum_x_kernel(const float* __restrict__ G,
                                                       const float* __restrict__ bias,
                                                       unsigned short* __restrict__ Xt,
                                                       int CO, int P) {
    __shared__ float T[64][65];
    int co0 = blockIdx.x * 64, l0 = blockIdx.y * 64;
    int tid = threadIdx.x;
#pragma unroll 1
    for (int i = 0; i < 16; i++) {
        int slot = tid + 256 * i;
        int r = slot >> 6, c = slot & 63;
        float v = bias[co0 + r];
        for (int p = 0; p < P; p++) v += G[((size_t)p * CO + co0 + r) * 768 + l0 + c];
        T[r][c] = v;
    }
    __syncthreads();
    unsigned short* Xh = Xt;
    unsigned short* Xl = Xt + (size_t)770 * CO;
#pragma unroll 1
    for (int i = 0; i < 16; i++) {
        int slot = tid + 256 * i;
        int li = slot >> 6, ci = slot & 63;
        float v = T[ci][li];
        unsigned short h = f2b(v);
        float lo = v - bf(h);
        size_t o = (size_t)(l0 + li + 1) * CO + co0 + ci;
        Xh[o] = h;
        Xl[o] = f2b(lo);
    }
}

// finalize: sum P planes + bias (+relu) -> fp32 [CO][768]
__global__ __launch_bounds__(256) void finsum_f_kernel(const float* __restrict__ G,
                                                       const float* __restrict__ bias,
                                                       float* __restrict__ out,
                                                       int CO, int P, int relu) {
    int i = blockIdx.x * 256 + threadIdx.x;
    if (i >= CO * 768) return;
    int r = i / 768, c = i - r * 768;
    float v = bias[r];
    for (int p = 0; p < P; p++) v += G[((size_t)p * CO + r) * 768 + c];
    if (relu) v = fmaxf(v, 0.f);
    out[i] = v;
}

// ---------------- finalize for fp32 split-K gemm path ----------------
__global__ __launch_bounds__(256) void finalize_kernel(const float* __restrict__ part,
                                                       float* __restrict__ out,
                                                       const float* __restrict__ bias,
                                                       int RPAD, int R, int NCOLS, int S, int relu) {
    int i = blockIdx.x * 256 + threadIdx.x;
    int total = R * NCOLS;
    if (i >= total) return;
    int r = i / NCOLS;
    int c = i - r * NCOLS;
    float v = 0.f;
    for (int s = 0; s < S; s++) v += part[((size_t)s * RPAD + r) * NCOLS + c];
    v += bias[r];
    if (relu) v = fmaxf(v, 0.f);
    out[i] = v;
}

// ---------------- fp32 gather-GEMM (unchanged from round 1, split-K bumped) ----------------
template <int MODE, int EPI>
__global__ __launch_bounds__(256) void gemm_kernel(const float* __restrict__ W,
                                                   const float* __restrict__ B,
                                                   const float* __restrict__ bias,
                                                   float* __restrict__ outF,
                                                   int R, int K, int NCOLS, int LDB, int S, int relu) {
    __shared__ __align__(16) float Bt[16][68];
    __shared__ __align__(16) float Wt[16][68];
    int tid = threadIdx.x;
    int tx = tid & 15, ty = tid >> 4;
    int r0 = blockIdx.x * 64, c0 = blockIdx.y * 64, s = blockIdx.z;
    int kPer = K / S;
    int k0s = s * kPer;
    float acc[4][4] = {};
    for (int kb = 0; kb < kPer; kb += 16) {
        int k0 = k0s + kb;
        {
            int rr = r0 + (tid >> 2);
            int q = tid & 3;
            float4 wv4 = {0.f, 0.f, 0.f, 0.f};
            if (rr < R) wv4 = *(const float4*)(W + (size_t)rr * K + k0 + q * 4);
            Wt[q * 4 + 0][tid >> 2] = wv4.x;
            Wt[q * 4 + 1][tid >> 2] = wv4.y;
            Wt[q * 4 + 2][tid >> 2] = wv4.z;
            Wt[q * 4 + 3][tid >> 2] = wv4.w;
        }
#pragma unroll
        for (int p = 0; p < 4; p++) {
            int kk = p * 4 + (tid >> 6);
            int c = tid & 63;
            int k = k0 + kk;
            int col = c0 + c;
            float v;
            if (MODE == 0) {
                v = B[(size_t)k * LDB + col];
            } else if (MODE == 1) {
                int ci = k / 3;
                int t = k - ci * 3;
                int lc = (col % 7) + t - 1;
                v = ((unsigned)lc < 7u) ? B[(size_t)ci * 896 + col + t - 1] : 0.f;
            } else {
                int co = k / 7;
                int b7 = k - co * 7;
                v = B[(size_t)co * 896 + col * 7 + b7];
            }
            Bt[kk][c] = v;
        }
        __syncthreads();
#pragma unroll
        for (int kk = 0; kk < 16; kk++) {
            float4 bv = *(const float4*)&Bt[kk][tx * 4];
            float4 wv = *(const float4*)&Wt[kk][ty * 4];
            float bb[4] = {bv.x, bv.y, bv.z, bv.w};
            float ww[4] = {wv.x, wv.y, wv.z, wv.w};
#pragma unroll
            for (int i = 0; i < 4; i++)
#pragma unroll
                for (int j = 0; j < 4; j++)
                    acc[i][j] = fmaf(ww[i], bb[j], acc[i][j]);
        }
        __syncthreads();
    }
    if (EPI == 0) {
        if (S > 1) {
#pragma unroll
            for (int i = 0; i < 4; i++) {
                int r = r0 + ty * 4 + i;
                float4 o = {acc[i][0], acc[i][1], acc[i][2], acc[i][3]};
                *(float4*)&outF[((size_t)s * R + r) * NCOLS + c0 + tx * 4] = o;
            }
        } else {
#pragma unroll
            for (int i = 0; i < 4; i++) {
                int r = r0 + ty * 4 + i;
                if (r < R) {
                    float bv = bias[r];
#pragma unroll
                    for (int j = 0; j < 4; j++) {
                        float v = acc[i][j] + bv;
                        if (relu) v = fmaxf(v, 0.f);
                        outF[(size_t)r * NCOLS + c0 + tx * 4 + j] = v;
                    }
                }
            }
        }
    } else {
#pragma unroll
        for (int i = 0; i < 4; i++) {
            int r = r0 + ty * 4 + i;
            if (r < R) {
                float bv = bias[r];
#pragma unroll
                for (int j = 0; j < 4; j++) {
                    int col = c0 + tx * 4 + j;
                    float v = acc[i][j] + bv;
                    if (EPI == 1) outF[512 + col * 21 + r] = v;
                    else outF[3200 + col * 40 + r] = v;
                }
            }
        }
    }
}

// ---------------- proposals: softmax, anchor decode ----------------
__global__ __launch_bounds__(256) void proposal_kernel(const float* __restrict__ clsS,
                                                       const float* __restrict__ segS,
                                                       float* __restrict__ cls2, float* __restrict__ off2,
                                                       float* __restrict__ scores,
                                                       float* __restrict__ sArr, float* __restrict__ eArr) {
    int i = blockIdx.x * 256 + threadIdx.x;
    if (i >= 7680) return;
    int l = i / 10;
    int a = i - l * 10;
    float c0 = clsS[(a * 2 + 0) * 768 + l];
    float c1 = clsS[(a * 2 + 1) * 768 + l];
    cls2[i * 2] = c0;
    cls2[i * 2 + 1] = c1;
    float m = fmaxf(c0, c1);
    float e0 = expf(c0 - m), e1 = expf(c1 - m);
    scores[i] = e1 / (e0 + e1);
    float o0 = segS[(a * 2 + 0) * 768 + l];
    float o1 = segS[(a * 2 + 1) * 768 + l];
    off2[i * 2] = o0;
    off2[i * 2 + 1] = o1;
    float ah = c_anchors[a] * 0.5f;
    float ac = (float)l + 0.5f;
    float c = ac + o0 * (2.f * ah);
    float hl = ah * expf(o1);
    sArr[i] = fminf(fmaxf(c - hl, 0.f), 768.f);
    eArr[i] = fminf(fmaxf(c + hl, 0.f), 768.f);
}

// ---------------- full bitonic sort of 8192 keys, keep top 1024 ----------------
__global__ __launch_bounds__(1024) void sort_kernel(const float* __restrict__ scores,
                                                    const float* __restrict__ sArr, const float* __restrict__ eArr,
                                                    int* __restrict__ topI,
                                                    float* __restrict__ ss, float* __restrict__ ee) {
    __shared__ unsigned long long kk[8192];
    int tid = threadIdx.x;
#pragma unroll
    for (int m = 0; m < 8; m++) {
        int i = tid + m * 1024;
        unsigned long long key = 0ull;
        if (i < 7680) {
            unsigned int sb = __float_as_uint(scores[i]);
            key = ((unsigned long long)sb << 32) | (unsigned long long)(0xFFFFFFFFu - (unsigned)i);
        }
        kk[i] = key;
    }
    __syncthreads();
    for (int k = 2; k <= 8192; k <<= 1) {
        for (int j = k >> 1; j > 0; j >>= 1) {
#pragma unroll 1
            for (int m = 0; m < 8; m++) {
                int i = tid + m * 1024;
                int ixj = i ^ j;
                if (ixj > i) {
                    unsigned long long a = kk[i], b = kk[ixj];
                    bool descend = ((i & k) == 0);
                    if (descend ? (a < b) : (a > b)) { kk[i] = b; kk[ixj] = a; }
                }
            }
            __syncthreads();
        }
    }
    int idx = (int)(0xFFFFFFFFu - (unsigned int)(kk[tid] & 0xFFFFFFFFull));
    topI[tid] = idx;
    ss[tid] = sArr[idx];
    ee[tid] = eArr[idx];
}

// ---------------- NMS suppression bitmask ----------------
__global__ __launch_bounds__(256) void nms_mask_kernel(const float* __restrict__ ss, const float* __restrict__ ee,
                                                       unsigned long long* __restrict__ mask) {
    int g = blockIdx.x * 256 + threadIdx.x;
    int i = g >> 4, w = g & 15;
    float si = ss[i], ei = ee[i];
    unsigned long long bits = 0ull;
#pragma unroll 1
    for (int jj = 0; jj < 64; jj++) {
        int j = w * 64 + jj;
        if (j > i) {
            float sj = ss[j], ej = ee[j];
            float inter = fmaxf(0.f, fminf(ei, ej) - fmaxf(si, sj));
            float uni = (ej - sj) + (ei - si) - inter;
            float iou = inter / fmaxf(uni, 1e-8f);
            if (iou > 0.7f) bits |= (1ull << jj);
        }
    }
    mask[(size_t)i * 16 + w] = bits;
}

// ---------------- sequential NMS scan + stable partition + gather ----------------
__global__ __launch_bounds__(1024) void nms_select_kernel(const unsigned long long* __restrict__ mask,
                                                          const int* __restrict__ topI,
                                                          const float* __restrict__ ss, const float* __restrict__ ee,
                                                          const float* __restrict__ cls2, const float* __restrict__ off2,
                                                          int* __restrict__ stA, int* __restrict__ enA,
                                                          float* __restrict__ out) {
    __shared__ unsigned long long keepW[16];
    __shared__ int scan[1024];
    int tid = threadIdx.x;
    if (tid < 64) {
        unsigned long long remv = 0ull;
        for (int i = 0; i < 1024; i++) {
            unsigned long long wv = __shfl(remv, i >> 6);
            if (!((wv >> (i & 63)) & 1ull)) {
                if (tid < 16) remv |= mask[(size_t)i * 16 + tid];
            }
        }
        if (tid < 16) keepW[tid] = ~remv;
    }
    __syncthreads();
    int keep = (int)((keepW[tid >> 6] >> (tid & 63)) & 1ull);
    scan[tid] = keep;
    __syncthreads();
    for (int off = 1; off < 1024; off <<= 1) {
        int v = (tid >= off) ? scan[tid - off] : 0;
        __syncthreads();
        scan[tid] += v;
        __syncthreads();
    }
    int total = scan[1023];
    int excl = scan[tid] - keep;
    int pos = keep ? excl : (total + tid - excl);
    if (pos < 128) {
        int orig = topI[tid];
        float ps = ss[tid], pe = ee[tid];
        out[pos * 2 + 0] = cls2[orig * 2 + 0];
        out[pos * 2 + 1] = cls2[orig * 2 + 1];
        out[256 + pos * 2 + 0] = off2[orig * 2 + 0];
        out[256 + pos * 2 + 1] = off2[orig * 2 + 1];
        float bc = (ps + pe) * 0.5f, bh = (pe - ps) * 0.5f;
        int st = (int)fminf(fmaxf(floorf(bc - bh), 0.f), 767.f);
        int en = (int)fminf(fmaxf(ceilf(bc + bh), 0.f), 767.f);
        if (en < st) en = st;
        stA[pos] = st;
        enA[pos] = en;
    }
}

// ---------------- ROI max pool ----------------
__global__ __launch_bounds__(256) void roi_kernel(const float* __restrict__ f,
                                                  const int* __restrict__ stA, const int* __restrict__ enA,
                                                  float* __restrict__ spp) {
    int n = blockIdx.x;
    int c = blockIdx.y * 256 + threadIdx.x;
    int st = stA[n], en = enA[n];
    int ln = en - st + 1;
    const float* row = f + (size_t)c * 768;
#pragma unroll 1
    for (int b = 0; b < 7; b++) {
        int bs = st + (b * ln) / 7;
        int be = st + ((b + 1) * ln + 6) / 7 - 1;
        float m = row[bs];
        for (int t = bs + 1; t <= be; t++) m = fmaxf(m, row[t]);
        spp[(size_t)c * 896 + n * 7 + b] = m;
    }
}

extern "C" void kernel_launch(void* const* d_in, const int* in_sizes, int n_in,
                              void* d_out, int out_size, void* d_ws, size_t ws_size,
                              hipStream_t stream) {
    const float* IN[39];
    for (int i = 0; i < 39; i++) IN[i] = (const float*)d_in[i];
    const float* feature = IN[0];
    const float *b1f = IN[1], *b2f = IN[2], *b3 = IN[3], *b4 = IN[4], *b5 = IN[5], *b6 = IN[6];
    const float *bc1 = IN[7], *bc2 = IN[8], *boxb = IN[9], *boxw = IN[10];
    const float *clsb = IN[11], *clsw = IN[12];
    const float *fc1b = IN[13], *fc1w = IN[14], *fc2b = IN[15], *fc2w = IN[16];
    const float *fc3b = IN[17], *fc3w = IN[18];
    const float *sp1b = IN[19], *sp1w = IN[20], *sp2b = IN[21], *sp2w = IN[22];
    const float *sp3b = IN[23], *sp3w = IN[24], *sp4b = IN[25], *sp4w = IN[26];
    const float *spcb = IN[27], *spcw = IN[28], *spsb = IN[29], *spsw = IN[30];
    const float *w1f = IN[31], *w2f = IN[32], *w3w = IN[33], *w4w = IN[34];
    const float *w5w = IN[35], *w6w = IN[36], *wc1 = IN[37], *wc2 = IN[38];
    float* out = (float*)d_out;

    char* base = (char*)d_ws;
    // shared region: G (<=18.87 MB) during convs; later part/spp/yA/yB/g1-3
    float* G    = (float*)base;
    float* part = (float*)base;
    float* spp  = (float*)(base + 14680064);
    float* yA   = (float*)(base + 22020096);
    float* yB   = (float*)(base + 23855104);
    float* g1   = (float*)(base + 25690112);
    float* g2   = (float*)(base + 25952256);
    float* g3   = (float*)(base + 26083328);
    size_t off = 26148864;
    auto alloc = [&](size_t bytes) { void* p = base + off; off += (bytes + 15) & ~((size_t)15); return p; };
    unsigned short* Xt = (unsigned short*)alloc((size_t)770 * 2048 * 2 * 2);
    float* fbuf = (float*)alloc((size_t)2048 * 768 * 4);
    float* xbuf = (float*)alloc((size_t)512 * 768 * 4);
    float* hB   = (float*)alloc((size_t)512 * 768 * 4);
    float* clsS = (float*)alloc((size_t)20 * 768 * 4);
    float* segS = (float*)alloc((size_t)20 * 768 * 4);
    float* cls2 = (float*)alloc(7680 * 2 * 4);
    float* off2 = (float*)alloc(7680 * 2 * 4);
    float* scores = (float*)alloc(7680 * 4);
    float* sArr = (float*)alloc(7680 * 4);
    float* eArr = (float*)alloc(7680 * 4);
    float* ssS  = (float*)alloc(1024 * 4);
    float* eeS  = (float*)alloc(1024 * 4);
    unsigned long long* mask = (unsigned long long*)alloc((size_t)16384 * 8);
    int* topI = (int*)alloc(1024 * 4);
    int* stA = (int*)alloc(128 * 4);
    int* enA = (int*)alloc(128 * 4);

    dim3 blk(256);
    dim3 blk512(512);

    // ---- conv1: feature -> Xt -> G -> Xt (no f1 buffer needed) ----
    zeroXt_kernel<<<16, blk, 0, stream>>>(Xt, 2048);
    decomp_kernel<<<dim3(24, 64), blk, 0, stream>>>(feature, Xt, 2048);
    convmm_kernel<<<dim3(32, 6, 3), blk512, 0, stream>>>(w1f, Xt, G, 2048, 2048, 1);
    finsum_x_kernel<<<dim3(32, 12), blk, 0, stream>>>(G, b1f, Xt, 2048, 3);
    // ---- conv2: Xt -> G -> fbuf (fp32, kept for ROI/wc1) ----
    convmm_kernel<<<dim3(32, 6, 3), blk512, 0, stream>>>(w2f, Xt, G, 2048, 2048, 1);
    finsum_f_kernel<<<6144, blk, 0, stream>>>(G, b2f, fbuf, 2048, 3, 0);

    // ---- wc1: xbuf = wc1 . fbuf + bc1 (fp32 path, S=8) ----
    gemm_kernel<0, 0><<<dim3(8, 12, 8), blk, 0, stream>>>(wc1, fbuf, bc1, part, 512, 2048, 768, 768, 8, 0);
    finalize_kernel<<<1536, blk, 0, stream>>>(part, xbuf, bc1, 512, 512, 768, 8, 0);

    // ---- sp1..sp4 via MFMA (S=4) ----
    zeroXt_kernel<<<4, blk, 0, stream>>>(Xt, 512);
    decomp_kernel<<<dim3(24, 16), blk, 0, stream>>>(xbuf, Xt, 512);
    convmm_kernel<<<dim3(8, 6, 12), blk512, 0, stream>>>(sp1w, Xt, G, 512, 512, 4);
    finsum_x_kernel<<<dim3(8, 12), blk, 0, stream>>>(G, sp1b, Xt, 512, 12);
    convmm_kernel<<<dim3(8, 6, 12), blk512, 0, stream>>>(sp2w, Xt, G, 512, 512, 4);
    finsum_x_kernel<<<dim3(8, 12), blk, 0, stream>>>(G, sp2b, Xt, 512, 12);
    convmm_kernel<<<dim3(8, 6, 12), blk512, 0, stream>>>(sp3w, Xt, G, 512, 512, 4);
    finsum_x_kernel<<<dim3(8, 12), blk, 0, stream>>>(G, sp3b, Xt, 512, 12);
    convmm_kernel<<<dim3(8, 6, 12), blk512, 0, stream>>>(sp4w, Xt, G, 512, 512, 4);
    finsum_f_kernel<<<1536, blk, 0, stream>>>(G, sp4b, hB, 512, 12, 1);  // relu

    // ---- heads ----
    gemm_kernel<0, 0><<<dim3(1, 12, 1), blk, 0, stream>>>(spcw, hB, spcb, clsS, 20, 512, 768, 768, 1, 0);
    gemm_kernel<0, 0><<<dim3(1, 12, 1), blk, 0, stream>>>(spsw, hB, spsb, segS, 20, 512, 768, 768, 1, 0);

    // ---- proposal decode / sort / NMS ----
    proposal_kernel<<<30, blk, 0, stream>>>(clsS, segS, cls2, off2, scores, sArr, eArr);
    sort_kernel<<<1, 1024, 0, stream>>>(scores, sArr, eArr, topI, ssS, eeS);
    nms_mask_kernel<<<64, blk, 0, stream>>>(ssS, eeS, mask);
    nms_select_kernel<<<1, 1024, 0, stream>>>(mask, topI, ssS, eeS, cls2, off2, stA, enA, out);

    // ---- ROI pool ----
    roi_kernel<<<dim3(128, 8), blk, 0, stream>>>(fbuf, stA, enA, spp);

    // ---- classifier tower (fp32 path, split-K bumped) ----
    gemm_kernel<0, 0><<<dim3(8, 14, 8), blk, 0, stream>>>(wc2, spp, bc2, part, 512, 2048, 896, 896, 8, 0);
    finalize_kernel<<<1792, blk, 0, stream>>>(part, yA, bc2, 512, 512, 896, 8, 0);

    gemm_kernel<1, 0><<<dim3(8, 14, 8), blk, 0, stream>>>(w3w, yA, b3, part, 512, 1536, 896, 896, 8, 0);
    finalize_kernel<<<1792, blk, 0, stream>>>(part, yB, b3, 512, 512, 896, 8, 0);
    gemm_kernel<1, 0><<<dim3(8, 14, 8), blk, 0, stream>>>(w4w, yB, b4, part, 512, 1536, 896, 896, 8, 0);
    finalize_kernel<<<1792, blk, 0, stream>>>(part, yA, b4, 512, 512, 896, 8, 1);  // relu
    gemm_kernel<1, 0><<<dim3(8, 14, 8), blk, 0, stream>>>(w5w, yA, b5, part, 512, 1536, 896, 896, 8, 0);
    finalize_kernel<<<1792, blk, 0, stream>>>(part, yB, b5, 512, 512, 896, 8, 0);
    gemm_kernel<1, 0><<<dim3(8, 14, 8), blk, 0, stream>>>(w6w, yB, b6, part, 512, 1536, 896, 896, 8, 0);
    finalize_kernel<<<1792, blk, 0, stream>>>(part, yA, b6, 512, 512, 896, 8, 1);  // relu

    gemm_kernel<2, 0><<<dim3(8, 2, 28), blk, 0, stream>>>(fc1w, yA, fc1b, part, 512, 3584, 128, 128, 28, 0);
    finalize_kernel<<<256, blk, 0, stream>>>(part, g1, fc1b, 512, 512, 128, 28, 1);

    gemm_kernel<0, 0><<<dim3(4, 2, 4), blk, 0, stream>>>(fc2w, g1, fc2b, part, 256, 512, 128, 128, 4, 0);
    finalize_kernel<<<128, blk, 0, stream>>>(part, g2, fc2b, 256, 256, 128, 4, 0);
    gemm_kernel<0, 0><<<dim3(2, 2, 2), blk, 0, stream>>>(fc3w, g2, fc3b, part, 128, 256, 128, 128, 2, 0);
    finalize_kernel<<<64, blk, 0, stream>>>(part, g3, fc3b, 128, 128, 128, 2, 0);

    gemm_kernel<0, 1><<<dim3(1, 2, 1), blk, 0, stream>>>(clsw, g3, clsb, out, 21, 128, 128, 128, 1, 0);
    gemm_kernel<0, 2><<<dim3(1, 2, 1), blk, 0, stream>>>(boxw, g3, boxb, out, 40, 128, 128, 128, 1, 0);
}

// Round 4
// 1402.051 us; speedup vs baseline: 1.6578x; 1.0839x over previous
//
#include <hip/hip_runtime.h>

typedef __attribute__((ext_vector_type(8))) short short8;
typedef __attribute__((ext_vector_type(4))) float float4v;

__device__ __forceinline__ float bf(unsigned short u) {
    return __uint_as_float(((unsigned int)u) << 16);
}
__device__ __forceinline__ unsigned short f2b(float f) {
    unsigned int u = __float_as_uint(f);
    unsigned int r = (u + 0x7FFFu + ((u >> 16) & 1u)) >> 16;
    return (unsigned short)r;
}

__constant__ float c_anchors[10] = {2.f,4.f,5.f,6.f,8.f,9.f,10.f,12.f,14.f,16.f};

// ============ Xt helpers: transposed bf16 hi/lo slab [770][CI], planes h/l ============
__global__ __launch_bounds__(256) void zeroXt_kernel(unsigned short* __restrict__ Xt, int CI) {
    int i = blockIdx.x * 256 + threadIdx.x;
    if (i < 2 * CI) {
        int row = (i >= CI) ? 769 : 0;
        int co = (i >= CI) ? (i - CI) : i;
        Xt[(size_t)row * CI + co] = 0;
        Xt[(size_t)770 * CI + (size_t)row * CI + co] = 0;
    }
}

// src fp32 [CI][768] -> Xt rows 1..768 (row l+1 = X[:,l]), hi/lo planes
__global__ __launch_bounds__(256) void decomp_kernel(const float* __restrict__ src,
                                                     unsigned short* __restrict__ Xt, int CI) {
    __shared__ float T[32][33];
    int l0 = blockIdx.x * 32, ci0 = blockIdx.y * 32;
    int tid = threadIdx.x;
#pragma unroll
    for (int i = 0; i < 4; i++) {
        int slot = tid + 256 * i;
        int r = slot >> 5, c = slot & 31;
        T[r][c] = src[(size_t)(ci0 + r) * 768 + l0 + c];
    }
    __syncthreads();
    unsigned short* Xh = Xt;
    unsigned short* Xl = Xt + (size_t)770 * CI;
#pragma unroll
    for (int i = 0; i < 4; i++) {
        int slot = tid + 256 * i;
        int li = slot >> 5, cc = slot & 31;
        float v = T[cc][li];
        unsigned short h = f2b(v);
        float lo = v - bf(h);
        size_t o = (size_t)(l0 + li + 1) * CI + ci0 + cc;
        Xh[o] = h;
        Xl[o] = f2b(lo);
    }
}

// ============ MFMA conv-as-GEMM: G[z][co][l] = sum_ci Wt[co][ci] * X[ci][l+t-1] ============
__global__ __launch_bounds__(512) void convmm_kernel(const float* __restrict__ W,
                                                     const unsigned short* __restrict__ Xt,
                                                     float* __restrict__ G,
                                                     int CO, int CI, int S) {
    __shared__ unsigned short At[2][64 * 40];
    __shared__ unsigned short Bt[2][130 * 40];
    int tid = threadIdx.x;
    int lane = tid & 63, wid = tid >> 6;
    int q = lane >> 4, ln = lane & 15;
    int co0 = blockIdx.x * 64;
    int l0 = blockIdx.y * 128;
    int z = blockIdx.z;
    int t = z / S, s = z - t * S;
    int kPer = CI / S, cis = s * kPer;
    const unsigned short* Xh = Xt;
    const unsigned short* Xl = Xt + (size_t)770 * CI;

    float4v zero4 = {0.f, 0.f, 0.f, 0.f};
    float4v acc[2][2];
    acc[0][0] = zero4; acc[0][1] = zero4; acc[1][0] = zero4; acc[1][1] = zero4;

    int wave_m = (wid >> 2) * 32;
    int wave_n = (wid & 3) * 32;

    for (int kb = 0; kb < kPer; kb += 32) {
        int cib = cis + kb;
#pragma unroll
        for (int i = 0; i < 4; i++) {
            int slot = tid + 512 * i;
            int row = slot >> 5, ci = slot & 31;
            float v = W[((size_t)(co0 + row) * CI + (cib + ci)) * 3 + t];
            unsigned short h = f2b(v);
            float lo = v - bf(h);
            At[0][row * 40 + ci] = h;
            At[1][row * 40 + ci] = f2b(lo);
        }
#pragma unroll
        for (int i = 0; i < 3; i++) {
            int slot = tid + 512 * i;
            if (slot < 1040) {
                int p = slot >= 520 ? 1 : 0;
                int rem = slot - p * 520;
                int r = rem >> 2, qq = rem & 3;
                const unsigned short* src = (p ? Xl : Xh) + (size_t)(l0 + r) * CI + cib + qq * 8;
                short8 v = *(const short8*)src;
                *(short8*)&Bt[p][r * 40 + qq * 8] = v;
            }
        }
        __syncthreads();
        short8 bh[2], bl[2];
#pragma unroll
        for (int nf = 0; nf < 2; nf++) {
            int rrow = wave_n + nf * 16 + ln + t;
            bh[nf] = *(const short8*)&Bt[0][rrow * 40 + q * 8];
            bl[nf] = *(const short8*)&Bt[1][rrow * 40 + q * 8];
        }
#pragma unroll
        for (int mf = 0; mf < 2; mf++) {
            int mrow = wave_m + mf * 16 + ln;
            short8 ah = *(const short8*)&At[0][mrow * 40 + q * 8];
            short8 al = *(const short8*)&At[1][mrow * 40 + q * 8];
#pragma unroll
            for (int nf = 0; nf < 2; nf++) {
                acc[mf][nf] = __builtin_amdgcn_mfma_f32_16x16x32_bf16(ah, bh[nf], acc[mf][nf], 0, 0, 0);
                acc[mf][nf] = __builtin_amdgcn_mfma_f32_16x16x32_bf16(ah, bl[nf], acc[mf][nf], 0, 0, 0);
                acc[mf][nf] = __builtin_amdgcn_mfma_f32_16x16x32_bf16(al, bh[nf], acc[mf][nf], 0, 0, 0);
            }
        }
        __syncthreads();
    }
    float* Gz = G + (size_t)z * CO * 768;
#pragma unroll
    for (int mf = 0; mf < 2; mf++)
#pragma unroll
        for (int nf = 0; nf < 2; nf++) {
            int col = l0 + wave_n + nf * 16 + ln;
            int rowb = co0 + wave_m + mf * 16 + q * 4;
#pragma unroll
            for (int r = 0; r < 4; r++)
                Gz[(size_t)(rowb + r) * 768 + col] = acc[mf][nf][r];
        }
}

// finalize: sum P planes + bias -> transposed bf16 hi/lo Xt (rows 1..768)
__global__ __launch_bounds__(256) void finsum_x_kernel(const float* __restrict__ G,
                                                       const float* __restrict__ bias,
                                                       unsigned short* __restrict__ Xt,
                                                       int CO, int P) {
    __shared__ float T[64][65];
    int co0 = blockIdx.x * 64, l0 = blockIdx.y * 64;
    int tid = threadIdx.x;
#pragma unroll 1
    for (int i = 0; i < 16; i++) {
        int slot = tid + 256 * i;
        int r = slot >> 6, c = slot & 63;
        float v = bias[co0 + r];
        for (int p = 0; p < P; p++) v += G[((size_t)p * CO + co0 + r) * 768 + l0 + c];
        T[r][c] = v;
    }
    __syncthreads();
    unsigned short* Xh = Xt;
    unsigned short* Xl = Xt + (size_t)770 * CO;
#pragma unroll 1
    for (int i = 0; i < 16; i++) {
        int slot = tid + 256 * i;
        int li = slot >> 6, ci = slot & 63;
        float v = T[ci][li];
        unsigned short h = f2b(v);
        float lo = v - bf(h);
        size_t o = (size_t)(l0 + li + 1) * CO + co0 + ci;
        Xh[o] = h;
        Xl[o] = f2b(lo);
    }
}

// finalize: sum P planes + bias (+relu) -> fp32 [CO][768]
__global__ __launch_bounds__(256) void finsum_f_kernel(const float* __restrict__ G,
                                                       const float* __restrict__ bias,
                                                       float* __restrict__ out,
                                                       int CO, int P, int relu) {
    int i = blockIdx.x * 256 + threadIdx.x;
    if (i >= CO * 768) return;
    int r = i / 768, c = i - r * 768;
    float v = bias[r];
    for (int p = 0; p < P; p++) v += G[((size_t)p * CO + r) * 768 + c];
    if (relu) v = fmaxf(v, 0.f);
    out[i] = v;
}

// ---------------- finalize for fp32 split-K gemm path ----------------
__global__ __launch_bounds__(256) void finalize_kernel(const float* __restrict__ part,
                                                       float* __restrict__ out,
                                                       const float* __restrict__ bias,
                                                       int RPAD, int R, int NCOLS, int S, int relu) {
    int i = blockIdx.x * 256 + threadIdx.x;
    int total = R * NCOLS;
    if (i >= total) return;
    int r = i / NCOLS;
    int c = i - r * NCOLS;
    float v = 0.f;
    for (int s = 0; s < S; s++) v += part[((size_t)s * RPAD + r) * NCOLS + c];
    v += bias[r];
    if (relu) v = fmaxf(v, 0.f);
    out[i] = v;
}

// ---------------- fp32 gather-GEMM ----------------
template <int MODE, int EPI>
__global__ __launch_bounds__(256) void gemm_kernel(const float* __restrict__ W,
                                                   const float* __restrict__ B,
                                                   const float* __restrict__ bias,
                                                   float* __restrict__ outF,
                                                   int R, int K, int NCOLS, int LDB, int S, int relu) {
    __shared__ __align__(16) float Bt[16][68];
    __shared__ __align__(16) float Wt[16][68];
    int tid = threadIdx.x;
    int tx = tid & 15, ty = tid >> 4;
    int r0 = blockIdx.x * 64, c0 = blockIdx.y * 64, s = blockIdx.z;
    int kPer = K / S;
    int k0s = s * kPer;
    float acc[4][4] = {};
    for (int kb = 0; kb < kPer; kb += 16) {
        int k0 = k0s + kb;
        {
            int rr = r0 + (tid >> 2);
            int q = tid & 3;
            float4 wv4 = {0.f, 0.f, 0.f, 0.f};
            if (rr < R) wv4 = *(const float4*)(W + (size_t)rr * K + k0 + q * 4);
            Wt[q * 4 + 0][tid >> 2] = wv4.x;
            Wt[q * 4 + 1][tid >> 2] = wv4.y;
            Wt[q * 4 + 2][tid >> 2] = wv4.z;
            Wt[q * 4 + 3][tid >> 2] = wv4.w;
        }
#pragma unroll
        for (int p = 0; p < 4; p++) {
            int kk = p * 4 + (tid >> 6);
            int c = tid & 63;
            int k = k0 + kk;
            int col = c0 + c;
            float v;
            if (MODE == 0) {
                v = B[(size_t)k * LDB + col];
            } else if (MODE == 1) {
                int ci = k / 3;
                int t = k - ci * 3;
                int lc = (col % 7) + t - 1;
                v = ((unsigned)lc < 7u) ? B[(size_t)ci * 896 + col + t - 1] : 0.f;
            } else {
                int co = k / 7;
                int b7 = k - co * 7;
                v = B[(size_t)co * 896 + col * 7 + b7];
            }
            Bt[kk][c] = v;
        }
        __syncthreads();
#pragma unroll
        for (int kk = 0; kk < 16; kk++) {
            float4 bv = *(const float4*)&Bt[kk][tx * 4];
            float4 wv = *(const float4*)&Wt[kk][ty * 4];
            float bb[4] = {bv.x, bv.y, bv.z, bv.w};
            float ww[4] = {wv.x, wv.y, wv.z, wv.w};
#pragma unroll
            for (int i = 0; i < 4; i++)
#pragma unroll
                for (int j = 0; j < 4; j++)
                    acc[i][j] = fmaf(ww[i], bb[j], acc[i][j]);
        }
        __syncthreads();
    }
    if (EPI == 0) {
        if (S > 1) {
#pragma unroll
            for (int i = 0; i < 4; i++) {
                int r = r0 + ty * 4 + i;
                float4 o = {acc[i][0], acc[i][1], acc[i][2], acc[i][3]};
                *(float4*)&outF[((size_t)s * R + r) * NCOLS + c0 + tx * 4] = o;
            }
        } else {
#pragma unroll
            for (int i = 0; i < 4; i++) {
                int r = r0 + ty * 4 + i;
                if (r < R) {
                    float bv = bias[r];
#pragma unroll
                    for (int j = 0; j < 4; j++) {
                        float v = acc[i][j] + bv;
                        if (relu) v = fmaxf(v, 0.f);
                        outF[(size_t)r * NCOLS + c0 + tx * 4 + j] = v;
                    }
                }
            }
        }
    } else {
#pragma unroll
        for (int i = 0; i < 4; i++) {
            int r = r0 + ty * 4 + i;
            if (r < R) {
                float bv = bias[r];
#pragma unroll
                for (int j = 0; j < 4; j++) {
                    int col = c0 + tx * 4 + j;
                    float v = acc[i][j] + bv;
                    if (EPI == 1) outF[512 + col * 21 + r] = v;
                    else outF[3200 + col * 40 + r] = v;
                }
            }
        }
    }
}

// ---------------- proposals: softmax, anchor decode ----------------
__global__ __launch_bounds__(256) void proposal_kernel(const float* __restrict__ clsS,
                                                       const float* __restrict__ segS,
                                                       float* __restrict__ cls2, float* __restrict__ off2,
                                                       float* __restrict__ scores,
                                                       float* __restrict__ sArr, float* __restrict__ eArr) {
    int i = blockIdx.x * 256 + threadIdx.x;
    if (i >= 7680) return;
    int l = i / 10;
    int a = i - l * 10;
    float c0 = clsS[(a * 2 + 0) * 768 + l];
    float c1 = clsS[(a * 2 + 1) * 768 + l];
    cls2[i * 2] = c0;
    cls2[i * 2 + 1] = c1;
    float m = fmaxf(c0, c1);
    float e0 = expf(c0 - m), e1 = expf(c1 - m);
    scores[i] = e1 / (e0 + e1);
    float o0 = segS[(a * 2 + 0) * 768 + l];
    float o1 = segS[(a * 2 + 1) * 768 + l];
    off2[i * 2] = o0;
    off2[i * 2 + 1] = o1;
    float ah = c_anchors[a] * 0.5f;
    float ac = (float)l + 0.5f;
    float c = ac + o0 * (2.f * ah);
    float hl = ah * expf(o1);
    sArr[i] = fminf(fmaxf(c - hl, 0.f), 768.f);
    eArr[i] = fminf(fmaxf(c + hl, 0.f), 768.f);
}

// ---------------- full bitonic sort of 8192 keys, keep top 1024 ----------------
__global__ __launch_bounds__(1024) void sort_kernel(const float* __restrict__ scores,
                                                    const float* __restrict__ sArr, const float* __restrict__ eArr,
                                                    int* __restrict__ topI,
                                                    float* __restrict__ ss, float* __restrict__ ee) {
    __shared__ unsigned long long kk[8192];
    int tid = threadIdx.x;
#pragma unroll
    for (int m = 0; m < 8; m++) {
        int i = tid + m * 1024;
        unsigned long long key = 0ull;
        if (i < 7680) {
            unsigned int sb = __float_as_uint(scores[i]);
            key = ((unsigned long long)sb << 32) | (unsigned long long)(0xFFFFFFFFu - (unsigned)i);
        }
        kk[i] = key;
    }
    __syncthreads();
    for (int k = 2; k <= 8192; k <<= 1) {
        for (int j = k >> 1; j > 0; j >>= 1) {
#pragma unroll 1
            for (int m = 0; m < 8; m++) {
                int i = tid + m * 1024;
                int ixj = i ^ j;
                if (ixj > i) {
                    unsigned long long a = kk[i], b = kk[ixj];
                    bool descend = ((i & k) == 0);
                    if (descend ? (a < b) : (a > b)) { kk[i] = b; kk[ixj] = a; }
                }
            }
            __syncthreads();
        }
    }
    int idx = (int)(0xFFFFFFFFu - (unsigned int)(kk[tid] & 0xFFFFFFFFull));
    topI[tid] = idx;
    ss[tid] = sArr[idx];
    ee[tid] = eArr[idx];
}

// ---------------- NMS suppression bitmask ----------------
__global__ __launch_bounds__(256) void nms_mask_kernel(const float* __restrict__ ss, const float* __restrict__ ee,
                                                       unsigned long long* __restrict__ mask) {
    int g = blockIdx.x * 256 + threadIdx.x;
    int i = g >> 4, w = g & 15;
    float si = ss[i], ei = ee[i];
    unsigned long long bits = 0ull;
#pragma unroll 1
    for (int jj = 0; jj < 64; jj++) {
        int j = w * 64 + jj;
        if (j > i) {
            float sj = ss[j], ej = ee[j];
            float inter = fmaxf(0.f, fminf(ei, ej) - fmaxf(si, sj));
            float uni = (ej - sj) + (ei - si) - inter;
            float iou = inter / fmaxf(uni, 1e-8f);
            if (iou > 0.7f) bits |= (1ull << jj);
        }
    }
    mask[(size_t)i * 16 + w] = bits;
}

// ---------------- blocked NMS scan (single wave) + stable partition + gather ----------------
// Processes 16 blocks of 64 proposals. Intra-block: in-register shfl recurrence
// (suppressions only go forward, so bit i is final when iteration reaches i —
// identical semantics to the reference's keep[i]-gated fori_loop).
// Inter-block: butterfly-OR propagation of kept rows' later mask words.
__global__ __launch_bounds__(64) void nms_select_kernel(const unsigned long long* __restrict__ mask,
                                                        const int* __restrict__ topI,
                                                        const float* __restrict__ ss, const float* __restrict__ ee,
                                                        const float* __restrict__ cls2, const float* __restrict__ off2,
                                                        int* __restrict__ stA, int* __restrict__ enA,
                                                        float* __restrict__ out) {
    __shared__ unsigned long long remvS[16];
    __shared__ unsigned long long keepS[16];
    __shared__ int prefixS[17];
    int lane = threadIdx.x;
    if (lane < 16) remvS[lane] = 0ull;
    __syncthreads();
#pragma unroll 1
    for (int b = 0; b < 16; b++) {
        int row = b * 64 + lane;
        const unsigned long long* mrow = mask + (size_t)row * 16;
        unsigned long long diag = mrow[b];
        unsigned long long later[15];
        int nlater = 15 - b;
#pragma unroll 1
        for (int c = 0; c < nlater; c++) later[c] = mrow[b + 1 + c];
        unsigned long long rem = remvS[b];
#pragma unroll 1
        for (int i = 0; i < 64; i++) {
            unsigned long long di = __shfl(diag, i);
            if (!((rem >> i) & 1ull)) rem |= di;
        }
        unsigned long long keep64 = ~rem;
        bool mykeep = (keep64 >> lane) & 1ull;
#pragma unroll 1
        for (int c = 0; c < nlater; c++) {
            unsigned long long v = mykeep ? later[c] : 0ull;
            for (int sft = 1; sft < 64; sft <<= 1) v |= __shfl_xor(v, sft);
            if (lane == 0) remvS[b + 1 + c] |= v;
        }
        if (lane == 0) keepS[b] = keep64;
        __syncthreads();
    }
    // prefix of kept counts
    if (lane == 0) {
        int acc = 0;
        for (int b = 0; b < 16; b++) { prefixS[b] = acc; acc += __popcll(keepS[b]); }
        prefixS[16] = acc;
    }
    __syncthreads();
    int total = prefixS[16];
#pragma unroll 1
    for (int b = 0; b < 16; b++) {
        int tid = b * 64 + lane;
        unsigned long long keep64 = keepS[b];
        unsigned long long below = (lane == 0) ? 0ull : (keep64 << (64 - lane));
        int keptBefore = prefixS[b] + __popcll(below);
        int kp = (int)((keep64 >> lane) & 1ull);
        int pos = kp ? keptBefore : (total + tid - keptBefore);
        if (pos < 128) {
            int orig = topI[tid];
            float ps = ss[tid], pe = ee[tid];
            out[pos * 2 + 0] = cls2[orig * 2 + 0];
            out[pos * 2 + 1] = cls2[orig * 2 + 1];
            out[256 + pos * 2 + 0] = off2[orig * 2 + 0];
            out[256 + pos * 2 + 1] = off2[orig * 2 + 1];
            float bc = (ps + pe) * 0.5f, bh = (pe - ps) * 0.5f;
            int st = (int)fminf(fmaxf(floorf(bc - bh), 0.f), 767.f);
            int en = (int)fminf(fmaxf(ceilf(bc + bh), 0.f), 767.f);
            if (en < st) en = st;
            stA[pos] = st;
            enA[pos] = en;
        }
    }
}

// ---------------- ROI max pool ----------------
__global__ __launch_bounds__(256) void roi_kernel(const float* __restrict__ f,
                                                  const int* __restrict__ stA, const int* __restrict__ enA,
                                                  float* __restrict__ spp) {
    int n = blockIdx.x;
    int c = blockIdx.y * 256 + threadIdx.x;
    int st = stA[n], en = enA[n];
    int ln = en - st + 1;
    const float* row = f + (size_t)c * 768;
#pragma unroll 1
    for (int b = 0; b < 7; b++) {
        int bs = st + (b * ln) / 7;
        int be = st + ((b + 1) * ln + 6) / 7 - 1;
        float m = row[bs];
        for (int t = bs + 1; t <= be; t++) m = fmaxf(m, row[t]);
        spp[(size_t)c * 896 + n * 7 + b] = m;
    }
}

extern "C" void kernel_launch(void* const* d_in, const int* in_sizes, int n_in,
                              void* d_out, int out_size, void* d_ws, size_t ws_size,
                              hipStream_t stream) {
    const float* IN[39];
    for (int i = 0; i < 39; i++) IN[i] = (const float*)d_in[i];
    const float* feature = IN[0];
    const float *b1f = IN[1], *b2f = IN[2], *b3 = IN[3], *b4 = IN[4], *b5 = IN[5], *b6 = IN[6];
    const float *bc1 = IN[7], *bc2 = IN[8], *boxb = IN[9], *boxw = IN[10];
    const float *clsb = IN[11], *clsw = IN[12];
    const float *fc1b = IN[13], *fc1w = IN[14], *fc2b = IN[15], *fc2w = IN[16];
    const float *fc3b = IN[17], *fc3w = IN[18];
    const float *sp1b = IN[19], *sp1w = IN[20], *sp2b = IN[21], *sp2w = IN[22];
    const float *sp3b = IN[23], *sp3w = IN[24], *sp4b = IN[25], *sp4w = IN[26];
    const float *spcb = IN[27], *spcw = IN[28], *spsb = IN[29], *spsw = IN[30];
    const float *w1f = IN[31], *w2f = IN[32], *w3w = IN[33], *w4w = IN[34];
    const float *w5w = IN[35], *w6w = IN[36], *wc1 = IN[37], *wc2 = IN[38];
    float* out = (float*)d_out;

    char* base = (char*)d_ws;
    float* G    = (float*)base;
    float* part = (float*)base;
    float* spp  = (float*)(base + 14680064);
    float* yA   = (float*)(base + 22020096);
    float* yB   = (float*)(base + 23855104);
    float* g1   = (float*)(base + 25690112);
    float* g2   = (float*)(base + 25952256);
    float* g3   = (float*)(base + 26083328);
    size_t off = 26148864;
    auto alloc = [&](size_t bytes) { void* p = base + off; off += (bytes + 15) & ~((size_t)15); return p; };
    unsigned short* Xt = (unsigned short*)alloc((size_t)770 * 2048 * 2 * 2);
    float* fbuf = (float*)alloc((size_t)2048 * 768 * 4);
    float* xbuf = (float*)alloc((size_t)512 * 768 * 4);
    float* hB   = (float*)alloc((size_t)512 * 768 * 4);
    float* clsS = (float*)alloc((size_t)20 * 768 * 4);
    float* segS = (float*)alloc((size_t)20 * 768 * 4);
    float* cls2 = (float*)alloc(7680 * 2 * 4);
    float* off2 = (float*)alloc(7680 * 2 * 4);
    float* scores = (float*)alloc(7680 * 4);
    float* sArr = (float*)alloc(7680 * 4);
    float* eArr = (float*)alloc(7680 * 4);
    float* ssS  = (float*)alloc(1024 * 4);
    float* eeS  = (float*)alloc(1024 * 4);
    unsigned long long* mask = (unsigned long long*)alloc((size_t)16384 * 8);
    int* topI = (int*)alloc(1024 * 4);
    int* stA = (int*)alloc(128 * 4);
    int* enA = (int*)alloc(128 * 4);

    dim3 blk(256);
    dim3 blk512(512);

    // ---- conv1: feature -> Xt -> G -> Xt ----
    zeroXt_kernel<<<16, blk, 0, stream>>>(Xt, 2048);
    decomp_kernel<<<dim3(24, 64), blk, 0, stream>>>(feature, Xt, 2048);
    convmm_kernel<<<dim3(32, 6, 3), blk512, 0, stream>>>(w1f, Xt, G, 2048, 2048, 1);
    finsum_x_kernel<<<dim3(32, 12), blk, 0, stream>>>(G, b1f, Xt, 2048, 3);
    // ---- conv2: Xt -> G -> fbuf ----
    convmm_kernel<<<dim3(32, 6, 3), blk512, 0, stream>>>(w2f, Xt, G, 2048, 2048, 1);
    finsum_f_kernel<<<6144, blk, 0, stream>>>(G, b2f, fbuf, 2048, 3, 0);

    // ---- wc1 ----
    gemm_kernel<0, 0><<<dim3(8, 12, 8), blk, 0, stream>>>(wc1, fbuf, bc1, part, 512, 2048, 768, 768, 8, 0);
    finalize_kernel<<<1536, blk, 0, stream>>>(part, xbuf, bc1, 512, 512, 768, 8, 0);

    // ---- sp1..sp4 via MFMA ----
    zeroXt_kernel<<<4, blk, 0, stream>>>(Xt, 512);
    decomp_kernel<<<dim3(24, 16), blk, 0, stream>>>(xbuf, Xt, 512);
    convmm_kernel<<<dim3(8, 6, 12), blk512, 0, stream>>>(sp1w, Xt, G, 512, 512, 4);
    finsum_x_kernel<<<dim3(8, 12), blk, 0, stream>>>(G, sp1b, Xt, 512, 12);
    convmm_kernel<<<dim3(8, 6, 12), blk512, 0, stream>>>(sp2w, Xt, G, 512, 512, 4);
    finsum_x_kernel<<<dim3(8, 12), blk, 0, stream>>>(G, sp2b, Xt, 512, 12);
    convmm_kernel<<<dim3(8, 6, 12), blk512, 0, stream>>>(sp3w, Xt, G, 512, 512, 4);
    finsum_x_kernel<<<dim3(8, 12), blk, 0, stream>>>(G, sp3b, Xt, 512, 12);
    convmm_kernel<<<dim3(8, 6, 12), blk512, 0, stream>>>(sp4w, Xt, G, 512, 512, 4);
    finsum_f_kernel<<<1536, blk, 0, stream>>>(G, sp4b, hB, 512, 12, 1);  // relu

    // ---- heads ----
    gemm_kernel<0, 0><<<dim3(1, 12, 1), blk, 0, stream>>>(spcw, hB, spcb, clsS, 20, 512, 768, 768, 1, 0);
    gemm_kernel<0, 0><<<dim3(1, 12, 1), blk, 0, stream>>>(spsw, hB, spsb, segS, 20, 512, 768, 768, 1, 0);

    // ---- proposal decode / sort / NMS ----
    proposal_kernel<<<30, blk, 0, stream>>>(clsS, segS, cls2, off2, scores, sArr, eArr);
    sort_kernel<<<1, 1024, 0, stream>>>(scores, sArr, eArr, topI, ssS, eeS);
    nms_mask_kernel<<<64, blk, 0, stream>>>(ssS, eeS, mask);
    nms_select_kernel<<<1, 64, 0, stream>>>(mask, topI, ssS, eeS, cls2, off2, stA, enA, out);

    // ---- ROI pool ----
    roi_kernel<<<dim3(128, 8), blk, 0, stream>>>(fbuf, stA, enA, spp);

    // ---- classifier tower ----
    gemm_kernel<0, 0><<<dim3(8, 14, 8), blk, 0, stream>>>(wc2, spp, bc2, part, 512, 2048, 896, 896, 8, 0);
    finalize_kernel<<<1792, blk, 0, stream>>>(part, yA, bc2, 512, 512, 896, 8, 0);

    gemm_kernel<1, 0><<<dim3(8, 14, 8), blk, 0, stream>>>(w3w, yA, b3, part, 512, 1536, 896, 896, 8, 0);
    finalize_kernel<<<1792, blk, 0, stream>>>(part, yB, b3, 512, 512, 896, 8, 0);
    gemm_kernel<1, 0><<<dim3(8, 14, 8), blk, 0, stream>>>(w4w, yB, b4, part, 512, 1536, 896, 896, 8, 0);
    finalize_kernel<<<1792, blk, 0, stream>>>(part, yA, b4, 512, 512, 896, 8, 1);  // relu
    gemm_kernel<1, 0><<<dim3(8, 14, 8), blk, 0, stream>>>(w5w, yA, b5, part, 512, 1536, 896, 896, 8, 0);
    finalize_kernel<<<1792, blk, 0, stream>>>(part, yB, b5, 512, 512, 896, 8, 0);
    gemm_kernel<1, 0><<<dim3(8, 14, 8), blk, 0, stream>>>(w6w, yB, b6, part, 512, 1536, 896, 896, 8, 0);
    finalize_kernel<<<1792, blk, 0, stream>>>(part, yA, b6, 512, 512, 896, 8, 1);  // relu

    gemm_kernel<2, 0><<<dim3(8, 2, 28), blk, 0, stream>>>(fc1w, yA, fc1b, part, 512, 3584, 128, 128, 28, 0);
    finalize_kernel<<<256, blk, 0, stream>>>(part, g1, fc1b, 512, 512, 128, 28, 1);

    gemm_kernel<0, 0><<<dim3(4, 2, 4), blk, 0, stream>>>(fc2w, g1, fc2b, part, 256, 512, 128, 128, 4, 0);
    finalize_kernel<<<128, blk, 0, stream>>>(part, g2, fc2b, 256, 256, 128, 4, 0);
    gemm_kernel<0, 0><<<dim3(2, 2, 2), blk, 0, stream>>>(fc3w, g2, fc3b, part, 128, 256, 128, 128, 2, 0);
    finalize_kernel<<<64, blk, 0, stream>>>(part, g3, fc3b, 128, 128, 128, 2, 0);

    gemm_kernel<0, 1><<<dim3(1, 2, 1), blk, 0, stream>>>(clsw, g3, clsb, out, 21, 128, 128, 128, 1, 0);
    gemm_kernel<0, 2><<<dim3(1, 2, 1), blk, 0, stream>>>(boxw, g3, boxb, out, 40, 128, 128, 128, 1, 0);
}

// Round 5
// 1206.736 us; speedup vs baseline: 1.9261x; 1.1619x over previous
//
#include <hip/hip_runtime.h>

typedef __attribute__((ext_vector_type(8))) short short8;
typedef __attribute__((ext_vector_type(4))) float float4v;

__device__ __forceinline__ float bf(unsigned short u) {
    return __uint_as_float(((unsigned int)u) << 16);
}
__device__ __forceinline__ unsigned short f2b(float f) {
    unsigned int u = __float_as_uint(f);
    unsigned int r = (u + 0x7FFFu + ((u >> 16) & 1u)) >> 16;
    return (unsigned short)r;
}

__constant__ float c_anchors[10] = {2.f,4.f,5.f,6.f,8.f,9.f,10.f,12.f,14.f,16.f};

// ============ Xt helpers: transposed bf16 hi/lo slab [770][CI], planes h/l ============
__global__ __launch_bounds__(256) void zeroXt_kernel(unsigned short* __restrict__ Xt, int CI) {
    int i = blockIdx.x * 256 + threadIdx.x;
    if (i < 2 * CI) {
        int row = (i >= CI) ? 769 : 0;
        int co = (i >= CI) ? (i - CI) : i;
        Xt[(size_t)row * CI + co] = 0;
        Xt[(size_t)770 * CI + (size_t)row * CI + co] = 0;
    }
}

// src fp32 [CI][768] -> Xt rows 1..768 (row l+1 = X[:,l]), hi/lo planes
__global__ __launch_bounds__(256) void decomp_kernel(const float* __restrict__ src,
                                                     unsigned short* __restrict__ Xt, int CI) {
    __shared__ float T[32][33];
    int l0 = blockIdx.x * 32, ci0 = blockIdx.y * 32;
    int tid = threadIdx.x;
#pragma unroll
    for (int i = 0; i < 4; i++) {
        int slot = tid + 256 * i;
        int r = slot >> 5, c = slot & 31;
        T[r][c] = src[(size_t)(ci0 + r) * 768 + l0 + c];
    }
    __syncthreads();
    unsigned short* Xh = Xt;
    unsigned short* Xl = Xt + (size_t)770 * CI;
#pragma unroll
    for (int i = 0; i < 4; i++) {
        int slot = tid + 256 * i;
        int li = slot >> 5, cc = slot & 31;
        float v = T[cc][li];
        unsigned short h = f2b(v);
        float lo = v - bf(h);
        size_t o = (size_t)(l0 + li + 1) * CI + ci0 + cc;
        Xh[o] = h;
        Xl[o] = f2b(lo);
    }
}

// ============ merged-tap MFMA conv-as-GEMM ============
// TAPS=3: W fp32 [CO][CI][3], G[s][co][l] = sum_{ci in slice} sum_t W_t X[ci][l+t-1]
// TAPS=1: W fp32 [CO][CI]   (1x1 conv / plain GEMM vs slab)
// grid (CO/64, 768/128, S), 512 threads / 8 waves, wave tile 32x32 (2x2 of 16x16x32)
template <int TAPS>
__global__ __launch_bounds__(512, 6) void convmm_kernel(const float* __restrict__ W,
                                                        const unsigned short* __restrict__ Xt,
                                                        float* __restrict__ G,
                                                        int CO, int CI, int S) {
    constexpr int RS = TAPS * 32 + 8;
    __shared__ unsigned short At[2][64 * RS];
    __shared__ unsigned short Bt[2][130 * 40];
    int tid = threadIdx.x;
    int lane = tid & 63, wid = tid >> 6;
    int q = lane >> 4, ln = lane & 15;
    int co0 = blockIdx.x * 64;
    int l0 = blockIdx.y * 128;
    int s = blockIdx.z;
    int kPer = CI / S, cis = s * kPer;
    const unsigned short* Xh = Xt;
    const unsigned short* Xl = Xt + (size_t)770 * CI;

    float4v zero4 = {0.f, 0.f, 0.f, 0.f};
    float4v acc[2][2];
    acc[0][0] = zero4; acc[0][1] = zero4; acc[1][0] = zero4; acc[1][1] = zero4;

    int wave_m = (wid >> 2) * 32;
    int wave_n = (wid & 3) * 32;

    for (int kb = 0; kb < kPer; kb += 32) {
        int cib = cis + kb;
        if (TAPS == 3) {
            // 1024 ci-pair slots: each loads 6 consecutive floats (2 ci x 3 taps)
#pragma unroll
            for (int i = 0; i < 2; i++) {
                int slot = tid + 512 * i;
                int row = slot >> 4, ci0 = (slot & 15) * 2;
                const float* wp = W + ((size_t)(co0 + row) * CI + cib + ci0) * 3;
                float fa[6];
#pragma unroll
                for (int j = 0; j < 6; j++) fa[j] = wp[j];
#pragma unroll
                for (int t = 0; t < 3; t++) {
                    unsigned short h0 = f2b(fa[t]);
                    unsigned short h1 = f2b(fa[t + 3]);
                    unsigned short e0 = f2b(fa[t] - bf(h0));
                    unsigned short e1 = f2b(fa[t + 3] - bf(h1));
                    *(unsigned int*)&At[0][row * RS + t * 32 + ci0] =
                        (unsigned int)h0 | ((unsigned int)h1 << 16);
                    *(unsigned int*)&At[1][row * RS + t * 32 + ci0] =
                        (unsigned int)e0 | ((unsigned int)e1 << 16);
                }
            }
        } else {
            // 512 float4 slots (64 rows x 8 quads)
            int row = tid >> 3, ci0 = (tid & 7) * 4;
            float4 wv = *(const float4*)(W + (size_t)(co0 + row) * CI + cib + ci0);
            float fa[4] = {wv.x, wv.y, wv.z, wv.w};
            unsigned short h[4], e[4];
#pragma unroll
            for (int j = 0; j < 4; j++) {
                h[j] = f2b(fa[j]);
                e[j] = f2b(fa[j] - bf(h[j]));
            }
            unsigned long long hp = (unsigned long long)h[0] | ((unsigned long long)h[1] << 16) |
                                    ((unsigned long long)h[2] << 32) | ((unsigned long long)h[3] << 48);
            unsigned long long ep = (unsigned long long)e[0] | ((unsigned long long)e[1] << 16) |
                                    ((unsigned long long)e[2] << 32) | ((unsigned long long)e[3] << 48);
            *(unsigned long long*)&At[0][row * RS + ci0] = hp;
            *(unsigned long long*)&At[1][row * RS + ci0] = ep;
        }
        // B slab: rows l0..l0+129, 32 ci, both planes, 16B chunks
#pragma unroll
        for (int i = 0; i < 3; i++) {
            int slot = tid + 512 * i;
            if (slot < 1040) {
                int p = slot >= 520 ? 1 : 0;
                int rem = slot - p * 520;
                int r = rem >> 2, qq = rem & 3;
                const unsigned short* src = (p ? Xl : Xh) + (size_t)(l0 + r) * CI + cib + qq * 8;
                short8 v = *(const short8*)src;
                *(short8*)&Bt[p][r * 40 + qq * 8] = v;
            }
        }
        __syncthreads();
#pragma unroll
        for (int t = 0; t < TAPS; t++) {
            int shift = (TAPS == 1) ? 1 : t;
            short8 bh[2], bl[2];
#pragma unroll
            for (int nf = 0; nf < 2; nf++) {
                int rrow = wave_n + nf * 16 + ln + shift;
                bh[nf] = *(const short8*)&Bt[0][rrow * 40 + q * 8];
                bl[nf] = *(const short8*)&Bt[1][rrow * 40 + q * 8];
            }
#pragma unroll
            for (int mf = 0; mf < 2; mf++) {
                int mrow = wave_m + mf * 16 + ln;
                short8 ah = *(const short8*)&At[0][mrow * RS + t * 32 + q * 8];
                short8 al = *(const short8*)&At[1][mrow * RS + t * 32 + q * 8];
#pragma unroll
                for (int nf = 0; nf < 2; nf++) {
                    acc[mf][nf] = __builtin_amdgcn_mfma_f32_16x16x32_bf16(ah, bh[nf], acc[mf][nf], 0, 0, 0);
                    acc[mf][nf] = __builtin_amdgcn_mfma_f32_16x16x32_bf16(ah, bl[nf], acc[mf][nf], 0, 0, 0);
                    acc[mf][nf] = __builtin_amdgcn_mfma_f32_16x16x32_bf16(al, bh[nf], acc[mf][nf], 0, 0, 0);
                }
            }
        }
        __syncthreads();
    }
    float* Gz = G + (size_t)s * CO * 768;
#pragma unroll
    for (int mf = 0; mf < 2; mf++)
#pragma unroll
        for (int nf = 0; nf < 2; nf++) {
            int col = l0 + wave_n + nf * 16 + ln;
            int rowb = co0 + wave_m + mf * 16 + q * 4;
#pragma unroll
            for (int r = 0; r < 4; r++)
                Gz[(size_t)(rowb + r) * 768 + col] = acc[mf][nf][r];
        }
}

// finalize: sum P planes + bias -> transposed bf16 hi/lo Xt (rows 1..768)
__global__ __launch_bounds__(256) void finsum_x_kernel(const float* __restrict__ G,
                                                       const float* __restrict__ bias,
                                                       unsigned short* __restrict__ Xt,
                                                       int CO, int P) {
    __shared__ float T[64][65];
    int co0 = blockIdx.x * 64, l0 = blockIdx.y * 64;
    int tid = threadIdx.x;
#pragma unroll 1
    for (int i = 0; i < 16; i++) {
        int slot = tid + 256 * i;
        int r = slot >> 6, c = slot & 63;
        float v = bias[co0 + r];
        for (int p = 0; p < P; p++) v += G[((size_t)p * CO + co0 + r) * 768 + l0 + c];
        T[r][c] = v;
    }
    __syncthreads();
    unsigned short* Xh = Xt;
    unsigned short* Xl = Xt + (size_t)770 * CO;
#pragma unroll 1
    for (int i = 0; i < 16; i++) {
        int slot = tid + 256 * i;
        int li = slot >> 6, ci = slot & 63;
        float v = T[ci][li];
        unsigned short h = f2b(v);
        float lo = v - bf(h);
        size_t o = (size_t)(l0 + li + 1) * CO + co0 + ci;
        Xh[o] = h;
        Xl[o] = f2b(lo);
    }
}

// finalize: sum P planes + bias -> Xt slab AND fp32 [CO][768]
__global__ __launch_bounds__(256) void finsum_xf_kernel(const float* __restrict__ G,
                                                        const float* __restrict__ bias,
                                                        unsigned short* __restrict__ Xt,
                                                        float* __restrict__ outF,
                                                        int CO, int P) {
    __shared__ float T[64][65];
    int co0 = blockIdx.x * 64, l0 = blockIdx.y * 64;
    int tid = threadIdx.x;
#pragma unroll 1
    for (int i = 0; i < 16; i++) {
        int slot = tid + 256 * i;
        int r = slot >> 6, c = slot & 63;
        float v = bias[co0 + r];
        for (int p = 0; p < P; p++) v += G[((size_t)p * CO + co0 + r) * 768 + l0 + c];
        T[r][c] = v;
        outF[(size_t)(co0 + r) * 768 + l0 + c] = v;
    }
    __syncthreads();
    unsigned short* Xh = Xt;
    unsigned short* Xl = Xt + (size_t)770 * CO;
#pragma unroll 1
    for (int i = 0; i < 16; i++) {
        int slot = tid + 256 * i;
        int li = slot >> 6, ci = slot & 63;
        float v = T[ci][li];
        unsigned short h = f2b(v);
        float lo = v - bf(h);
        size_t o = (size_t)(l0 + li + 1) * CO + co0 + ci;
        Xh[o] = h;
        Xl[o] = f2b(lo);
    }
}

// finalize: sum P planes + bias (+relu) -> fp32 [CO][768]
__global__ __launch_bounds__(256) void finsum_f_kernel(const float* __restrict__ G,
                                                       const float* __restrict__ bias,
                                                       float* __restrict__ out,
                                                       int CO, int P, int relu) {
    int i = blockIdx.x * 256 + threadIdx.x;
    if (i >= CO * 768) return;
    int r = i / 768, c = i - r * 768;
    float v = bias[r];
    for (int p = 0; p < P; p++) v += G[((size_t)p * CO + r) * 768 + c];
    if (relu) v = fmaxf(v, 0.f);
    out[i] = v;
}

// ---------------- finalize for fp32 split-K gemm path ----------------
__global__ __launch_bounds__(256) void finalize_kernel(const float* __restrict__ part,
                                                       float* __restrict__ out,
                                                       const float* __restrict__ bias,
                                                       int RPAD, int R, int NCOLS, int S, int relu) {
    int i = blockIdx.x * 256 + threadIdx.x;
    int total = R * NCOLS;
    if (i >= total) return;
    int r = i / NCOLS;
    int c = i - r * NCOLS;
    float v = 0.f;
    for (int s = 0; s < S; s++) v += part[((size_t)s * RPAD + r) * NCOLS + c];
    v += bias[r];
    if (relu) v = fmaxf(v, 0.f);
    out[i] = v;
}

// ---------------- fp32 gather-GEMM ----------------
template <int MODE, int EPI>
__global__ __launch_bounds__(256) void gemm_kernel(const float* __restrict__ W,
                                                   const float* __restrict__ B,
                                                   const float* __restrict__ bias,
                                                   float* __restrict__ outF,
                                                   int R, int K, int NCOLS, int LDB, int S, int relu) {
    __shared__ __align__(16) float Bt[16][68];
    __shared__ __align__(16) float Wt[16][68];
    int tid = threadIdx.x;
    int tx = tid & 15, ty = tid >> 4;
    int r0 = blockIdx.x * 64, c0 = blockIdx.y * 64, s = blockIdx.z;
    int kPer = K / S;
    int k0s = s * kPer;
    float acc[4][4] = {};
    for (int kb = 0; kb < kPer; kb += 16) {
        int k0 = k0s + kb;
        {
            int rr = r0 + (tid >> 2);
            int q = tid & 3;
            float4 wv4 = {0.f, 0.f, 0.f, 0.f};
            if (rr < R) wv4 = *(const float4*)(W + (size_t)rr * K + k0 + q * 4);
            Wt[q * 4 + 0][tid >> 2] = wv4.x;
            Wt[q * 4 + 1][tid >> 2] = wv4.y;
            Wt[q * 4 + 2][tid >> 2] = wv4.z;
            Wt[q * 4 + 3][tid >> 2] = wv4.w;
        }
#pragma unroll
        for (int p = 0; p < 4; p++) {
            int kk = p * 4 + (tid >> 6);
            int c = tid & 63;
            int k = k0 + kk;
            int col = c0 + c;
            float v;
            if (MODE == 0) {
                v = B[(size_t)k * LDB + col];
            } else if (MODE == 1) {
                int ci = k / 3;
                int t = k - ci * 3;
                int lc = (col % 7) + t - 1;
                v = ((unsigned)lc < 7u) ? B[(size_t)ci * 896 + col + t - 1] : 0.f;
            } else {
                int co = k / 7;
                int b7 = k - co * 7;
                v = B[(size_t)co * 896 + col * 7 + b7];
            }
            Bt[kk][c] = v;
        }
        __syncthreads();
#pragma unroll
        for (int kk = 0; kk < 16; kk++) {
            float4 bv = *(const float4*)&Bt[kk][tx * 4];
            float4 wv = *(const float4*)&Wt[kk][ty * 4];
            float bb[4] = {bv.x, bv.y, bv.z, bv.w};
            float ww[4] = {wv.x, wv.y, wv.z, wv.w};
#pragma unroll
            for (int i = 0; i < 4; i++)
#pragma unroll
                for (int j = 0; j < 4; j++)
                    acc[i][j] = fmaf(ww[i], bb[j], acc[i][j]);
        }
        __syncthreads();
    }
    if (EPI == 0) {
        if (S > 1) {
#pragma unroll
            for (int i = 0; i < 4; i++) {
                int r = r0 + ty * 4 + i;
                float4 o = {acc[i][0], acc[i][1], acc[i][2], acc[i][3]};
                *(float4*)&outF[((size_t)s * R + r) * NCOLS + c0 + tx * 4] = o;
            }
        } else {
#pragma unroll
            for (int i = 0; i < 4; i++) {
                int r = r0 + ty * 4 + i;
                if (r < R) {
                    float bv = bias[r];
#pragma unroll
                    for (int j = 0; j < 4; j++) {
                        float v = acc[i][j] + bv;
                        if (relu) v = fmaxf(v, 0.f);
                        outF[(size_t)r * NCOLS + c0 + tx * 4 + j] = v;
                    }
                }
            }
        }
    } else {
#pragma unroll
        for (int i = 0; i < 4; i++) {
            int r = r0 + ty * 4 + i;
            if (r < R) {
                float bv = bias[r];
#pragma unroll
                for (int j = 0; j < 4; j++) {
                    int col = c0 + tx * 4 + j;
                    float v = acc[i][j] + bv;
                    if (EPI == 1) outF[512 + col * 21 + r] = v;
                    else outF[3200 + col * 40 + r] = v;
                }
            }
        }
    }
}

// ---------------- proposals: softmax, anchor decode ----------------
__global__ __launch_bounds__(256) void proposal_kernel(const float* __restrict__ clsS,
                                                       const float* __restrict__ segS,
                                                       float* __restrict__ cls2, float* __restrict__ off2,
                                                       float* __restrict__ scores,
                                                       float* __restrict__ sArr, float* __restrict__ eArr) {
    int i = blockIdx.x * 256 + threadIdx.x;
    if (i >= 7680) return;
    int l = i / 10;
    int a = i - l * 10;
    float c0 = clsS[(a * 2 + 0) * 768 + l];
    float c1 = clsS[(a * 2 + 1) * 768 + l];
    cls2[i * 2] = c0;
    cls2[i * 2 + 1] = c1;
    float m = fmaxf(c0, c1);
    float e0 = expf(c0 - m), e1 = expf(c1 - m);
    scores[i] = e1 / (e0 + e1);
    float o0 = segS[(a * 2 + 0) * 768 + l];
    float o1 = segS[(a * 2 + 1) * 768 + l];
    off2[i * 2] = o0;
    off2[i * 2 + 1] = o1;
    float ah = c_anchors[a] * 0.5f;
    float ac = (float)l + 0.5f;
    float c = ac + o0 * (2.f * ah);
    float hl = ah * expf(o1);
    sArr[i] = fminf(fmaxf(c - hl, 0.f), 768.f);
    eArr[i] = fminf(fmaxf(c + hl, 0.f), 768.f);
}

// ---------------- full bitonic sort of 8192 keys, keep top 1024 ----------------
__global__ __launch_bounds__(1024) void sort_kernel(const float* __restrict__ scores,
                                                    const float* __restrict__ sArr, const float* __restrict__ eArr,
                                                    int* __restrict__ topI,
                                                    float* __restrict__ ss, float* __restrict__ ee) {
    __shared__ unsigned long long kk[8192];
    int tid = threadIdx.x;
#pragma unroll
    for (int m = 0; m < 8; m++) {
        int i = tid + m * 1024;
        unsigned long long key = 0ull;
        if (i < 7680) {
            unsigned int sb = __float_as_uint(scores[i]);
            key = ((unsigned long long)sb << 32) | (unsigned long long)(0xFFFFFFFFu - (unsigned)i);
        }
        kk[i] = key;
    }
    __syncthreads();
    for (int k = 2; k <= 8192; k <<= 1) {
        for (int j = k >> 1; j > 0; j >>= 1) {
#pragma unroll 1
            for (int m = 0; m < 8; m++) {
                int i = tid + m * 1024;
                int ixj = i ^ j;
                if (ixj > i) {
                    unsigned long long a = kk[i], b = kk[ixj];
                    bool descend = ((i & k) == 0);
                    if (descend ? (a < b) : (a > b)) { kk[i] = b; kk[ixj] = a; }
                }
            }
            __syncthreads();
        }
    }
    int idx = (int)(0xFFFFFFFFu - (unsigned int)(kk[tid] & 0xFFFFFFFFull));
    topI[tid] = idx;
    ss[tid] = sArr[idx];
    ee[tid] = eArr[idx];
}

// ---------------- NMS suppression bitmask ----------------
__global__ __launch_bounds__(256) void nms_mask_kernel(const float* __restrict__ ss, const float* __restrict__ ee,
                                                       unsigned long long* __restrict__ mask) {
    int g = blockIdx.x * 256 + threadIdx.x;
    int i = g >> 4, w = g & 15;
    float si = ss[i], ei = ee[i];
    unsigned long long bits = 0ull;
#pragma unroll 1
    for (int jj = 0; jj < 64; jj++) {
        int j = w * 64 + jj;
        if (j > i) {
            float sj = ss[j], ej = ee[j];
            float inter = fmaxf(0.f, fminf(ei, ej) - fmaxf(si, sj));
            float uni = (ej - sj) + (ei - si) - inter;
            float iou = inter / fmaxf(uni, 1e-8f);
            if (iou > 0.7f) bits |= (1ull << jj);
        }
    }
    mask[(size_t)i * 16 + w] = bits;
}

// ---------------- blocked NMS scan (single wave) + stable partition + gather ----------------
__global__ __launch_bounds__(64) void nms_select_kernel(const unsigned long long* __restrict__ mask,
                                                        const int* __restrict__ topI,
                                                        const float* __restrict__ ss, const float* __restrict__ ee,
                                                        const float* __restrict__ cls2, const float* __restrict__ off2,
                                                        int* __restrict__ stA, int* __restrict__ enA,
                                                        float* __restrict__ out) {
    __shared__ unsigned long long remvS[16];
    __shared__ unsigned long long keepS[16];
    __shared__ int prefixS[17];
    int lane = threadIdx.x;
    if (lane < 16) remvS[lane] = 0ull;
    __syncthreads();
#pragma unroll 1
    for (int b = 0; b < 16; b++) {
        int row = b * 64 + lane;
        const unsigned long long* mrow = mask + (size_t)row * 16;
        unsigned long long diag = mrow[b];
        unsigned long long later[15];
        int nlater = 15 - b;
#pragma unroll 1
        for (int c = 0; c < nlater; c++) later[c] = mrow[b + 1 + c];
        unsigned long long rem = remvS[b];
#pragma unroll 1
        for (int i = 0; i < 64; i++) {
            unsigned long long di = __shfl(diag, i);
            if (!((rem >> i) & 1ull)) rem |= di;
        }
        unsigned long long keep64 = ~rem;
        bool mykeep = (keep64 >> lane) & 1ull;
#pragma unroll 1
        for (int c = 0; c < nlater; c++) {
            unsigned long long v = mykeep ? later[c] : 0ull;
            for (int sft = 1; sft < 64; sft <<= 1) v |= __shfl_xor(v, sft);
            if (lane == 0) remvS[b + 1 + c] |= v;
        }
        if (lane == 0) keepS[b] = keep64;
        __syncthreads();
    }
    if (lane == 0) {
        int acc = 0;
        for (int b = 0; b < 16; b++) { prefixS[b] = acc; acc += __popcll(keepS[b]); }
        prefixS[16] = acc;
    }
    __syncthreads();
    int total = prefixS[16];
#pragma unroll 1
    for (int b = 0; b < 16; b++) {
        int tid = b * 64 + lane;
        unsigned long long keep64 = keepS[b];
        unsigned long long below = (lane == 0) ? 0ull : (keep64 << (64 - lane));
        int keptBefore = prefixS[b] + __popcll(below);
        int kp = (int)((keep64 >> lane) & 1ull);
        int pos = kp ? keptBefore : (total + tid - keptBefore);
        if (pos < 128) {
            int orig = topI[tid];
            float ps = ss[tid], pe = ee[tid];
            out[pos * 2 + 0] = cls2[orig * 2 + 0];
            out[pos * 2 + 1] = cls2[orig * 2 + 1];
            out[256 + pos * 2 + 0] = off2[orig * 2 + 0];
            out[256 + pos * 2 + 1] = off2[orig * 2 + 1];
            float bc = (ps + pe) * 0.5f, bh = (pe - ps) * 0.5f;
            int st = (int)fminf(fmaxf(floorf(bc - bh), 0.f), 767.f);
            int en = (int)fminf(fmaxf(ceilf(bc + bh), 0.f), 767.f);
            if (en < st) en = st;
            stA[pos] = st;
            enA[pos] = en;
        }
    }
}

// ---------------- ROI max pool ----------------
__global__ __launch_bounds__(256) void roi_kernel(const float* __restrict__ f,
                                                  const int* __restrict__ stA, const int* __restrict__ enA,
                                                  float* __restrict__ spp) {
    int n = blockIdx.x;
    int c = blockIdx.y * 256 + threadIdx.x;
    int st = stA[n], en = enA[n];
    int ln = en - st + 1;
    const float* row = f + (size_t)c * 768;
#pragma unroll 1
    for (int b = 0; b < 7; b++) {
        int bs = st + (b * ln) / 7;
        int be = st + ((b + 1) * ln + 6) / 7 - 1;
        float m = row[bs];
        for (int t = bs + 1; t <= be; t++) m = fmaxf(m, row[t]);
        spp[(size_t)c * 896 + n * 7 + b] = m;
    }
}

extern "C" void kernel_launch(void* const* d_in, const int* in_sizes, int n_in,
                              void* d_out, int out_size, void* d_ws, size_t ws_size,
                              hipStream_t stream) {
    const float* IN[39];
    for (int i = 0; i < 39; i++) IN[i] = (const float*)d_in[i];
    const float* feature = IN[0];
    const float *b1f = IN[1], *b2f = IN[2], *b3 = IN[3], *b4 = IN[4], *b5 = IN[5], *b6 = IN[6];
    const float *bc1 = IN[7], *bc2 = IN[8], *boxb = IN[9], *boxw = IN[10];
    const float *clsb = IN[11], *clsw = IN[12];
    const float *fc1b = IN[13], *fc1w = IN[14], *fc2b = IN[15], *fc2w = IN[16];
    const float *fc3b = IN[17], *fc3w = IN[18];
    const float *sp1b = IN[19], *sp1w = IN[20], *sp2b = IN[21], *sp2w = IN[22];
    const float *sp3b = IN[23], *sp3w = IN[24], *sp4b = IN[25], *sp4w = IN[26];
    const float *spcb = IN[27], *spcw = IN[28], *spsb = IN[29], *spsw = IN[30];
    const float *w1f = IN[31], *w2f = IN[32], *w3w = IN[33], *w4w = IN[34];
    const float *w5w = IN[35], *w6w = IN[36], *wc1 = IN[37], *wc2 = IN[38];
    float* out = (float*)d_out;

    char* base = (char*)d_ws;
    float* G    = (float*)base;            // up to 25.2 MB during conv phase (dead before spp/yA/yB writes)
    float* part = (float*)base;            // tower split-K partials (post-ROI)
    float* spp  = (float*)(base + 14680064);
    float* yA   = (float*)(base + 22020096);
    float* yB   = (float*)(base + 23855104);
    float* g1   = (float*)(base + 25690112);
    float* g2   = (float*)(base + 25952256);
    float* g3   = (float*)(base + 26083328);
    size_t off = 26148864;
    auto alloc = [&](size_t bytes) { void* p = base + off; off += (bytes + 15) & ~((size_t)15); return p; };
    unsigned short* Xt = (unsigned short*)alloc((size_t)770 * 2048 * 2 * 2);
    float* fbuf = (float*)alloc((size_t)2048 * 768 * 4);
    float* hB   = (float*)alloc((size_t)512 * 768 * 4);
    float* clsS = (float*)alloc((size_t)20 * 768 * 4);
    float* segS = (float*)alloc((size_t)20 * 768 * 4);
    float* cls2 = (float*)alloc(7680 * 2 * 4);
    float* off2 = (float*)alloc(7680 * 2 * 4);
    float* scores = (float*)alloc(7680 * 4);
    float* sArr = (float*)alloc(7680 * 4);
    float* eArr = (float*)alloc(7680 * 4);
    float* ssS  = (float*)alloc(1024 * 4);
    float* eeS  = (float*)alloc(1024 * 4);
    unsigned long long* mask = (unsigned long long*)alloc((size_t)16384 * 8);
    int* topI = (int*)alloc(1024 * 4);
    int* stA = (int*)alloc(128 * 4);
    int* enA = (int*)alloc(128 * 4);

    dim3 blk(256);
    dim3 blk512(512);

    // ---- conv1: feature -> slab -> G -> slab ----
    zeroXt_kernel<<<16, blk, 0, stream>>>(Xt, 2048);
    decomp_kernel<<<dim3(24, 64), blk, 0, stream>>>(feature, Xt, 2048);
    convmm_kernel<3><<<dim3(32, 6, 4), blk512, 0, stream>>>(w1f, Xt, G, 2048, 2048, 4);
    finsum_x_kernel<<<dim3(32, 12), blk, 0, stream>>>(G, b1f, Xt, 2048, 4);
    // ---- conv2: slab -> G -> fbuf (fp32) + slab ----
    convmm_kernel<3><<<dim3(32, 6, 4), blk512, 0, stream>>>(w2f, Xt, G, 2048, 2048, 4);
    finsum_xf_kernel<<<dim3(32, 12), blk, 0, stream>>>(G, b2f, Xt, fbuf, 2048, 4);

    // ---- wc1 via MFMA (TAPS=1 on conv2 slab) -> 512-slab ----
    convmm_kernel<1><<<dim3(8, 6, 8), blk512, 0, stream>>>(wc1, Xt, G, 512, 2048, 8);
    zeroXt_kernel<<<4, blk, 0, stream>>>(Xt, 512);
    finsum_x_kernel<<<dim3(8, 12), blk, 0, stream>>>(G, bc1, Xt, 512, 8);

    // ---- sp1..sp4 via MFMA ----
    convmm_kernel<3><<<dim3(8, 6, 8), blk512, 0, stream>>>(sp1w, Xt, G, 512, 512, 8);
    finsum_x_kernel<<<dim3(8, 12), blk, 0, stream>>>(G, sp1b, Xt, 512, 8);
    convmm_kernel<3><<<dim3(8, 6, 8), blk512, 0, stream>>>(sp2w, Xt, G, 512, 512, 8);
    finsum_x_kernel<<<dim3(8, 12), blk, 0, stream>>>(G, sp2b, Xt, 512, 8);
    convmm_kernel<3><<<dim3(8, 6, 8), blk512, 0, stream>>>(sp3w, Xt, G, 512, 512, 8);
    finsum_x_kernel<<<dim3(8, 12), blk, 0, stream>>>(G, sp3b, Xt, 512, 8);
    convmm_kernel<3><<<dim3(8, 6, 8), blk512, 0, stream>>>(sp4w, Xt, G, 512, 512, 8);
    finsum_f_kernel<<<1536, blk, 0, stream>>>(G, sp4b, hB, 512, 8, 1);  // relu

    // ---- heads ----
    gemm_kernel<0, 0><<<dim3(1, 12, 1), blk, 0, stream>>>(spcw, hB, spcb, clsS, 20, 512, 768, 768, 1, 0);
    gemm_kernel<0, 0><<<dim3(1, 12, 1), blk, 0, stream>>>(spsw, hB, spsb, segS, 20, 512, 768, 768, 1, 0);

    // ---- proposal decode / sort / NMS ----
    proposal_kernel<<<30, blk, 0, stream>>>(clsS, segS, cls2, off2, scores, sArr, eArr);
    sort_kernel<<<1, 1024, 0, stream>>>(scores, sArr, eArr, topI, ssS, eeS);
    nms_mask_kernel<<<64, blk, 0, stream>>>(ssS, eeS, mask);
    nms_select_kernel<<<1, 64, 0, stream>>>(mask, topI, ssS, eeS, cls2, off2, stA, enA, out);

    // ---- ROI pool ----
    roi_kernel<<<dim3(128, 8), blk, 0, stream>>>(fbuf, stA, enA, spp);

    // ---- classifier tower (fp32 path) ----
    gemm_kernel<0, 0><<<dim3(8, 14, 8), blk, 0, stream>>>(wc2, spp, bc2, part, 512, 2048, 896, 896, 8, 0);
    finalize_kernel<<<1792, blk, 0, stream>>>(part, yA, bc2, 512, 512, 896, 8, 0);

    gemm_kernel<1, 0><<<dim3(8, 14, 8), blk, 0, stream>>>(w3w, yA, b3, part, 512, 1536, 896, 896, 8, 0);
    finalize_kernel<<<1792, blk, 0, stream>>>(part, yB, b3, 512, 512, 896, 8, 0);
    gemm_kernel<1, 0><<<dim3(8, 14, 8), blk, 0, stream>>>(w4w, yB, b4, part, 512, 1536, 896, 896, 8, 0);
    finalize_kernel<<<1792, blk, 0, stream>>>(part, yA, b4, 512, 512, 896, 8, 1);  // relu
    gemm_kernel<1, 0><<<dim3(8, 14, 8), blk, 0, stream>>>(w5w, yA, b5, part, 512, 1536, 896, 896, 8, 0);
    finalize_kernel<<<1792, blk, 0, stream>>>(part, yB, b5, 512, 512, 896, 8, 0);
    gemm_kernel<1, 0><<<dim3(8, 14, 8), blk, 0, stream>>>(w6w, yB, b6, part, 512, 1536, 896, 896, 8, 0);
    finalize_kernel<<<1792, blk, 0, stream>>>(part, yA, b6, 512, 512, 896, 8, 1);  // relu

    gemm_kernel<2, 0><<<dim3(8, 2, 28), blk, 0, stream>>>(fc1w, yA, fc1b, part, 512, 3584, 128, 128, 28, 0);
    finalize_kernel<<<256, blk, 0, stream>>>(part, g1, fc1b, 512, 512, 128, 28, 1);

    gemm_kernel<0, 0><<<dim3(4, 2, 4), blk, 0, stream>>>(fc2w, g1, fc2b, part, 256, 512, 128, 128, 4, 0);
    finalize_kernel<<<128, blk, 0, stream>>>(part, g2, fc2b, 256, 256, 128, 4, 0);
    gemm_kernel<0, 0><<<dim3(2, 2, 2), blk, 0, stream>>>(fc3w, g2, fc3b, part, 128, 256, 128, 128, 2, 0);
    finalize_kernel<<<64, blk, 0, stream>>>(part, g3, fc3b, 128, 128, 128, 2, 0);

    gemm_kernel<0, 1><<<dim3(1, 2, 1), blk, 0, stream>>>(clsw, g3, clsb, out, 21, 128, 128, 128, 1, 0);
    gemm_kernel<0, 2><<<dim3(1, 2, 1), blk, 0, stream>>>(boxw, g3, boxb, out, 40, 128, 128, 128, 1, 0);
}

// Round 6
// 1111.399 us; speedup vs baseline: 2.0913x; 1.0858x over previous
//
#include <hip/hip_runtime.h>

typedef __attribute__((ext_vector_type(8))) short short8;
typedef __attribute__((ext_vector_type(4))) float float4v;

__device__ __forceinline__ float bf(unsigned short u) {
    return __uint_as_float(((unsigned int)u) << 16);
}
__device__ __forceinline__ unsigned short f2b(float f) {
    unsigned int u = __float_as_uint(f);
    unsigned int r = (u + 0x7FFFu + ((u >> 16) & 1u)) >> 16;
    return (unsigned short)r;
}

__constant__ float c_anchors[10] = {2.f,4.f,5.f,6.f,8.f,9.f,10.f,12.f,14.f,16.f};

// ============ Xt helpers: transposed bf16 hi/lo slab [770][CI], planes h/l ============
__global__ __launch_bounds__(256) void zeroXt_kernel(unsigned short* __restrict__ Xt, int CI) {
    int i = blockIdx.x * 256 + threadIdx.x;
    if (i < 2 * CI) {
        int row = (i >= CI) ? 769 : 0;
        int co = (i >= CI) ? (i - CI) : i;
        Xt[(size_t)row * CI + co] = 0;
        Xt[(size_t)770 * CI + (size_t)row * CI + co] = 0;
    }
}

// src fp32 [CI][768] -> Xt rows 1..768 (row l+1 = X[:,l]), hi/lo planes
__global__ __launch_bounds__(256) void decomp_kernel(const float* __restrict__ src,
                                                     unsigned short* __restrict__ Xt, int CI) {
    __shared__ float T[32][33];
    int l0 = blockIdx.x * 32, ci0 = blockIdx.y * 32;
    int tid = threadIdx.x;
#pragma unroll
    for (int i = 0; i < 4; i++) {
        int slot = tid + 256 * i;
        int r = slot >> 5, c = slot & 31;
        T[r][c] = src[(size_t)(ci0 + r) * 768 + l0 + c];
    }
    __syncthreads();
    unsigned short* Xh = Xt;
    unsigned short* Xl = Xt + (size_t)770 * CI;
#pragma unroll
    for (int i = 0; i < 4; i++) {
        int slot = tid + 256 * i;
        int li = slot >> 5, cc = slot & 31;
        float v = T[cc][li];
        unsigned short h = f2b(v);
        float lo = v - bf(h);
        size_t o = (size_t)(l0 + li + 1) * CI + ci0 + cc;
        Xh[o] = h;
        Xl[o] = f2b(lo);
    }
}

// ============ merged-tap MFMA conv-as-GEMM ============
template <int TAPS>
__global__ __launch_bounds__(512, 6) void convmm_kernel(const float* __restrict__ W,
                                                        const unsigned short* __restrict__ Xt,
                                                        float* __restrict__ G,
                                                        int CO, int CI, int S) {
    constexpr int RS = TAPS * 32 + 8;
    __shared__ unsigned short At[2][64 * RS];
    __shared__ unsigned short Bt[2][130 * 40];
    int tid = threadIdx.x;
    int lane = tid & 63, wid = tid >> 6;
    int q = lane >> 4, ln = lane & 15;
    int co0 = blockIdx.x * 64;
    int l0 = blockIdx.y * 128;
    int s = blockIdx.z;
    int kPer = CI / S, cis = s * kPer;
    const unsigned short* Xh = Xt;
    const unsigned short* Xl = Xt + (size_t)770 * CI;

    float4v zero4 = {0.f, 0.f, 0.f, 0.f};
    float4v acc[2][2];
    acc[0][0] = zero4; acc[0][1] = zero4; acc[1][0] = zero4; acc[1][1] = zero4;

    int wave_m = (wid >> 2) * 32;
    int wave_n = (wid & 3) * 32;

    for (int kb = 0; kb < kPer; kb += 32) {
        int cib = cis + kb;
        if (TAPS == 3) {
#pragma unroll
            for (int i = 0; i < 2; i++) {
                int slot = tid + 512 * i;
                int row = slot >> 4, ci0 = (slot & 15) * 2;
                const float* wp = W + ((size_t)(co0 + row) * CI + cib + ci0) * 3;
                float fa[6];
#pragma unroll
                for (int j = 0; j < 6; j++) fa[j] = wp[j];
#pragma unroll
                for (int t = 0; t < 3; t++) {
                    unsigned short h0 = f2b(fa[t]);
                    unsigned short h1 = f2b(fa[t + 3]);
                    unsigned short e0 = f2b(fa[t] - bf(h0));
                    unsigned short e1 = f2b(fa[t + 3] - bf(h1));
                    *(unsigned int*)&At[0][row * RS + t * 32 + ci0] =
                        (unsigned int)h0 | ((unsigned int)h1 << 16);
                    *(unsigned int*)&At[1][row * RS + t * 32 + ci0] =
                        (unsigned int)e0 | ((unsigned int)e1 << 16);
                }
            }
        } else {
            int row = tid >> 3, ci0 = (tid & 7) * 4;
            float4 wv = *(const float4*)(W + (size_t)(co0 + row) * CI + cib + ci0);
            float fa[4] = {wv.x, wv.y, wv.z, wv.w};
            unsigned short h[4], e[4];
#pragma unroll
            for (int j = 0; j < 4; j++) {
                h[j] = f2b(fa[j]);
                e[j] = f2b(fa[j] - bf(h[j]));
            }
            unsigned long long hp = (unsigned long long)h[0] | ((unsigned long long)h[1] << 16) |
                                    ((unsigned long long)h[2] << 32) | ((unsigned long long)h[3] << 48);
            unsigned long long ep = (unsigned long long)e[0] | ((unsigned long long)e[1] << 16) |
                                    ((unsigned long long)e[2] << 32) | ((unsigned long long)e[3] << 48);
            *(unsigned long long*)&At[0][row * RS + ci0] = hp;
            *(unsigned long long*)&At[1][row * RS + ci0] = ep;
        }
#pragma unroll
        for (int i = 0; i < 3; i++) {
            int slot = tid + 512 * i;
            if (slot < 1040) {
                int p = slot >= 520 ? 1 : 0;
                int rem = slot - p * 520;
                int r = rem >> 2, qq = rem & 3;
                const unsigned short* src = (p ? Xl : Xh) + (size_t)(l0 + r) * CI + cib + qq * 8;
                short8 v = *(const short8*)src;
                *(short8*)&Bt[p][r * 40 + qq * 8] = v;
            }
        }
        __syncthreads();
#pragma unroll
        for (int t = 0; t < TAPS; t++) {
            int shift = (TAPS == 1) ? 1 : t;
            short8 bh[2], bl[2];
#pragma unroll
            for (int nf = 0; nf < 2; nf++) {
                int rrow = wave_n + nf * 16 + ln + shift;
                bh[nf] = *(const short8*)&Bt[0][rrow * 40 + q * 8];
                bl[nf] = *(const short8*)&Bt[1][rrow * 40 + q * 8];
            }
#pragma unroll
            for (int mf = 0; mf < 2; mf++) {
                int mrow = wave_m + mf * 16 + ln;
                short8 ah = *(const short8*)&At[0][mrow * RS + t * 32 + q * 8];
                short8 al = *(const short8*)&At[1][mrow * RS + t * 32 + q * 8];
#pragma unroll
                for (int nf = 0; nf < 2; nf++) {
                    acc[mf][nf] = __builtin_amdgcn_mfma_f32_16x16x32_bf16(ah, bh[nf], acc[mf][nf], 0, 0, 0);
                    acc[mf][nf] = __builtin_amdgcn_mfma_f32_16x16x32_bf16(ah, bl[nf], acc[mf][nf], 0, 0, 0);
                    acc[mf][nf] = __builtin_amdgcn_mfma_f32_16x16x32_bf16(al, bh[nf], acc[mf][nf], 0, 0, 0);
                }
            }
        }
        __syncthreads();
    }
    float* Gz = G + (size_t)s * CO * 768;
#pragma unroll
    for (int mf = 0; mf < 2; mf++)
#pragma unroll
        for (int nf = 0; nf < 2; nf++) {
            int col = l0 + wave_n + nf * 16 + ln;
            int rowb = co0 + wave_m + mf * 16 + q * 4;
#pragma unroll
            for (int r = 0; r < 4; r++)
                Gz[(size_t)(rowb + r) * 768 + col] = acc[mf][nf][r];
        }
}

// finalize: sum P planes + bias -> transposed bf16 hi/lo Xt (rows 1..768)
__global__ __launch_bounds__(256) void finsum_x_kernel(const float* __restrict__ G,
                                                       const float* __restrict__ bias,
                                                       unsigned short* __restrict__ Xt,
                                                       int CO, int P) {
    __shared__ float T[64][65];
    int co0 = blockIdx.x * 64, l0 = blockIdx.y * 64;
    int tid = threadIdx.x;
#pragma unroll 1
    for (int i = 0; i < 16; i++) {
        int slot = tid + 256 * i;
        int r = slot >> 6, c = slot & 63;
        float v = bias[co0 + r];
        for (int p = 0; p < P; p++) v += G[((size_t)p * CO + co0 + r) * 768 + l0 + c];
        T[r][c] = v;
    }
    __syncthreads();
    unsigned short* Xh = Xt;
    unsigned short* Xl = Xt + (size_t)770 * CO;
#pragma unroll 1
    for (int i = 0; i < 16; i++) {
        int slot = tid + 256 * i;
        int li = slot >> 6, ci = slot & 63;
        float v = T[ci][li];
        unsigned short h = f2b(v);
        float lo = v - bf(h);
        size_t o = (size_t)(l0 + li + 1) * CO + co0 + ci;
        Xh[o] = h;
        Xl[o] = f2b(lo);
    }
}

// finalize: sum P planes + bias -> Xt slab AND fp32 [CO][768]
__global__ __launch_bounds__(256) void finsum_xf_kernel(const float* __restrict__ G,
                                                        const float* __restrict__ bias,
                                                        unsigned short* __restrict__ Xt,
                                                        float* __restrict__ outF,
                                                        int CO, int P) {
    __shared__ float T[64][65];
    int co0 = blockIdx.x * 64, l0 = blockIdx.y * 64;
    int tid = threadIdx.x;
#pragma unroll 1
    for (int i = 0; i < 16; i++) {
        int slot = tid + 256 * i;
        int r = slot >> 6, c = slot & 63;
        float v = bias[co0 + r];
        for (int p = 0; p < P; p++) v += G[((size_t)p * CO + co0 + r) * 768 + l0 + c];
        T[r][c] = v;
        outF[(size_t)(co0 + r) * 768 + l0 + c] = v;
    }
    __syncthreads();
    unsigned short* Xh = Xt;
    unsigned short* Xl = Xt + (size_t)770 * CO;
#pragma unroll 1
    for (int i = 0; i < 16; i++) {
        int slot = tid + 256 * i;
        int li = slot >> 6, ci = slot & 63;
        float v = T[ci][li];
        unsigned short h = f2b(v);
        float lo = v - bf(h);
        size_t o = (size_t)(l0 + li + 1) * CO + co0 + ci;
        Xh[o] = h;
        Xl[o] = f2b(lo);
    }
}

// finalize: sum P planes + bias (+relu) -> fp32 [CO][768]
__global__ __launch_bounds__(256) void finsum_f_kernel(const float* __restrict__ G,
                                                       const float* __restrict__ bias,
                                                       float* __restrict__ out,
                                                       int CO, int P, int relu) {
    int i = blockIdx.x * 256 + threadIdx.x;
    if (i >= CO * 768) return;
    int r = i / 768, c = i - r * 768;
    float v = bias[r];
    for (int p = 0; p < P; p++) v += G[((size_t)p * CO + r) * 768 + c];
    if (relu) v = fmaxf(v, 0.f);
    out[i] = v;
}

// ---------------- finalize for fp32 split-K gemm path ----------------
__global__ __launch_bounds__(256) void finalize_kernel(const float* __restrict__ part,
                                                       float* __restrict__ out,
                                                       const float* __restrict__ bias,
                                                       int RPAD, int R, int NCOLS, int S, int relu) {
    int i = blockIdx.x * 256 + threadIdx.x;
    int total = R * NCOLS;
    if (i >= total) return;
    int r = i / NCOLS;
    int c = i - r * NCOLS;
    float v = 0.f;
    for (int s = 0; s < S; s++) v += part[((size_t)s * RPAD + r) * NCOLS + c];
    v += bias[r];
    if (relu) v = fmaxf(v, 0.f);
    out[i] = v;
}

// ---------------- fp32 gather-GEMM ----------------
template <int MODE, int EPI>
__global__ __launch_bounds__(256) void gemm_kernel(const float* __restrict__ W,
                                                   const float* __restrict__ B,
                                                   const float* __restrict__ bias,
                                                   float* __restrict__ outF,
                                                   int R, int K, int NCOLS, int LDB, int S, int relu) {
    __shared__ __align__(16) float Bt[16][68];
    __shared__ __align__(16) float Wt[16][68];
    int tid = threadIdx.x;
    int tx = tid & 15, ty = tid >> 4;
    int r0 = blockIdx.x * 64, c0 = blockIdx.y * 64, s = blockIdx.z;
    int kPer = K / S;
    int k0s = s * kPer;
    float acc[4][4] = {};
    for (int kb = 0; kb < kPer; kb += 16) {
        int k0 = k0s + kb;
        {
            int rr = r0 + (tid >> 2);
            int q = tid & 3;
            float4 wv4 = {0.f, 0.f, 0.f, 0.f};
            if (rr < R) wv4 = *(const float4*)(W + (size_t)rr * K + k0 + q * 4);
            Wt[q * 4 + 0][tid >> 2] = wv4.x;
            Wt[q * 4 + 1][tid >> 2] = wv4.y;
            Wt[q * 4 + 2][tid >> 2] = wv4.z;
            Wt[q * 4 + 3][tid >> 2] = wv4.w;
        }
#pragma unroll
        for (int p = 0; p < 4; p++) {
            int kk = p * 4 + (tid >> 6);
            int c = tid & 63;
            int k = k0 + kk;
            int col = c0 + c;
            float v;
            if (MODE == 0) {
                v = B[(size_t)k * LDB + col];
            } else if (MODE == 1) {
                int ci = k / 3;
                int t = k - ci * 3;
                int lc = (col % 7) + t - 1;
                v = ((unsigned)lc < 7u) ? B[(size_t)ci * 896 + col + t - 1] : 0.f;
            } else {
                int co = k / 7;
                int b7 = k - co * 7;
                v = B[(size_t)co * 896 + col * 7 + b7];
            }
            Bt[kk][c] = v;
        }
        __syncthreads();
#pragma unroll
        for (int kk = 0; kk < 16; kk++) {
            float4 bv = *(const float4*)&Bt[kk][tx * 4];
            float4 wv = *(const float4*)&Wt[kk][ty * 4];
            float bb[4] = {bv.x, bv.y, bv.z, bv.w};
            float ww[4] = {wv.x, wv.y, wv.z, wv.w};
#pragma unroll
            for (int i = 0; i < 4; i++)
#pragma unroll
                for (int j = 0; j < 4; j++)
                    acc[i][j] = fmaf(ww[i], bb[j], acc[i][j]);
        }
        __syncthreads();
    }
    if (EPI == 0) {
        if (S > 1) {
#pragma unroll
            for (int i = 0; i < 4; i++) {
                int r = r0 + ty * 4 + i;
                float4 o = {acc[i][0], acc[i][1], acc[i][2], acc[i][3]};
                *(float4*)&outF[((size_t)s * R + r) * NCOLS + c0 + tx * 4] = o;
            }
        } else {
#pragma unroll
            for (int i = 0; i < 4; i++) {
                int r = r0 + ty * 4 + i;
                if (r < R) {
                    float bv = bias[r];
#pragma unroll
                    for (int j = 0; j < 4; j++) {
                        float v = acc[i][j] + bv;
                        if (relu) v = fmaxf(v, 0.f);
                        outF[(size_t)r * NCOLS + c0 + tx * 4 + j] = v;
                    }
                }
            }
        }
    } else {
#pragma unroll
        for (int i = 0; i < 4; i++) {
            int r = r0 + ty * 4 + i;
            if (r < R) {
                float bv = bias[r];
#pragma unroll
                for (int j = 0; j < 4; j++) {
                    int col = c0 + tx * 4 + j;
                    float v = acc[i][j] + bv;
                    if (EPI == 1) outF[512 + col * 21 + r] = v;
                    else outF[3200 + col * 40 + r] = v;
                }
            }
        }
    }
}

// ---------------- proposals: softmax, anchor decode ----------------
__global__ __launch_bounds__(256) void proposal_kernel(const float* __restrict__ clsS,
                                                       const float* __restrict__ segS,
                                                       float* __restrict__ cls2, float* __restrict__ off2,
                                                       float* __restrict__ scores,
                                                       float* __restrict__ sArr, float* __restrict__ eArr) {
    int i = blockIdx.x * 256 + threadIdx.x;
    if (i >= 7680) return;
    int l = i / 10;
    int a = i - l * 10;
    float c0 = clsS[(a * 2 + 0) * 768 + l];
    float c1 = clsS[(a * 2 + 1) * 768 + l];
    cls2[i * 2] = c0;
    cls2[i * 2 + 1] = c1;
    float m = fmaxf(c0, c1);
    float e0 = expf(c0 - m), e1 = expf(c1 - m);
    scores[i] = e1 / (e0 + e1);
    float o0 = segS[(a * 2 + 0) * 768 + l];
    float o1 = segS[(a * 2 + 1) * 768 + l];
    off2[i * 2] = o0;
    off2[i * 2 + 1] = o1;
    float ah = c_anchors[a] * 0.5f;
    float ac = (float)l + 0.5f;
    float c = ac + o0 * (2.f * ah);
    float hl = ah * expf(o1);
    sArr[i] = fminf(fmaxf(c - hl, 0.f), 768.f);
    eArr[i] = fminf(fmaxf(c + hl, 0.f), 768.f);
}

// ---------------- bitonic top-k phase A: 8 blocks sort 1024 keys each (desc) ----------------
__global__ __launch_bounds__(1024) void sortA_kernel(const float* __restrict__ scores,
                                                     unsigned long long* __restrict__ runs) {
    __shared__ unsigned long long kk[1024];
    int tid = threadIdx.x;
    int gbase = blockIdx.x * 1024;
    int gi = gbase + tid;
    unsigned long long key = 0ull;
    if (gi < 7680) {
        unsigned int sb = __float_as_uint(scores[gi]);
        key = ((unsigned long long)sb << 32) | (unsigned long long)(0xFFFFFFFFu - (unsigned)gi);
    }
    kk[tid] = key;
    __syncthreads();
    for (int k = 2; k <= 1024; k <<= 1) {
        for (int j = k >> 1; j > 0; j >>= 1) {
            int ixj = tid ^ j;
            if (ixj > tid) {
                unsigned long long a = kk[tid], b = kk[ixj];
                bool descend = ((tid & k) == 0);
                if (descend ? (a < b) : (a > b)) { kk[tid] = b; kk[ixj] = a; }
            }
            __syncthreads();
        }
    }
    runs[gbase + tid] = kk[tid];
}

// ---------------- phase B: tree-merge 8 sorted runs, keep exact top-1024 desc ----------------
// Half-cleaner lemma: A,B desc-sorted len-1024 -> C[i]=max(A[i],B[1023-i]) is a bitonic
// permutation of the exact top-1024 of A∪B; 10 butterfly passes re-sort descending.
__global__ __launch_bounds__(1024) void sortB_kernel(const unsigned long long* __restrict__ runs,
                                                     const float* __restrict__ sArr, const float* __restrict__ eArr,
                                                     int* __restrict__ topI,
                                                     float* __restrict__ ss, float* __restrict__ ee) {
    __shared__ unsigned long long S[8192];
    int tid = threadIdx.x;
#pragma unroll
    for (int m = 0; m < 8; m++) S[m * 1024 + tid] = runs[m * 1024 + tid];
    __syncthreads();
#pragma unroll 1
    for (int level = 0; level < 3; level++) {
        int span = 1024 << level;
        int nm = 4 >> level;
        for (int m = 0; m < nm; m++) {
            int baseA = m * (span * 2);
            int baseB = baseA + span;
            unsigned long long a = S[baseA + tid], b = S[baseB + 1023 - tid];
            S[baseA + tid] = (a > b) ? a : b;
        }
        __syncthreads();
        for (int j = 512; j > 0; j >>= 1) {
            for (int m = 0; m < nm; m++) {
                int baseA = m * (span * 2);
                int ixj = tid ^ j;
                if (ixj > tid) {
                    unsigned long long a = S[baseA + tid], b = S[baseA + ixj];
                    if (a < b) { S[baseA + tid] = b; S[baseA + ixj] = a; }
                }
            }
            __syncthreads();
        }
    }
    int idx = (int)(0xFFFFFFFFu - (unsigned int)(S[tid] & 0xFFFFFFFFull));
    topI[tid] = idx;
    ss[tid] = sArr[idx];
    ee[tid] = eArr[idx];
}

// ---------------- NMS suppression bitmask ----------------
__global__ __launch_bounds__(256) void nms_mask_kernel(const float* __restrict__ ss, const float* __restrict__ ee,
                                                       unsigned long long* __restrict__ mask) {
    int g = blockIdx.x * 256 + threadIdx.x;
    int i = g >> 4, w = g & 15;
    float si = ss[i], ei = ee[i];
    unsigned long long bits = 0ull;
#pragma unroll 1
    for (int jj = 0; jj < 64; jj++) {
        int j = w * 64 + jj;
        if (j > i) {
            float sj = ss[j], ej = ee[j];
            float inter = fmaxf(0.f, fminf(ei, ej) - fmaxf(si, sj));
            float uni = (ej - sj) + (ei - si) - inter;
            float iou = inter / fmaxf(uni, 1e-8f);
            if (iou > 0.7f) bits |= (1ull << jj);
        }
    }
    mask[(size_t)i * 16 + w] = bits;
}

// ---------------- blocked NMS scan (single wave) + stable partition + gather ----------------
__global__ __launch_bounds__(64) void nms_select_kernel(const unsigned long long* __restrict__ mask,
                                                        const int* __restrict__ topI,
                                                        const float* __restrict__ ss, const float* __restrict__ ee,
                                                        const float* __restrict__ cls2, const float* __restrict__ off2,
                                                        int* __restrict__ stA, int* __restrict__ enA,
                                                        float* __restrict__ out) {
    __shared__ unsigned long long remvS[16];
    __shared__ unsigned long long keepS[16];
    __shared__ int prefixS[17];
    int lane = threadIdx.x;
    if (lane < 16) remvS[lane] = 0ull;
    __syncthreads();
#pragma unroll 1
    for (int b = 0; b < 16; b++) {
        int row = b * 64 + lane;
        const unsigned long long* mrow = mask + (size_t)row * 16;
        unsigned long long diag = mrow[b];
        unsigned long long later[15];
        int nlater = 15 - b;
#pragma unroll 1
        for (int c = 0; c < nlater; c++) later[c] = mrow[b + 1 + c];
        unsigned long long rem = remvS[b];
#pragma unroll 1
        for (int i = 0; i < 64; i++) {
            unsigned long long di = __shfl(diag, i);
            if (!((rem >> i) & 1ull)) rem |= di;
        }
        unsigned long long keep64 = ~rem;
        bool mykeep = (keep64 >> lane) & 1ull;
#pragma unroll 1
        for (int c = 0; c < nlater; c++) {
            unsigned long long v = mykeep ? later[c] : 0ull;
            for (int sft = 1; sft < 64; sft <<= 1) v |= __shfl_xor(v, sft);
            if (lane == 0) remvS[b + 1 + c] |= v;
        }
        if (lane == 0) keepS[b] = keep64;
        __syncthreads();
    }
    if (lane == 0) {
        int acc = 0;
        for (int b = 0; b < 16; b++) { prefixS[b] = acc; acc += __popcll(keepS[b]); }
        prefixS[16] = acc;
    }
    __syncthreads();
    int total = prefixS[16];
#pragma unroll 1
    for (int b = 0; b < 16; b++) {
        int tid = b * 64 + lane;
        unsigned long long keep64 = keepS[b];
        unsigned long long below = (lane == 0) ? 0ull : (keep64 << (64 - lane));
        int keptBefore = prefixS[b] + __popcll(below);
        int kp = (int)((keep64 >> lane) & 1ull);
        int pos = kp ? keptBefore : (total + tid - keptBefore);
        if (pos < 128) {
            int orig = topI[tid];
            float ps = ss[tid], pe = ee[tid];
            out[pos * 2 + 0] = cls2[orig * 2 + 0];
            out[pos * 2 + 1] = cls2[orig * 2 + 1];
            out[256 + pos * 2 + 0] = off2[orig * 2 + 0];
            out[256 + pos * 2 + 1] = off2[orig * 2 + 1];
            float bc = (ps + pe) * 0.5f, bh = (pe - ps) * 0.5f;
            int st = (int)fminf(fmaxf(floorf(bc - bh), 0.f), 767.f);
            int en = (int)fminf(fmaxf(ceilf(bc + bh), 0.f), 767.f);
            if (en < st) en = st;
            stA[pos] = st;
            enA[pos] = en;
        }
    }
}

// ---------------- ROI max pool ----------------
__global__ __launch_bounds__(256) void roi_kernel(const float* __restrict__ f,
                                                  const int* __restrict__ stA, const int* __restrict__ enA,
                                                  float* __restrict__ spp) {
    int n = blockIdx.x;
    int c = blockIdx.y * 256 + threadIdx.x;
    int st = stA[n], en = enA[n];
    int ln = en - st + 1;
    const float* row = f + (size_t)c * 768;
#pragma unroll 1
    for (int b = 0; b < 7; b++) {
        int bs = st + (b * ln) / 7;
        int be = st + ((b + 1) * ln + 6) / 7 - 1;
        float m = row[bs];
        for (int t = bs + 1; t <= be; t++) m = fmaxf(m, row[t]);
        spp[(size_t)c * 896 + n * 7 + b] = m;
    }
}

extern "C" void kernel_launch(void* const* d_in, const int* in_sizes, int n_in,
                              void* d_out, int out_size, void* d_ws, size_t ws_size,
                              hipStream_t stream) {
    const float* IN[39];
    for (int i = 0; i < 39; i++) IN[i] = (const float*)d_in[i];
    const float* feature = IN[0];
    const float *b1f = IN[1], *b2f = IN[2], *b3 = IN[3], *b4 = IN[4], *b5 = IN[5], *b6 = IN[6];
    const float *bc1 = IN[7], *bc2 = IN[8], *boxb = IN[9], *boxw = IN[10];
    const float *clsb = IN[11], *clsw = IN[12];
    const float *fc1b = IN[13], *fc1w = IN[14], *fc2b = IN[15], *fc2w = IN[16];
    const float *fc3b = IN[17], *fc3w = IN[18];
    const float *sp1b = IN[19], *sp1w = IN[20], *sp2b = IN[21], *sp2w = IN[22];
    const float *sp3b = IN[23], *sp3w = IN[24], *sp4b = IN[25], *sp4w = IN[26];
    const float *spcb = IN[27], *spcw = IN[28], *spsb = IN[29], *spsw = IN[30];
    const float *w1f = IN[31], *w2f = IN[32], *w3w = IN[33], *w4w = IN[34];
    const float *w5w = IN[35], *w6w = IN[36], *wc1 = IN[37], *wc2 = IN[38];
    float* out = (float*)d_out;

    char* base = (char*)d_ws;
    float* G    = (float*)base;
    float* part = (float*)base;
    float* spp  = (float*)(base + 14680064);
    float* yA   = (float*)(base + 22020096);
    float* yB   = (float*)(base + 23855104);
    float* g1   = (float*)(base + 25690112);
    float* g2   = (float*)(base + 25952256);
    float* g3   = (float*)(base + 26083328);
    size_t off = 26148864;
    auto alloc = [&](size_t bytes) { void* p = base + off; off += (bytes + 15) & ~((size_t)15); return p; };
    unsigned short* Xt = (unsigned short*)alloc((size_t)770 * 2048 * 2 * 2);
    float* fbuf = (float*)alloc((size_t)2048 * 768 * 4);
    float* hB   = (float*)alloc((size_t)512 * 768 * 4);
    float* clsS = (float*)alloc((size_t)20 * 768 * 4);
    float* segS = (float*)alloc((size_t)20 * 768 * 4);
    float* cls2 = (float*)alloc(7680 * 2 * 4);
    float* off2 = (float*)alloc(7680 * 2 * 4);
    float* scores = (float*)alloc(7680 * 4);
    float* sArr = (float*)alloc(7680 * 4);
    float* eArr = (float*)alloc(7680 * 4);
    float* ssS  = (float*)alloc(1024 * 4);
    float* eeS  = (float*)alloc(1024 * 4);
    unsigned long long* runs = (unsigned long long*)alloc((size_t)8192 * 8);
    unsigned long long* mask = (unsigned long long*)alloc((size_t)16384 * 8);
    int* topI = (int*)alloc(1024 * 4);
    int* stA = (int*)alloc(128 * 4);
    int* enA = (int*)alloc(128 * 4);

    dim3 blk(256);
    dim3 blk512(512);

    // ---- conv1: feature -> slab -> G -> slab ----
    zeroXt_kernel<<<16, blk, 0, stream>>>(Xt, 2048);
    decomp_kernel<<<dim3(24, 64), blk, 0, stream>>>(feature, Xt, 2048);
    convmm_kernel<3><<<dim3(32, 6, 4), blk512, 0, stream>>>(w1f, Xt, G, 2048, 2048, 4);
    finsum_x_kernel<<<dim3(32, 12), blk, 0, stream>>>(G, b1f, Xt, 2048, 4);
    // ---- conv2: slab -> G -> fbuf (fp32) + slab ----
    convmm_kernel<3><<<dim3(32, 6, 4), blk512, 0, stream>>>(w2f, Xt, G, 2048, 2048, 4);
    finsum_xf_kernel<<<dim3(32, 12), blk, 0, stream>>>(G, b2f, Xt, fbuf, 2048, 4);

    // ---- wc1 via MFMA (TAPS=1 on conv2 slab) -> 512-slab ----
    convmm_kernel<1><<<dim3(8, 6, 8), blk512, 0, stream>>>(wc1, Xt, G, 512, 2048, 8);
    zeroXt_kernel<<<4, blk, 0, stream>>>(Xt, 512);
    finsum_x_kernel<<<dim3(8, 12), blk, 0, stream>>>(G, bc1, Xt, 512, 8);

    // ---- sp1..sp4 via MFMA ----
    convmm_kernel<3><<<dim3(8, 6, 8), blk512, 0, stream>>>(sp1w, Xt, G, 512, 512, 8);
    finsum_x_kernel<<<dim3(8, 12), blk, 0, stream>>>(G, sp1b, Xt, 512, 8);
    convmm_kernel<3><<<dim3(8, 6, 8), blk512, 0, stream>>>(sp2w, Xt, G, 512, 512, 8);
    finsum_x_kernel<<<dim3(8, 12), blk, 0, stream>>>(G, sp2b, Xt, 512, 8);
    convmm_kernel<3><<<dim3(8, 6, 8), blk512, 0, stream>>>(sp3w, Xt, G, 512, 512, 8);
    finsum_x_kernel<<<dim3(8, 12), blk, 0, stream>>>(G, sp3b, Xt, 512, 8);
    convmm_kernel<3><<<dim3(8, 6, 8), blk512, 0, stream>>>(sp4w, Xt, G, 512, 512, 8);
    finsum_f_kernel<<<1536, blk, 0, stream>>>(G, sp4b, hB, 512, 8, 1);  // relu

    // ---- heads ----
    gemm_kernel<0, 0><<<dim3(1, 12, 1), blk, 0, stream>>>(spcw, hB, spcb, clsS, 20, 512, 768, 768, 1, 0);
    gemm_kernel<0, 0><<<dim3(1, 12, 1), blk, 0, stream>>>(spsw, hB, spsb, segS, 20, 512, 768, 768, 1, 0);

    // ---- proposal decode / top-k / NMS ----
    proposal_kernel<<<30, blk, 0, stream>>>(clsS, segS, cls2, off2, scores, sArr, eArr);
    sortA_kernel<<<8, 1024, 0, stream>>>(scores, runs);
    sortB_kernel<<<1, 1024, 0, stream>>>(runs, sArr, eArr, topI, ssS, eeS);
    nms_mask_kernel<<<64, blk, 0, stream>>>(ssS, eeS, mask);
    nms_select_kernel<<<1, 64, 0, stream>>>(mask, topI, ssS, eeS, cls2, off2, stA, enA, out);

    // ---- ROI pool ----
    roi_kernel<<<dim3(128, 8), blk, 0, stream>>>(fbuf, stA, enA, spp);

    // ---- classifier tower (fp32 path) ----
    gemm_kernel<0, 0><<<dim3(8, 14, 8), blk, 0, stream>>>(wc2, spp, bc2, part, 512, 2048, 896, 896, 8, 0);
    finalize_kernel<<<1792, blk, 0, stream>>>(part, yA, bc2, 512, 512, 896, 8, 0);

    gemm_kernel<1, 0><<<dim3(8, 14, 8), blk, 0, stream>>>(w3w, yA, b3, part, 512, 1536, 896, 896, 8, 0);
    finalize_kernel<<<1792, blk, 0, stream>>>(part, yB, b3, 512, 512, 896, 8, 0);
    gemm_kernel<1, 0><<<dim3(8, 14, 8), blk, 0, stream>>>(w4w, yB, b4, part, 512, 1536, 896, 896, 8, 0);
    finalize_kernel<<<1792, blk, 0, stream>>>(part, yA, b4, 512, 512, 896, 8, 1);  // relu
    gemm_kernel<1, 0><<<dim3(8, 14, 8), blk, 0, stream>>>(w5w, yA, b5, part, 512, 1536, 896, 896, 8, 0);
    finalize_kernel<<<1792, blk, 0, stream>>>(part, yB, b5, 512, 512, 896, 8, 0);
    gemm_kernel<1, 0><<<dim3(8, 14, 8), blk, 0, stream>>>(w6w, yB, b6, part, 512, 1536, 896, 896, 8, 0);
    finalize_kernel<<<1792, blk, 0, stream>>>(part, yA, b6, 512, 512, 896, 8, 1);  // relu

    gemm_kernel<2, 0><<<dim3(8, 2, 28), blk, 0, stream>>>(fc1w, yA, fc1b, part, 512, 3584, 128, 128, 28, 0);
    finalize_kernel<<<256, blk, 0, stream>>>(part, g1, fc1b, 512, 512, 128, 28, 1);

    gemm_kernel<0, 0><<<dim3(4, 2, 4), blk, 0, stream>>>(fc2w, g1, fc2b, part, 256, 512, 128, 128, 4, 0);
    finalize_kernel<<<128, blk, 0, stream>>>(part, g2, fc2b, 256, 256, 128, 4, 0);
    gemm_kernel<0, 0><<<dim3(2, 2, 2), blk, 0, stream>>>(fc3w, g2, fc3b, part, 128, 256, 128, 128, 2, 0);
    finalize_kernel<<<64, blk, 0, stream>>>(part, g3, fc3b, 128, 128, 128, 2, 0);

    gemm_kernel<0, 1><<<dim3(1, 2, 1), blk, 0, stream>>>(clsw, g3, clsb, out, 21, 128, 128, 128, 1, 0);
    gemm_kernel<0, 2><<<dim3(1, 2, 1), blk, 0, stream>>>(boxw, g3, boxb, out, 40, 128, 128, 128, 1, 0);
}

// Round 7
// 1064.755 us; speedup vs baseline: 2.1829x; 1.0438x over previous
//
#include <hip/hip_runtime.h>

typedef __attribute__((ext_vector_type(8))) short short8;
typedef __attribute__((ext_vector_type(4))) float float4v;

__device__ __forceinline__ float bf(unsigned short u) {
    return __uint_as_float(((unsigned int)u) << 16);
}
__device__ __forceinline__ unsigned short f2b(float f) {
    unsigned int u = __float_as_uint(f);
    unsigned int r = (u + 0x7FFFu + ((u >> 16) & 1u)) >> 16;
    return (unsigned short)r;
}

__constant__ float c_anchors[10] = {2.f,4.f,5.f,6.f,8.f,9.f,10.f,12.f,14.f,16.f};

// ============ Xt helpers: transposed bf16 hi/lo slab [770][CI], planes h/l ============
__global__ __launch_bounds__(256) void zeroXt_kernel(unsigned short* __restrict__ Xt, int CI) {
    int i = blockIdx.x * 256 + threadIdx.x;
    if (i < 2 * CI) {
        int row = (i >= CI) ? 769 : 0;
        int co = (i >= CI) ? (i - CI) : i;
        Xt[(size_t)row * CI + co] = 0;
        Xt[(size_t)770 * CI + (size_t)row * CI + co] = 0;
    }
}

// src fp32 [CI][768] -> Xt rows 1..768 (row l+1 = X[:,l]), hi/lo planes
__global__ __launch_bounds__(256) void decomp_kernel(const float* __restrict__ src,
                                                     unsigned short* __restrict__ Xt, int CI) {
    __shared__ float T[32][33];
    int l0 = blockIdx.x * 32, ci0 = blockIdx.y * 32;
    int tid = threadIdx.x;
#pragma unroll
    for (int i = 0; i < 4; i++) {
        int slot = tid + 256 * i;
        int r = slot >> 5, c = slot & 31;
        T[r][c] = src[(size_t)(ci0 + r) * 768 + l0 + c];
    }
    __syncthreads();
    unsigned short* Xh = Xt;
    unsigned short* Xl = Xt + (size_t)770 * CI;
#pragma unroll
    for (int i = 0; i < 4; i++) {
        int slot = tid + 256 * i;
        int li = slot >> 5, cc = slot & 31;
        float v = T[cc][li];
        unsigned short h = f2b(v);
        float lo = v - bf(h);
        size_t o = (size_t)(l0 + li + 1) * CI + ci0 + cc;
        Xh[o] = h;
        Xl[o] = f2b(lo);
    }
}

// ============ merged-tap MFMA conv-as-GEMM ============
template <int TAPS>
__global__ __launch_bounds__(512, 6) void convmm_kernel(const float* __restrict__ W,
                                                        const unsigned short* __restrict__ Xt,
                                                        float* __restrict__ G,
                                                        int CO, int CI, int S) {
    constexpr int RS = TAPS * 32 + 8;
    __shared__ unsigned short At[2][64 * RS];
    __shared__ unsigned short Bt[2][130 * 40];
    int tid = threadIdx.x;
    int lane = tid & 63, wid = tid >> 6;
    int q = lane >> 4, ln = lane & 15;
    int co0 = blockIdx.x * 64;
    int l0 = blockIdx.y * 128;
    int s = blockIdx.z;
    int kPer = CI / S, cis = s * kPer;
    const unsigned short* Xh = Xt;
    const unsigned short* Xl = Xt + (size_t)770 * CI;

    float4v zero4 = {0.f, 0.f, 0.f, 0.f};
    float4v acc[2][2];
    acc[0][0] = zero4; acc[0][1] = zero4; acc[1][0] = zero4; acc[1][1] = zero4;

    int wave_m = (wid >> 2) * 32;
    int wave_n = (wid & 3) * 32;

    for (int kb = 0; kb < kPer; kb += 32) {
        int cib = cis + kb;
        if (TAPS == 3) {
#pragma unroll
            for (int i = 0; i < 2; i++) {
                int slot = tid + 512 * i;
                int row = slot >> 4, ci0 = (slot & 15) * 2;
                const float* wp = W + ((size_t)(co0 + row) * CI + cib + ci0) * 3;
                float fa[6];
#pragma unroll
                for (int j = 0; j < 6; j++) fa[j] = wp[j];
#pragma unroll
                for (int t = 0; t < 3; t++) {
                    unsigned short h0 = f2b(fa[t]);
                    unsigned short h1 = f2b(fa[t + 3]);
                    unsigned short e0 = f2b(fa[t] - bf(h0));
                    unsigned short e1 = f2b(fa[t + 3] - bf(h1));
                    *(unsigned int*)&At[0][row * RS + t * 32 + ci0] =
                        (unsigned int)h0 | ((unsigned int)h1 << 16);
                    *(unsigned int*)&At[1][row * RS + t * 32 + ci0] =
                        (unsigned int)e0 | ((unsigned int)e1 << 16);
                }
            }
        } else {
            int row = tid >> 3, ci0 = (tid & 7) * 4;
            float4 wv = *(const float4*)(W + (size_t)(co0 + row) * CI + cib + ci0);
            float fa[4] = {wv.x, wv.y, wv.z, wv.w};
            unsigned short h[4], e[4];
#pragma unroll
            for (int j = 0; j < 4; j++) {
                h[j] = f2b(fa[j]);
                e[j] = f2b(fa[j] - bf(h[j]));
            }
            unsigned long long hp = (unsigned long long)h[0] | ((unsigned long long)h[1] << 16) |
                                    ((unsigned long long)h[2] << 32) | ((unsigned long long)h[3] << 48);
            unsigned long long ep = (unsigned long long)e[0] | ((unsigned long long)e[1] << 16) |
                                    ((unsigned long long)e[2] << 32) | ((unsigned long long)e[3] << 48);
            *(unsigned long long*)&At[0][row * RS + ci0] = hp;
            *(unsigned long long*)&At[1][row * RS + ci0] = ep;
        }
#pragma unroll
        for (int i = 0; i < 3; i++) {
            int slot = tid + 512 * i;
            if (slot < 1040) {
                int p = slot >= 520 ? 1 : 0;
                int rem = slot - p * 520;
                int r = rem >> 2, qq = rem & 3;
                const unsigned short* src = (p ? Xl : Xh) + (size_t)(l0 + r) * CI + cib + qq * 8;
                short8 v = *(const short8*)src;
                *(short8*)&Bt[p][r * 40 + qq * 8] = v;
            }
        }
        __syncthreads();
#pragma unroll
        for (int t = 0; t < TAPS; t++) {
            int shift = (TAPS == 1) ? 1 : t;
            short8 bh[2], bl[2];
#pragma unroll
            for (int nf = 0; nf < 2; nf++) {
                int rrow = wave_n + nf * 16 + ln + shift;
                bh[nf] = *(const short8*)&Bt[0][rrow * 40 + q * 8];
                bl[nf] = *(const short8*)&Bt[1][rrow * 40 + q * 8];
            }
#pragma unroll
            for (int mf = 0; mf < 2; mf++) {
                int mrow = wave_m + mf * 16 + ln;
                short8 ah = *(const short8*)&At[0][mrow * RS + t * 32 + q * 8];
                short8 al = *(const short8*)&At[1][mrow * RS + t * 32 + q * 8];
#pragma unroll
                for (int nf = 0; nf < 2; nf++) {
                    acc[mf][nf] = __builtin_amdgcn_mfma_f32_16x16x32_bf16(ah, bh[nf], acc[mf][nf], 0, 0, 0);
                    acc[mf][nf] = __builtin_amdgcn_mfma_f32_16x16x32_bf16(ah, bl[nf], acc[mf][nf], 0, 0, 0);
                    acc[mf][nf] = __builtin_amdgcn_mfma_f32_16x16x32_bf16(al, bh[nf], acc[mf][nf], 0, 0, 0);
                }
            }
        }
        __syncthreads();
    }
    float* Gz = G + (size_t)s * CO * 768;
#pragma unroll
    for (int mf = 0; mf < 2; mf++)
#pragma unroll
        for (int nf = 0; nf < 2; nf++) {
            int col = l0 + wave_n + nf * 16 + ln;
            int rowb = co0 + wave_m + mf * 16 + q * 4;
#pragma unroll
            for (int r = 0; r < 4; r++)
                Gz[(size_t)(rowb + r) * 768 + col] = acc[mf][nf][r];
        }
}

// finalize: sum P planes + bias -> transposed bf16 hi/lo Xt (rows 1..768)
__global__ __launch_bounds__(256) void finsum_x_kernel(const float* __restrict__ G,
                                                       const float* __restrict__ bias,
                                                       unsigned short* __restrict__ Xt,
                                                       int CO, int P) {
    __shared__ float T[64][65];
    int co0 = blockIdx.x * 64, l0 = blockIdx.y * 64;
    int tid = threadIdx.x;
#pragma unroll 1
    for (int i = 0; i < 16; i++) {
        int slot = tid + 256 * i;
        int r = slot >> 6, c = slot & 63;
        float v = bias[co0 + r];
        for (int p = 0; p < P; p++) v += G[((size_t)p * CO + co0 + r) * 768 + l0 + c];
        T[r][c] = v;
    }
    __syncthreads();
    unsigned short* Xh = Xt;
    unsigned short* Xl = Xt + (size_t)770 * CO;
#pragma unroll 1
    for (int i = 0; i < 16; i++) {
        int slot = tid + 256 * i;
        int li = slot >> 6, ci = slot & 63;
        float v = T[ci][li];
        unsigned short h = f2b(v);
        float lo = v - bf(h);
        size_t o = (size_t)(l0 + li + 1) * CO + co0 + ci;
        Xh[o] = h;
        Xl[o] = f2b(lo);
    }
}

// finalize: sum P planes + bias -> Xt slab AND fp32 [CO][768]
__global__ __launch_bounds__(256) void finsum_xf_kernel(const float* __restrict__ G,
                                                        const float* __restrict__ bias,
                                                        unsigned short* __restrict__ Xt,
                                                        float* __restrict__ outF,
                                                        int CO, int P) {
    __shared__ float T[64][65];
    int co0 = blockIdx.x * 64, l0 = blockIdx.y * 64;
    int tid = threadIdx.x;
#pragma unroll 1
    for (int i = 0; i < 16; i++) {
        int slot = tid + 256 * i;
        int r = slot >> 6, c = slot & 63;
        float v = bias[co0 + r];
        for (int p = 0; p < P; p++) v += G[((size_t)p * CO + co0 + r) * 768 + l0 + c];
        T[r][c] = v;
        outF[(size_t)(co0 + r) * 768 + l0 + c] = v;
    }
    __syncthreads();
    unsigned short* Xh = Xt;
    unsigned short* Xl = Xt + (size_t)770 * CO;
#pragma unroll 1
    for (int i = 0; i < 16; i++) {
        int slot = tid + 256 * i;
        int li = slot >> 6, ci = slot & 63;
        float v = T[ci][li];
        unsigned short h = f2b(v);
        float lo = v - bf(h);
        size_t o = (size_t)(l0 + li + 1) * CO + co0 + ci;
        Xh[o] = h;
        Xl[o] = f2b(lo);
    }
}

// finalize: sum P planes + bias (+relu) -> fp32 [CO][768]
__global__ __launch_bounds__(256) void finsum_f_kernel(const float* __restrict__ G,
                                                       const float* __restrict__ bias,
                                                       float* __restrict__ out,
                                                       int CO, int P, int relu) {
    int i = blockIdx.x * 256 + threadIdx.x;
    if (i >= CO * 768) return;
    int r = i / 768, c = i - r * 768;
    float v = bias[r];
    for (int p = 0; p < P; p++) v += G[((size_t)p * CO + r) * 768 + c];
    if (relu) v = fmaxf(v, 0.f);
    out[i] = v;
}

// ---------------- finalize for fp32 split-K gemm path ----------------
__global__ __launch_bounds__(256) void finalize_kernel(const float* __restrict__ part,
                                                       float* __restrict__ out,
                                                       const float* __restrict__ bias,
                                                       int RPAD, int R, int NCOLS, int S, int relu) {
    int i = blockIdx.x * 256 + threadIdx.x;
    int total = R * NCOLS;
    if (i >= total) return;
    int r = i / NCOLS;
    int c = i - r * NCOLS;
    float v = 0.f;
    for (int s = 0; s < S; s++) v += part[((size_t)s * RPAD + r) * NCOLS + c];
    v += bias[r];
    if (relu) v = fmaxf(v, 0.f);
    out[i] = v;
}

// ---------------- fp32 gather-GEMM ----------------
template <int MODE, int EPI>
__global__ __launch_bounds__(256) void gemm_kernel(const float* __restrict__ W,
                                                   const float* __restrict__ B,
                                                   const float* __restrict__ bias,
                                                   float* __restrict__ outF,
                                                   int R, int K, int NCOLS, int LDB, int S, int relu) {
    __shared__ __align__(16) float Bt[16][68];
    __shared__ __align__(16) float Wt[16][68];
    int tid = threadIdx.x;
    int tx = tid & 15, ty = tid >> 4;
    int r0 = blockIdx.x * 64, c0 = blockIdx.y * 64, s = blockIdx.z;
    int kPer = K / S;
    int k0s = s * kPer;
    float acc[4][4] = {};
    for (int kb = 0; kb < kPer; kb += 16) {
        int k0 = k0s + kb;
        {
            int rr = r0 + (tid >> 2);
            int q = tid & 3;
            float4 wv4 = {0.f, 0.f, 0.f, 0.f};
            if (rr < R) wv4 = *(const float4*)(W + (size_t)rr * K + k0 + q * 4);
            Wt[q * 4 + 0][tid >> 2] = wv4.x;
            Wt[q * 4 + 1][tid >> 2] = wv4.y;
            Wt[q * 4 + 2][tid >> 2] = wv4.z;
            Wt[q * 4 + 3][tid >> 2] = wv4.w;
        }
#pragma unroll
        for (int p = 0; p < 4; p++) {
            int kk = p * 4 + (tid >> 6);
            int c = tid & 63;
            int k = k0 + kk;
            int col = c0 + c;
            float v;
            if (MODE == 0) {
                v = B[(size_t)k * LDB + col];
            } else if (MODE == 1) {
                int ci = k / 3;
                int t = k - ci * 3;
                int lc = (col % 7) + t - 1;
                v = ((unsigned)lc < 7u) ? B[(size_t)ci * 896 + col + t - 1] : 0.f;
            } else {
                int co = k / 7;
                int b7 = k - co * 7;
                v = B[(size_t)co * 896 + col * 7 + b7];
            }
            Bt[kk][c] = v;
        }
        __syncthreads();
#pragma unroll
        for (int kk = 0; kk < 16; kk++) {
            float4 bv = *(const float4*)&Bt[kk][tx * 4];
            float4 wv = *(const float4*)&Wt[kk][ty * 4];
            float bb[4] = {bv.x, bv.y, bv.z, bv.w};
            float ww[4] = {wv.x, wv.y, wv.z, wv.w};
#pragma unroll
            for (int i = 0; i < 4; i++)
#pragma unroll
                for (int j = 0; j < 4; j++)
                    acc[i][j] = fmaf(ww[i], bb[j], acc[i][j]);
        }
        __syncthreads();
    }
    if (EPI == 0) {
        if (S > 1) {
#pragma unroll
            for (int i = 0; i < 4; i++) {
                int r = r0 + ty * 4 + i;
                float4 o = {acc[i][0], acc[i][1], acc[i][2], acc[i][3]};
                *(float4*)&outF[((size_t)s * R + r) * NCOLS + c0 + tx * 4] = o;
            }
        } else {
#pragma unroll
            for (int i = 0; i < 4; i++) {
                int r = r0 + ty * 4 + i;
                if (r < R) {
                    float bv = bias[r];
#pragma unroll
                    for (int j = 0; j < 4; j++) {
                        float v = acc[i][j] + bv;
                        if (relu) v = fmaxf(v, 0.f);
                        outF[(size_t)r * NCOLS + c0 + tx * 4 + j] = v;
                    }
                }
            }
        }
    } else {
#pragma unroll
        for (int i = 0; i < 4; i++) {
            int r = r0 + ty * 4 + i;
            if (r < R) {
                float bv = bias[r];
#pragma unroll
                for (int j = 0; j < 4; j++) {
                    int col = c0 + tx * 4 + j;
                    float v = acc[i][j] + bv;
                    if (EPI == 1) outF[512 + col * 21 + r] = v;
                    else outF[3200 + col * 40 + r] = v;
                }
            }
        }
    }
}

// ---------------- proposals: softmax, anchor decode ----------------
__global__ __launch_bounds__(256) void proposal_kernel(const float* __restrict__ clsS,
                                                       const float* __restrict__ segS,
                                                       float* __restrict__ cls2, float* __restrict__ off2,
                                                       float* __restrict__ scores,
                                                       float* __restrict__ sArr, float* __restrict__ eArr) {
    int i = blockIdx.x * 256 + threadIdx.x;
    if (i >= 7680) return;
    int l = i / 10;
    int a = i - l * 10;
    float c0 = clsS[(a * 2 + 0) * 768 + l];
    float c1 = clsS[(a * 2 + 1) * 768 + l];
    cls2[i * 2] = c0;
    cls2[i * 2 + 1] = c1;
    float m = fmaxf(c0, c1);
    float e0 = expf(c0 - m), e1 = expf(c1 - m);
    scores[i] = e1 / (e0 + e1);
    float o0 = segS[(a * 2 + 0) * 768 + l];
    float o1 = segS[(a * 2 + 1) * 768 + l];
    off2[i * 2] = o0;
    off2[i * 2 + 1] = o1;
    float ah = c_anchors[a] * 0.5f;
    float ac = (float)l + 0.5f;
    float c = ac + o0 * (2.f * ah);
    float hl = ah * expf(o1);
    sArr[i] = fminf(fmaxf(c - hl, 0.f), 768.f);
    eArr[i] = fminf(fmaxf(c + hl, 0.f), 768.f);
}

// ---------------- bitonic top-k phase A: 8 blocks sort 1024 keys each (desc) ----------------
__global__ __launch_bounds__(1024) void sortA_kernel(const float* __restrict__ scores,
                                                     unsigned long long* __restrict__ runs) {
    __shared__ unsigned long long kk[1024];
    int tid = threadIdx.x;
    int gbase = blockIdx.x * 1024;
    int gi = gbase + tid;
    unsigned long long key = 0ull;
    if (gi < 7680) {
        unsigned int sb = __float_as_uint(scores[gi]);
        key = ((unsigned long long)sb << 32) | (unsigned long long)(0xFFFFFFFFu - (unsigned)gi);
    }
    kk[tid] = key;
    __syncthreads();
    for (int k = 2; k <= 1024; k <<= 1) {
        for (int j = k >> 1; j > 0; j >>= 1) {
            int ixj = tid ^ j;
            if (ixj > tid) {
                unsigned long long a = kk[tid], b = kk[ixj];
                bool descend = ((tid & k) == 0);
                if (descend ? (a < b) : (a > b)) { kk[tid] = b; kk[ixj] = a; }
            }
            __syncthreads();
        }
    }
    runs[gbase + tid] = kk[tid];
}

// ---------------- phase B: tree-merge 8 sorted runs, keep exact top-1024 desc ----------------
__global__ __launch_bounds__(1024) void sortB_kernel(const unsigned long long* __restrict__ runs,
                                                     const float* __restrict__ sArr, const float* __restrict__ eArr,
                                                     int* __restrict__ topI,
                                                     float* __restrict__ ss, float* __restrict__ ee) {
    __shared__ unsigned long long S[8192];
    int tid = threadIdx.x;
#pragma unroll
    for (int m = 0; m < 8; m++) S[m * 1024 + tid] = runs[m * 1024 + tid];
    __syncthreads();
#pragma unroll 1
    for (int level = 0; level < 3; level++) {
        int span = 1024 << level;
        int nm = 4 >> level;
        for (int m = 0; m < nm; m++) {
            int baseA = m * (span * 2);
            int baseB = baseA + span;
            unsigned long long a = S[baseA + tid], b = S[baseB + 1023 - tid];
            S[baseA + tid] = (a > b) ? a : b;
        }
        __syncthreads();
        for (int j = 512; j > 0; j >>= 1) {
            for (int m = 0; m < nm; m++) {
                int baseA = m * (span * 2);
                int ixj = tid ^ j;
                if (ixj > tid) {
                    unsigned long long a = S[baseA + tid], b = S[baseA + ixj];
                    if (a < b) { S[baseA + tid] = b; S[baseA + ixj] = a; }
                }
            }
            __syncthreads();
        }
    }
    int idx = (int)(0xFFFFFFFFu - (unsigned int)(S[tid] & 0xFFFFFFFFull));
    topI[tid] = idx;
    ss[tid] = sArr[idx];
    ee[tid] = eArr[idx];
}

// ---------------- NMS suppression bitmask ----------------
__global__ __launch_bounds__(256) void nms_mask_kernel(const float* __restrict__ ss, const float* __restrict__ ee,
                                                       unsigned long long* __restrict__ mask) {
    int g = blockIdx.x * 256 + threadIdx.x;
    int i = g >> 4, w = g & 15;
    float si = ss[i], ei = ee[i];
    unsigned long long bits = 0ull;
#pragma unroll 1
    for (int jj = 0; jj < 64; jj++) {
        int j = w * 64 + jj;
        if (j > i) {
            float sj = ss[j], ej = ee[j];
            float inter = fmaxf(0.f, fminf(ei, ej) - fmaxf(si, sj));
            float uni = (ej - sj) + (ei - si) - inter;
            float iou = inter / fmaxf(uni, 1e-8f);
            if (iou > 0.7f) bits |= (1ull << jj);
        }
    }
    mask[(size_t)i * 16 + w] = bits;
}

// ---------------- NMS scan via readlane (scalar-pipe) + lazy rem + partition ----------------
__device__ __forceinline__ unsigned long long readlane64(unsigned long long v, int i) {
    unsigned int lo = (unsigned int)__builtin_amdgcn_readlane((int)(unsigned int)(v & 0xFFFFFFFFull), i);
    unsigned int hi = (unsigned int)__builtin_amdgcn_readlane((int)(unsigned int)(v >> 32), i);
    return ((unsigned long long)hi << 32) | (unsigned long long)lo;
}

__global__ __launch_bounds__(64) void nms_select_kernel(const unsigned long long* __restrict__ mask,
                                                        const int* __restrict__ topI,
                                                        const float* __restrict__ ss, const float* __restrict__ ee,
                                                        const float* __restrict__ cls2, const float* __restrict__ off2,
                                                        int* __restrict__ stA, int* __restrict__ enA,
                                                        float* __restrict__ out) {
    int lane = threadIdx.x;
    unsigned long long keepW[16];
#pragma unroll 1
    for (int b = 0; b < 16; b++) {
        // lazy incoming rem: OR over kept rows of earlier blocks, word b.
        // lane L handles rows a*64+L; loads are independent -> pipelined.
        unsigned long long accv = 0ull;
#pragma unroll 1
        for (int a = 0; a < b; a++) {
            unsigned long long m = mask[(size_t)(a * 64 + lane) * 16 + b];
            unsigned long long kb = (keepW[a] >> lane) & 1ull;
            accv |= m & (0ull - kb);
        }
        // single wave OR-reduce -> uniform
#pragma unroll
        for (int sft = 1; sft < 64; sft <<= 1) accv |= __shfl_xor(accv, sft);
        unsigned long long diag = mask[(size_t)(b * 64 + lane) * 16 + b];
        unsigned long long rem = accv;
        // intra-block recurrence on the scalar pipe: readlane (const idx) + scalar ops
#pragma unroll
        for (int i = 0; i < 64; i++) {
            unsigned long long di = readlane64(diag, i);
            if (!((rem >> i) & 1ull)) rem |= di;
        }
        keepW[b] = ~rem;
    }
    // prefix of kept counts (all wave-uniform)
    int total = 0;
    int prefix[16];
#pragma unroll
    for (int b = 0; b < 16; b++) { prefix[b] = total; total += __popcll(keepW[b]); }
    // stable partition + gather
#pragma unroll 1
    for (int b = 0; b < 16; b++) {
        int tid = b * 64 + lane;
        unsigned long long keep64 = keepW[b];
        unsigned long long below = (lane == 0) ? 0ull : (keep64 << (64 - lane));
        int keptBefore = prefix[b] + __popcll(below);
        int kp = (int)((keep64 >> lane) & 1ull);
        int pos = kp ? keptBefore : (total + tid - keptBefore);
        if (pos < 128) {
            int orig = topI[tid];
            float ps = ss[tid], pe = ee[tid];
            out[pos * 2 + 0] = cls2[orig * 2 + 0];
            out[pos * 2 + 1] = cls2[orig * 2 + 1];
            out[256 + pos * 2 + 0] = off2[orig * 2 + 0];
            out[256 + pos * 2 + 1] = off2[orig * 2 + 1];
            float bc = (ps + pe) * 0.5f, bh = (pe - ps) * 0.5f;
            int st = (int)fminf(fmaxf(floorf(bc - bh), 0.f), 767.f);
            int en = (int)fminf(fmaxf(ceilf(bc + bh), 0.f), 767.f);
            if (en < st) en = st;
            stA[pos] = st;
            enA[pos] = en;
        }
    }
}

// ---------------- ROI max pool ----------------
__global__ __launch_bounds__(256) void roi_kernel(const float* __restrict__ f,
                                                  const int* __restrict__ stA, const int* __restrict__ enA,
                                                  float* __restrict__ spp) {
    int n = blockIdx.x;
    int c = blockIdx.y * 256 + threadIdx.x;
    int st = stA[n], en = enA[n];
    int ln = en - st + 1;
    const float* row = f + (size_t)c * 768;
#pragma unroll 1
    for (int b = 0; b < 7; b++) {
        int bs = st + (b * ln) / 7;
        int be = st + ((b + 1) * ln + 6) / 7 - 1;
        float m = row[bs];
        for (int t = bs + 1; t <= be; t++) m = fmaxf(m, row[t]);
        spp[(size_t)c * 896 + n * 7 + b] = m;
    }
}

extern "C" void kernel_launch(void* const* d_in, const int* in_sizes, int n_in,
                              void* d_out, int out_size, void* d_ws, size_t ws_size,
                              hipStream_t stream) {
    const float* IN[39];
    for (int i = 0; i < 39; i++) IN[i] = (const float*)d_in[i];
    const float* feature = IN[0];
    const float *b1f = IN[1], *b2f = IN[2], *b3 = IN[3], *b4 = IN[4], *b5 = IN[5], *b6 = IN[6];
    const float *bc1 = IN[7], *bc2 = IN[8], *boxb = IN[9], *boxw = IN[10];
    const float *clsb = IN[11], *clsw = IN[12];
    const float *fc1b = IN[13], *fc1w = IN[14], *fc2b = IN[15], *fc2w = IN[16];
    const float *fc3b = IN[17], *fc3w = IN[18];
    const float *sp1b = IN[19], *sp1w = IN[20], *sp2b = IN[21], *sp2w = IN[22];
    const float *sp3b = IN[23], *sp3w = IN[24], *sp4b = IN[25], *sp4w = IN[26];
    const float *spcb = IN[27], *spcw = IN[28], *spsb = IN[29], *spsw = IN[30];
    const float *w1f = IN[31], *w2f = IN[32], *w3w = IN[33], *w4w = IN[34];
    const float *w5w = IN[35], *w6w = IN[36], *wc1 = IN[37], *wc2 = IN[38];
    float* out = (float*)d_out;

    char* base = (char*)d_ws;
    float* G    = (float*)base;
    float* part = (float*)base;
    float* spp  = (float*)(base + 14680064);
    float* yA   = (float*)(base + 22020096);
    float* yB   = (float*)(base + 23855104);
    float* g1   = (float*)(base + 25690112);
    float* g2   = (float*)(base + 25952256);
    float* g3   = (float*)(base + 26083328);
    size_t off = 26148864;
    auto alloc = [&](size_t bytes) { void* p = base + off; off += (bytes + 15) & ~((size_t)15); return p; };
    unsigned short* Xt = (unsigned short*)alloc((size_t)770 * 2048 * 2 * 2);
    float* fbuf = (float*)alloc((size_t)2048 * 768 * 4);
    float* hB   = (float*)alloc((size_t)512 * 768 * 4);
    float* clsS = (float*)alloc((size_t)20 * 768 * 4);
    float* segS = (float*)alloc((size_t)20 * 768 * 4);
    float* cls2 = (float*)alloc(7680 * 2 * 4);
    float* off2 = (float*)alloc(7680 * 2 * 4);
    float* scores = (float*)alloc(7680 * 4);
    float* sArr = (float*)alloc(7680 * 4);
    float* eArr = (float*)alloc(7680 * 4);
    float* ssS  = (float*)alloc(1024 * 4);
    float* eeS  = (float*)alloc(1024 * 4);
    unsigned long long* runs = (unsigned long long*)alloc((size_t)8192 * 8);
    unsigned long long* mask = (unsigned long long*)alloc((size_t)16384 * 8);
    int* topI = (int*)alloc(1024 * 4);
    int* stA = (int*)alloc(128 * 4);
    int* enA = (int*)alloc(128 * 4);

    dim3 blk(256);
    dim3 blk512(512);

    // ---- conv1: feature -> slab -> G -> slab ----
    zeroXt_kernel<<<16, blk, 0, stream>>>(Xt, 2048);
    decomp_kernel<<<dim3(24, 64), blk, 0, stream>>>(feature, Xt, 2048);
    convmm_kernel<3><<<dim3(32, 6, 4), blk512, 0, stream>>>(w1f, Xt, G, 2048, 2048, 4);
    finsum_x_kernel<<<dim3(32, 12), blk, 0, stream>>>(G, b1f, Xt, 2048, 4);
    // ---- conv2: slab -> G -> fbuf (fp32) + slab ----
    convmm_kernel<3><<<dim3(32, 6, 4), blk512, 0, stream>>>(w2f, Xt, G, 2048, 2048, 4);
    finsum_xf_kernel<<<dim3(32, 12), blk, 0, stream>>>(G, b2f, Xt, fbuf, 2048, 4);

    // ---- wc1 via MFMA (TAPS=1 on conv2 slab) -> 512-slab ----
    convmm_kernel<1><<<dim3(8, 6, 8), blk512, 0, stream>>>(wc1, Xt, G, 512, 2048, 8);
    zeroXt_kernel<<<4, blk, 0, stream>>>(Xt, 512);
    finsum_x_kernel<<<dim3(8, 12), blk, 0, stream>>>(G, bc1, Xt, 512, 8);

    // ---- sp1..sp4 via MFMA ----
    convmm_kernel<3><<<dim3(8, 6, 8), blk512, 0, stream>>>(sp1w, Xt, G, 512, 512, 8);
    finsum_x_kernel<<<dim3(8, 12), blk, 0, stream>>>(G, sp1b, Xt, 512, 8);
    convmm_kernel<3><<<dim3(8, 6, 8), blk512, 0, stream>>>(sp2w, Xt, G, 512, 512, 8);
    finsum_x_kernel<<<dim3(8, 12), blk, 0, stream>>>(G, sp2b, Xt, 512, 8);
    convmm_kernel<3><<<dim3(8, 6, 8), blk512, 0, stream>>>(sp3w, Xt, G, 512, 512, 8);
    finsum_x_kernel<<<dim3(8, 12), blk, 0, stream>>>(G, sp3b, Xt, 512, 8);
    convmm_kernel<3><<<dim3(8, 6, 8), blk512, 0, stream>>>(sp4w, Xt, G, 512, 512, 8);
    finsum_f_kernel<<<1536, blk, 0, stream>>>(G, sp4b, hB, 512, 8, 1);  // relu

    // ---- heads ----
    gemm_kernel<0, 0><<<dim3(1, 12, 1), blk, 0, stream>>>(spcw, hB, spcb, clsS, 20, 512, 768, 768, 1, 0);
    gemm_kernel<0, 0><<<dim3(1, 12, 1), blk, 0, stream>>>(spsw, hB, spsb, segS, 20, 512, 768, 768, 1, 0);

    // ---- proposal decode / top-k / NMS ----
    proposal_kernel<<<30, blk, 0, stream>>>(clsS, segS, cls2, off2, scores, sArr, eArr);
    sortA_kernel<<<8, 1024, 0, stream>>>(scores, runs);
    sortB_kernel<<<1, 1024, 0, stream>>>(runs, sArr, eArr, topI, ssS, eeS);
    nms_mask_kernel<<<64, blk, 0, stream>>>(ssS, eeS, mask);
    nms_select_kernel<<<1, 64, 0, stream>>>(mask, topI, ssS, eeS, cls2, off2, stA, enA, out);

    // ---- ROI pool ----
    roi_kernel<<<dim3(128, 8), blk, 0, stream>>>(fbuf, stA, enA, spp);

    // ---- classifier tower (fp32 path) ----
    gemm_kernel<0, 0><<<dim3(8, 14, 8), blk, 0, stream>>>(wc2, spp, bc2, part, 512, 2048, 896, 896, 8, 0);
    finalize_kernel<<<1792, blk, 0, stream>>>(part, yA, bc2, 512, 512, 896, 8, 0);

    gemm_kernel<1, 0><<<dim3(8, 14, 8), blk, 0, stream>>>(w3w, yA, b3, part, 512, 1536, 896, 896, 8, 0);
    finalize_kernel<<<1792, blk, 0, stream>>>(part, yB, b3, 512, 512, 896, 8, 0);
    gemm_kernel<1, 0><<<dim3(8, 14, 8), blk, 0, stream>>>(w4w, yB, b4, part, 512, 1536, 896, 896, 8, 0);
    finalize_kernel<<<1792, blk, 0, stream>>>(part, yA, b4, 512, 512, 896, 8, 1);  // relu
    gemm_kernel<1, 0><<<dim3(8, 14, 8), blk, 0, stream>>>(w5w, yA, b5, part, 512, 1536, 896, 896, 8, 0);
    finalize_kernel<<<1792, blk, 0, stream>>>(part, yB, b5, 512, 512, 896, 8, 0);
    gemm_kernel<1, 0><<<dim3(8, 14, 8), blk, 0, stream>>>(w6w, yB, b6, part, 512, 1536, 896, 896, 8, 0);
    finalize_kernel<<<1792, blk, 0, stream>>>(part, yA, b6, 512, 512, 896, 8, 1);  // relu

    gemm_kernel<2, 0><<<dim3(8, 2, 28), blk, 0, stream>>>(fc1w, yA, fc1b, part, 512, 3584, 128, 128, 28, 0);
    finalize_kernel<<<256, blk, 0, stream>>>(part, g1, fc1b, 512, 512, 128, 28, 1);

    gemm_kernel<0, 0><<<dim3(4, 2, 4), blk, 0, stream>>>(fc2w, g1, fc2b, part, 256, 512, 128, 128, 4, 0);
    finalize_kernel<<<128, blk, 0, stream>>>(part, g2, fc2b, 256, 256, 128, 4, 0);
    gemm_kernel<0, 0><<<dim3(2, 2, 2), blk, 0, stream>>>(fc3w, g2, fc3b, part, 128, 256, 128, 128, 2, 0);
    finalize_kernel<<<64, blk, 0, stream>>>(part, g3, fc3b, 128, 128, 128, 2, 0);

    gemm_kernel<0, 1><<<dim3(1, 2, 1), blk, 0, stream>>>(clsw, g3, clsb, out, 21, 128, 128, 128, 1, 0);
    gemm_kernel<0, 2><<<dim3(1, 2, 1), blk, 0, stream>>>(boxw, g3, boxb, out, 40, 128, 128, 128, 1, 0);
}

// Round 8
// 1029.421 us; speedup vs baseline: 2.2579x; 1.0343x over previous
//
#include <hip/hip_runtime.h>

typedef __attribute__((ext_vector_type(8))) short short8;
typedef __attribute__((ext_vector_type(4))) float float4v;

__device__ __forceinline__ float bf(unsigned short u) {
    return __uint_as_float(((unsigned int)u) << 16);
}
__device__ __forceinline__ unsigned short f2b(float f) {
    unsigned int u = __float_as_uint(f);
    unsigned int r = (u + 0x7FFFu + ((u >> 16) & 1u)) >> 16;
    return (unsigned short)r;
}

__constant__ float c_anchors[10] = {2.f,4.f,5.f,6.f,8.f,9.f,10.f,12.f,14.f,16.f};

// ============ Xt helpers: transposed bf16 hi/lo slab [770][CI], planes h/l ============
__global__ __launch_bounds__(256) void zeroXt_kernel(unsigned short* __restrict__ Xt, int CI) {
    int i = blockIdx.x * 256 + threadIdx.x;
    if (i < 2 * CI) {
        int row = (i >= CI) ? 769 : 0;
        int co = (i >= CI) ? (i - CI) : i;
        Xt[(size_t)row * CI + co] = 0;
        Xt[(size_t)770 * CI + (size_t)row * CI + co] = 0;
    }
}

// src fp32 [CI][768] -> Xt rows 1..768 (row l+1 = X[:,l]), hi/lo planes
__global__ __launch_bounds__(256) void decomp_kernel(const float* __restrict__ src,
                                                     unsigned short* __restrict__ Xt, int CI) {
    __shared__ float T[32][33];
    int l0 = blockIdx.x * 32, ci0 = blockIdx.y * 32;
    int tid = threadIdx.x;
#pragma unroll
    for (int i = 0; i < 4; i++) {
        int slot = tid + 256 * i;
        int r = slot >> 5, c = slot & 31;
        T[r][c] = src[(size_t)(ci0 + r) * 768 + l0 + c];
    }
    __syncthreads();
    unsigned short* Xh = Xt;
    unsigned short* Xl = Xt + (size_t)770 * CI;
#pragma unroll
    for (int i = 0; i < 4; i++) {
        int slot = tid + 256 * i;
        int li = slot >> 5, cc = slot & 31;
        float v = T[cc][li];
        unsigned short h = f2b(v);
        float lo = v - bf(h);
        size_t o = (size_t)(l0 + li + 1) * CI + ci0 + cc;
        Xh[o] = h;
        Xl[o] = f2b(lo);
    }
}

// ============ merged-tap MFMA conv-as-GEMM ============
// SEGM=0: slab row of col c = c+1 (plain, 770/898-row slabs)
// SEGM=1: slab row of col c = (c/7)*9 + c%7 + 1 (segmented per-proposal pads)
template <int TAPS, int SEGM>
__global__ __launch_bounds__(512, 6) void convmm_kernel(const float* __restrict__ W,
                                                        const unsigned short* __restrict__ Xt,
                                                        float* __restrict__ G,
                                                        int CO, int CI, int S, int NCOL, int planeElems) {
    constexpr int RS = TAPS * 32 + 8;
    constexpr int BROWS = SEGM ? 168 : 130;
    __shared__ unsigned short At[2][64 * RS];
    __shared__ unsigned short Bt[2][BROWS * 40];
    int tid = threadIdx.x;
    int lane = tid & 63, wid = tid >> 6;
    int q = lane >> 4, ln = lane & 15;
    int co0 = blockIdx.x * 64;
    int c0 = blockIdx.y * 128;
    int s = blockIdx.z;
    int kPer = CI / S, cis = s * kPer;
    const unsigned short* Xh = Xt;
    const unsigned short* Xl = Xt + planeElems;
    int row0 = SEGM ? ((c0 / 7) * 9 + c0 % 7) : c0;

    float4v zero4 = {0.f, 0.f, 0.f, 0.f};
    float4v acc[2][2];
    acc[0][0] = zero4; acc[0][1] = zero4; acc[1][0] = zero4; acc[1][1] = zero4;

    int wave_m = (wid >> 2) * 32;
    int wave_n = (wid & 3) * 32;

    int rowb[2];
#pragma unroll
    for (int nf = 0; nf < 2; nf++) {
        int col = c0 + wave_n + nf * 16 + ln;
        rowb[nf] = SEGM ? ((col / 7) * 9 + col % 7 - row0) : (wave_n + nf * 16 + ln);
    }

    for (int kb = 0; kb < kPer; kb += 32) {
        int cib = cis + kb;
        if (TAPS == 3) {
#pragma unroll
            for (int i = 0; i < 2; i++) {
                int slot = tid + 512 * i;
                int row = slot >> 4, cc0 = (slot & 15) * 2;
                const float* wp = W + ((size_t)(co0 + row) * CI + cib + cc0) * 3;
                float fa[6];
#pragma unroll
                for (int j = 0; j < 6; j++) fa[j] = wp[j];
#pragma unroll
                for (int t = 0; t < 3; t++) {
                    unsigned short h0 = f2b(fa[t]);
                    unsigned short h1 = f2b(fa[t + 3]);
                    unsigned short e0 = f2b(fa[t] - bf(h0));
                    unsigned short e1 = f2b(fa[t + 3] - bf(h1));
                    *(unsigned int*)&At[0][row * RS + t * 32 + cc0] =
                        (unsigned int)h0 | ((unsigned int)h1 << 16);
                    *(unsigned int*)&At[1][row * RS + t * 32 + cc0] =
                        (unsigned int)e0 | ((unsigned int)e1 << 16);
                }
            }
        } else {
            int row = tid >> 3, cc0 = (tid & 7) * 4;
            float4 wv = *(const float4*)(W + (size_t)(co0 + row) * CI + cib + cc0);
            float fa[4] = {wv.x, wv.y, wv.z, wv.w};
            unsigned short h[4], e[4];
#pragma unroll
            for (int j = 0; j < 4; j++) {
                h[j] = f2b(fa[j]);
                e[j] = f2b(fa[j] - bf(h[j]));
            }
            unsigned long long hp = (unsigned long long)h[0] | ((unsigned long long)h[1] << 16) |
                                    ((unsigned long long)h[2] << 32) | ((unsigned long long)h[3] << 48);
            unsigned long long ep = (unsigned long long)e[0] | ((unsigned long long)e[1] << 16) |
                                    ((unsigned long long)e[2] << 32) | ((unsigned long long)e[3] << 48);
            *(unsigned long long*)&At[0][row * RS + cc0] = hp;
            *(unsigned long long*)&At[1][row * RS + cc0] = ep;
        }
#pragma unroll
        for (int i = 0; i < 3; i++) {
            int slot = tid + 512 * i;
            if (slot < BROWS * 8) {
                int p = slot >= BROWS * 4 ? 1 : 0;
                int rem = slot - p * BROWS * 4;
                int r = rem >> 2, qq = rem & 3;
                const unsigned short* src = (p ? Xl : Xh) + (size_t)(row0 + r) * CI + cib + qq * 8;
                short8 v = *(const short8*)src;
                *(short8*)&Bt[p][r * 40 + qq * 8] = v;
            }
        }
        __syncthreads();
#pragma unroll
        for (int t = 0; t < TAPS; t++) {
            int shift = (TAPS == 1) ? 1 : t;
            short8 bh[2], bl[2];
#pragma unroll
            for (int nf = 0; nf < 2; nf++) {
                int rrow = rowb[nf] + shift;
                bh[nf] = *(const short8*)&Bt[0][rrow * 40 + q * 8];
                bl[nf] = *(const short8*)&Bt[1][rrow * 40 + q * 8];
            }
#pragma unroll
            for (int mf = 0; mf < 2; mf++) {
                int mrow = wave_m + mf * 16 + ln;
                short8 ah = *(const short8*)&At[0][mrow * RS + t * 32 + q * 8];
                short8 al = *(const short8*)&At[1][mrow * RS + t * 32 + q * 8];
#pragma unroll
                for (int nf = 0; nf < 2; nf++) {
                    acc[mf][nf] = __builtin_amdgcn_mfma_f32_16x16x32_bf16(ah, bh[nf], acc[mf][nf], 0, 0, 0);
                    acc[mf][nf] = __builtin_amdgcn_mfma_f32_16x16x32_bf16(ah, bl[nf], acc[mf][nf], 0, 0, 0);
                    acc[mf][nf] = __builtin_amdgcn_mfma_f32_16x16x32_bf16(al, bh[nf], acc[mf][nf], 0, 0, 0);
                }
            }
        }
        __syncthreads();
    }
    float* Gz = G + (size_t)s * CO * NCOL;
#pragma unroll
    for (int mf = 0; mf < 2; mf++)
#pragma unroll
        for (int nf = 0; nf < 2; nf++) {
            int col = c0 + wave_n + nf * 16 + ln;
            int rowb2 = co0 + wave_m + mf * 16 + q * 4;
#pragma unroll
            for (int r = 0; r < 4; r++)
                Gz[(size_t)(rowb2 + r) * NCOL + col] = acc[mf][nf][r];
        }
}

// finalize: sum P planes + bias -> transposed bf16 hi/lo Xt (770-row slab)
__global__ __launch_bounds__(256) void finsum_x_kernel(const float* __restrict__ G,
                                                       const float* __restrict__ bias,
                                                       unsigned short* __restrict__ Xt,
                                                       int CO, int P) {
    __shared__ float T[64][65];
    int co0 = blockIdx.x * 64, l0 = blockIdx.y * 64;
    int tid = threadIdx.x;
#pragma unroll 1
    for (int i = 0; i < 16; i++) {
        int slot = tid + 256 * i;
        int r = slot >> 6, c = slot & 63;
        float v = bias[co0 + r];
        for (int p = 0; p < P; p++) v += G[((size_t)p * CO + co0 + r) * 768 + l0 + c];
        T[r][c] = v;
    }
    __syncthreads();
    unsigned short* Xh = Xt;
    unsigned short* Xl = Xt + (size_t)770 * CO;
#pragma unroll 1
    for (int i = 0; i < 16; i++) {
        int slot = tid + 256 * i;
        int li = slot >> 6, ci = slot & 63;
        float v = T[ci][li];
        unsigned short h = f2b(v);
        float lo = v - bf(h);
        size_t o = (size_t)(l0 + li + 1) * CO + co0 + ci;
        Xh[o] = h;
        Xl[o] = f2b(lo);
    }
}

// finalize: sum P planes + bias -> 770-slab AND fp32 [CO][768]
__global__ __launch_bounds__(256) void finsum_xf_kernel(const float* __restrict__ G,
                                                        const float* __restrict__ bias,
                                                        unsigned short* __restrict__ Xt,
                                                        float* __restrict__ outF,
                                                        int CO, int P) {
    __shared__ float T[64][65];
    int co0 = blockIdx.x * 64, l0 = blockIdx.y * 64;
    int tid = threadIdx.x;
#pragma unroll 1
    for (int i = 0; i < 16; i++) {
        int slot = tid + 256 * i;
        int r = slot >> 6, c = slot & 63;
        float v = bias[co0 + r];
        for (int p = 0; p < P; p++) v += G[((size_t)p * CO + co0 + r) * 768 + l0 + c];
        T[r][c] = v;
        outF[(size_t)(co0 + r) * 768 + l0 + c] = v;
    }
    __syncthreads();
    unsigned short* Xh = Xt;
    unsigned short* Xl = Xt + (size_t)770 * CO;
#pragma unroll 1
    for (int i = 0; i < 16; i++) {
        int slot = tid + 256 * i;
        int li = slot >> 6, ci = slot & 63;
        float v = T[ci][li];
        unsigned short h = f2b(v);
        float lo = v - bf(h);
        size_t o = (size_t)(l0 + li + 1) * CO + co0 + ci;
        Xh[o] = h;
        Xl[o] = f2b(lo);
    }
}

// finalize: sum P planes + bias -> segmented slab [1160][512] hi/lo (+relu)
__global__ __launch_bounds__(256) void finsum_seg_kernel(const float* __restrict__ G,
                                                         const float* __restrict__ bias,
                                                         unsigned short* __restrict__ Xs,
                                                         int P, int relu) {
    __shared__ float T[64][65];
    int co0 = blockIdx.x * 64, c0 = blockIdx.y * 64;
    int tid = threadIdx.x;
#pragma unroll 1
    for (int i = 0; i < 16; i++) {
        int slot = tid + 256 * i;
        int r = slot >> 6, c = slot & 63;
        float v = bias[co0 + r];
        for (int p = 0; p < P; p++) v += G[((size_t)p * 512 + co0 + r) * 896 + c0 + c];
        if (relu) v = fmaxf(v, 0.f);
        T[r][c] = v;
    }
    __syncthreads();
    unsigned short* Xh = Xs;
    unsigned short* Xl = Xs + (size_t)1160 * 512;
#pragma unroll 1
    for (int i = 0; i < 16; i++) {
        int slot = tid + 256 * i;
        int li = slot >> 6, ci = slot & 63;
        float v = T[ci][li];
        int c = c0 + li;
        int row = (c / 7) * 9 + c % 7 + 1;
        unsigned short h = f2b(v);
        float lo = v - bf(h);
        size_t o = (size_t)row * 512 + co0 + ci;
        Xh[o] = h;
        Xl[o] = f2b(lo);
    }
}

// finalize: sum P planes + bias (+relu) -> fp32 [CO][ncol]
__global__ __launch_bounds__(256) void finsum_f_kernel(const float* __restrict__ G,
                                                       const float* __restrict__ bias,
                                                       float* __restrict__ out,
                                                       int CO, int P, int ncol, int relu) {
    int i = blockIdx.x * 256 + threadIdx.x;
    if (i >= CO * ncol) return;
    int r = i / ncol, c = i - r * ncol;
    float v = bias[r];
    for (int p = 0; p < P; p++) v += G[((size_t)p * CO + r) * ncol + c];
    if (relu) v = fmaxf(v, 0.f);
    out[i] = v;
}

// ---------------- finalize for fp32 split-K gemm path ----------------
__global__ __launch_bounds__(256) void finalize_kernel(const float* __restrict__ part,
                                                       float* __restrict__ out,
                                                       const float* __restrict__ bias,
                                                       int RPAD, int R, int NCOLS, int S, int relu) {
    int i = blockIdx.x * 256 + threadIdx.x;
    int total = R * NCOLS;
    if (i >= total) return;
    int r = i / NCOLS;
    int c = i - r * NCOLS;
    float v = 0.f;
    for (int s = 0; s < S; s++) v += part[((size_t)s * RPAD + r) * NCOLS + c];
    v += bias[r];
    if (relu) v = fmaxf(v, 0.f);
    out[i] = v;
}

// ---------------- fp32 gather-GEMM (heads, fc1-3, output heads) ----------------
template <int MODE, int EPI>
__global__ __launch_bounds__(256) void gemm_kernel(const float* __restrict__ W,
                                                   const float* __restrict__ B,
                                                   const float* __restrict__ bias,
                                                   float* __restrict__ outF,
                                                   int R, int K, int NCOLS, int LDB, int S, int relu) {
    __shared__ __align__(16) float Bt[16][68];
    __shared__ __align__(16) float Wt[16][68];
    int tid = threadIdx.x;
    int tx = tid & 15, ty = tid >> 4;
    int r0 = blockIdx.x * 64, c0 = blockIdx.y * 64, s = blockIdx.z;
    int kPer = K / S;
    int k0s = s * kPer;
    float acc[4][4] = {};
    for (int kb = 0; kb < kPer; kb += 16) {
        int k0 = k0s + kb;
        {
            int rr = r0 + (tid >> 2);
            int q = tid & 3;
            float4 wv4 = {0.f, 0.f, 0.f, 0.f};
            if (rr < R) wv4 = *(const float4*)(W + (size_t)rr * K + k0 + q * 4);
            Wt[q * 4 + 0][tid >> 2] = wv4.x;
            Wt[q * 4 + 1][tid >> 2] = wv4.y;
            Wt[q * 4 + 2][tid >> 2] = wv4.z;
            Wt[q * 4 + 3][tid >> 2] = wv4.w;
        }
#pragma unroll
        for (int p = 0; p < 4; p++) {
            int kk = p * 4 + (tid >> 6);
            int c = tid & 63;
            int k = k0 + kk;
            int col = c0 + c;
            float v;
            if (MODE == 0) {
                v = B[(size_t)k * LDB + col];
            } else {
                int co = k / 7;
                int b7 = k - co * 7;
                v = B[(size_t)co * 896 + col * 7 + b7];
            }
            Bt[kk][c] = v;
        }
        __syncthreads();
#pragma unroll
        for (int kk = 0; kk < 16; kk++) {
            float4 bv = *(const float4*)&Bt[kk][tx * 4];
            float4 wv = *(const float4*)&Wt[kk][ty * 4];
            float bb[4] = {bv.x, bv.y, bv.z, bv.w};
            float ww[4] = {wv.x, wv.y, wv.z, wv.w};
#pragma unroll
            for (int i = 0; i < 4; i++)
#pragma unroll
                for (int j = 0; j < 4; j++)
                    acc[i][j] = fmaf(ww[i], bb[j], acc[i][j]);
        }
        __syncthreads();
    }
    if (EPI == 0) {
        if (S > 1) {
#pragma unroll
            for (int i = 0; i < 4; i++) {
                int r = r0 + ty * 4 + i;
                float4 o = {acc[i][0], acc[i][1], acc[i][2], acc[i][3]};
                *(float4*)&outF[((size_t)s * R + r) * NCOLS + c0 + tx * 4] = o;
            }
        } else {
#pragma unroll
            for (int i = 0; i < 4; i++) {
                int r = r0 + ty * 4 + i;
                if (r < R) {
                    float bv = bias[r];
#pragma unroll
                    for (int j = 0; j < 4; j++) {
                        float v = acc[i][j] + bv;
                        if (relu) v = fmaxf(v, 0.f);
                        outF[(size_t)r * NCOLS + c0 + tx * 4 + j] = v;
                    }
                }
            }
        }
    } else {
#pragma unroll
        for (int i = 0; i < 4; i++) {
            int r = r0 + ty * 4 + i;
            if (r < R) {
                float bv = bias[r];
#pragma unroll
                for (int j = 0; j < 4; j++) {
                    int col = c0 + tx * 4 + j;
                    float v = acc[i][j] + bv;
                    if (EPI == 1) outF[512 + col * 21 + r] = v;
                    else outF[3200 + col * 40 + r] = v;
                }
            }
        }
    }
}

// ---------------- proposals: softmax, anchor decode ----------------
__global__ __launch_bounds__(256) void proposal_kernel(const float* __restrict__ clsS,
                                                       const float* __restrict__ segS,
                                                       float* __restrict__ cls2, float* __restrict__ off2,
                                                       float* __restrict__ scores,
                                                       float* __restrict__ sArr, float* __restrict__ eArr) {
    int i = blockIdx.x * 256 + threadIdx.x;
    if (i >= 7680) return;
    int l = i / 10;
    int a = i - l * 10;
    float c0 = clsS[(a * 2 + 0) * 768 + l];
    float c1 = clsS[(a * 2 + 1) * 768 + l];
    cls2[i * 2] = c0;
    cls2[i * 2 + 1] = c1;
    float m = fmaxf(c0, c1);
    float e0 = expf(c0 - m), e1 = expf(c1 - m);
    scores[i] = e1 / (e0 + e1);
    float o0 = segS[(a * 2 + 0) * 768 + l];
    float o1 = segS[(a * 2 + 1) * 768 + l];
    off2[i * 2] = o0;
    off2[i * 2 + 1] = o1;
    float ah = c_anchors[a] * 0.5f;
    float ac = (float)l + 0.5f;
    float c = ac + o0 * (2.f * ah);
    float hl = ah * expf(o1);
    sArr[i] = fminf(fmaxf(c - hl, 0.f), 768.f);
    eArr[i] = fminf(fmaxf(c + hl, 0.f), 768.f);
}

// ---------------- bitonic top-k phase A ----------------
__global__ __launch_bounds__(1024) void sortA_kernel(const float* __restrict__ scores,
                                                     unsigned long long* __restrict__ runs) {
    __shared__ unsigned long long kk[1024];
    int tid = threadIdx.x;
    int gbase = blockIdx.x * 1024;
    int gi = gbase + tid;
    unsigned long long key = 0ull;
    if (gi < 7680) {
        unsigned int sb = __float_as_uint(scores[gi]);
        key = ((unsigned long long)sb << 32) | (unsigned long long)(0xFFFFFFFFu - (unsigned)gi);
    }
    kk[tid] = key;
    __syncthreads();
    for (int k = 2; k <= 1024; k <<= 1) {
        for (int j = k >> 1; j > 0; j >>= 1) {
            int ixj = tid ^ j;
            if (ixj > tid) {
                unsigned long long a = kk[tid], b = kk[ixj];
                bool descend = ((tid & k) == 0);
                if (descend ? (a < b) : (a > b)) { kk[tid] = b; kk[ixj] = a; }
            }
            __syncthreads();
        }
    }
    runs[gbase + tid] = kk[tid];
}

// ---------------- phase B: tree-merge, exact top-1024 desc ----------------
__global__ __launch_bounds__(1024) void sortB_kernel(const unsigned long long* __restrict__ runs,
                                                     const float* __restrict__ sArr, const float* __restrict__ eArr,
                                                     int* __restrict__ topI,
                                                     float* __restrict__ ss, float* __restrict__ ee) {
    __shared__ unsigned long long S[8192];
    int tid = threadIdx.x;
#pragma unroll
    for (int m = 0; m < 8; m++) S[m * 1024 + tid] = runs[m * 1024 + tid];
    __syncthreads();
#pragma unroll 1
    for (int level = 0; level < 3; level++) {
        int span = 1024 << level;
        int nm = 4 >> level;
        for (int m = 0; m < nm; m++) {
            int baseA = m * (span * 2);
            int baseB = baseA + span;
            unsigned long long a = S[baseA + tid], b = S[baseB + 1023 - tid];
            S[baseA + tid] = (a > b) ? a : b;
        }
        __syncthreads();
        for (int j = 512; j > 0; j >>= 1) {
            for (int m = 0; m < nm; m++) {
                int baseA = m * (span * 2);
                int ixj = tid ^ j;
                if (ixj > tid) {
                    unsigned long long a = S[baseA + tid], b = S[baseA + ixj];
                    if (a < b) { S[baseA + tid] = b; S[baseA + ixj] = a; }
                }
            }
            __syncthreads();
        }
    }
    int idx = (int)(0xFFFFFFFFu - (unsigned int)(S[tid] & 0xFFFFFFFFull));
    topI[tid] = idx;
    ss[tid] = sArr[idx];
    ee[tid] = eArr[idx];
}

// ---------------- NMS suppression bitmask ----------------
__global__ __launch_bounds__(256) void nms_mask_kernel(const float* __restrict__ ss, const float* __restrict__ ee,
                                                       unsigned long long* __restrict__ mask) {
    int g = blockIdx.x * 256 + threadIdx.x;
    int i = g >> 4, w = g & 15;
    float si = ss[i], ei = ee[i];
    unsigned long long bits = 0ull;
#pragma unroll 1
    for (int jj = 0; jj < 64; jj++) {
        int j = w * 64 + jj;
        if (j > i) {
            float sj = ss[j], ej = ee[j];
            float inter = fmaxf(0.f, fminf(ei, ej) - fmaxf(si, sj));
            float uni = (ej - sj) + (ei - si) - inter;
            float iou = inter / fmaxf(uni, 1e-8f);
            if (iou > 0.7f) bits |= (1ull << jj);
        }
    }
    mask[(size_t)i * 16 + w] = bits;
}

// ---------------- NMS scan (readlane scalar-pipe) + partition + gather ----------------
__device__ __forceinline__ unsigned long long readlane64(unsigned long long v, int i) {
    unsigned int lo = (unsigned int)__builtin_amdgcn_readlane((int)(unsigned int)(v & 0xFFFFFFFFull), i);
    unsigned int hi = (unsigned int)__builtin_amdgcn_readlane((int)(unsigned int)(v >> 32), i);
    return ((unsigned long long)hi << 32) | (unsigned long long)lo;
}

__global__ __launch_bounds__(64) void nms_select_kernel(const unsigned long long* __restrict__ mask,
                                                        const int* __restrict__ topI,
                                                        const float* __restrict__ ss, const float* __restrict__ ee,
                                                        const float* __restrict__ cls2, const float* __restrict__ off2,
                                                        int* __restrict__ stA, int* __restrict__ enA,
                                                        float* __restrict__ out) {
    int lane = threadIdx.x;
    unsigned long long keepW[16];
#pragma unroll 1
    for (int b = 0; b < 16; b++) {
        unsigned long long accv = 0ull;
#pragma unroll 1
        for (int a = 0; a < b; a++) {
            unsigned long long m = mask[(size_t)(a * 64 + lane) * 16 + b];
            unsigned long long kb = (keepW[a] >> lane) & 1ull;
            accv |= m & (0ull - kb);
        }
#pragma unroll
        for (int sft = 1; sft < 64; sft <<= 1) accv |= __shfl_xor(accv, sft);
        unsigned long long diag = mask[(size_t)(b * 64 + lane) * 16 + b];
        unsigned long long rem = accv;
#pragma unroll
        for (int i = 0; i < 64; i++) {
            unsigned long long di = readlane64(diag, i);
            if (!((rem >> i) & 1ull)) rem |= di;
        }
        keepW[b] = ~rem;
    }
    int total = 0;
    int prefix[16];
#pragma unroll
    for (int b = 0; b < 16; b++) { prefix[b] = total; total += __popcll(keepW[b]); }
#pragma unroll 1
    for (int b = 0; b < 16; b++) {
        int tid = b * 64 + lane;
        unsigned long long keep64 = keepW[b];
        unsigned long long below = (lane == 0) ? 0ull : (keep64 << (64 - lane));
        int keptBefore = prefix[b] + __popcll(below);
        int kp = (int)((keep64 >> lane) & 1ull);
        int pos = kp ? keptBefore : (total + tid - keptBefore);
        if (pos < 128) {
            int orig = topI[tid];
            float ps = ss[tid], pe = ee[tid];
            out[pos * 2 + 0] = cls2[orig * 2 + 0];
            out[pos * 2 + 1] = cls2[orig * 2 + 1];
            out[256 + pos * 2 + 0] = off2[orig * 2 + 0];
            out[256 + pos * 2 + 1] = off2[orig * 2 + 1];
            float bc = (ps + pe) * 0.5f, bh = (pe - ps) * 0.5f;
            int st = (int)fminf(fmaxf(floorf(bc - bh), 0.f), 767.f);
            int en = (int)fminf(fmaxf(ceilf(bc + bh), 0.f), 767.f);
            if (en < st) en = st;
            stA[pos] = st;
            enA[pos] = en;
        }
    }
}

// ---------------- ROI max pool -> 898-row hi/lo slab [row c+1][2048] ----------------
__global__ __launch_bounds__(256) void roi_slab_kernel(const float* __restrict__ f,
                                                       const int* __restrict__ stA, const int* __restrict__ enA,
                                                       unsigned short* __restrict__ Xs) {
    int col = blockIdx.x;  // 0..895
    int n = col / 7, b = col - n * 7;
    int st = stA[n], en = enA[n];
    int ln = en - st + 1;
    int bs = st + (b * ln) / 7;
    int be = st + ((b + 1) * ln + 6) / 7 - 1;
    unsigned short* Xh = Xs;
    unsigned short* Xl = Xs + (size_t)898 * 2048;
    int tid = threadIdx.x;
#pragma unroll 1
    for (int j = 0; j < 8; j++) {
        int ci = tid + 256 * j;
        const float* row = f + (size_t)ci * 768;
        float m = row[bs];
        for (int t = bs + 1; t <= be; t++) m = fmaxf(m, row[t]);
        unsigned short h = f2b(m);
        float lo = m - bf(h);
        size_t o = (size_t)(col + 1) * 2048 + ci;
        Xh[o] = h;
        Xl[o] = f2b(lo);
    }
}

__global__ __launch_bounds__(256) void zrow_wc2_kernel(unsigned short* __restrict__ Xs) {
    int i = blockIdx.x * 256 + threadIdx.x;
    if (i < 2048) {
        Xs[i] = 0;
        Xs[(size_t)897 * 2048 + i] = 0;
        Xs[(size_t)898 * 2048 + i] = 0;
        Xs[(size_t)898 * 2048 + (size_t)897 * 2048 + i] = 0;
    }
}

// zero both segmented slabs fully (pads stay zero; data rows rewritten each layer)
__global__ __launch_bounds__(256) void zseg_kernel(uint4* __restrict__ p, int n16) {
    int i = blockIdx.x * 256 + threadIdx.x;
    uint4 z = {0, 0, 0, 0};
    if (i < n16) p[i] = z;
}

extern "C" void kernel_launch(void* const* d_in, const int* in_sizes, int n_in,
                              void* d_out, int out_size, void* d_ws, size_t ws_size,
                              hipStream_t stream) {
    const float* IN[39];
    for (int i = 0; i < 39; i++) IN[i] = (const float*)d_in[i];
    const float* feature = IN[0];
    const float *b1f = IN[1], *b2f = IN[2], *b3 = IN[3], *b4 = IN[4], *b5 = IN[5], *b6 = IN[6];
    const float *bc1 = IN[7], *bc2 = IN[8], *boxb = IN[9], *boxw = IN[10];
    const float *clsb = IN[11], *clsw = IN[12];
    const float *fc1b = IN[13], *fc1w = IN[14], *fc2b = IN[15], *fc2w = IN[16];
    const float *fc3b = IN[17], *fc3w = IN[18];
    const float *sp1b = IN[19], *sp1w = IN[20], *sp2b = IN[21], *sp2w = IN[22];
    const float *sp3b = IN[23], *sp3w = IN[24], *sp4b = IN[25], *sp4w = IN[26];
    const float *spcb = IN[27], *spcw = IN[28], *spsb = IN[29], *spsw = IN[30];
    const float *w1f = IN[31], *w2f = IN[32], *w3w = IN[33], *w4w = IN[34];
    const float *w5w = IN[35], *w6w = IN[36], *wc1 = IN[37], *wc2 = IN[38];
    float* out = (float*)d_out;

    char* base = (char*)d_ws;
    float* G    = (float*)base;   // conv phase: ≤25.2 MB; tower phase: 8*512*896*4 = 14,680,064 B
    float* part = (float*)base;   // fc1 split-K partials (post-tower)
    unsigned short* segSA = (unsigned short*)(base + 14680064);  // 2*1160*512*2 = 2,375,680 B
    unsigned short* segSB = (unsigned short*)(base + 17055744);
    float* yA   = (float*)(base + 22020096);  // [512][896] fp32 (fc1 input)
    float* g1   = (float*)(base + 25690112);
    float* g2   = (float*)(base + 25952256);
    float* g3   = (float*)(base + 26083328);
    size_t off = 26148864;
    auto alloc = [&](size_t bytes) { void* p = base + off; off += (bytes + 15) & ~((size_t)15); return p; };
    unsigned short* Xt = (unsigned short*)alloc((size_t)770 * 2048 * 2 * 2);  // also wc2 slab (898*2048*2*2 = 7.36 MB)
    float* fbuf = (float*)alloc((size_t)2048 * 768 * 4);
    float* hB   = (float*)alloc((size_t)512 * 768 * 4);
    float* clsS = (float*)alloc((size_t)20 * 768 * 4);
    float* segS = (float*)alloc((size_t)20 * 768 * 4);
    float* cls2 = (float*)alloc(7680 * 2 * 4);
    float* off2 = (float*)alloc(7680 * 2 * 4);
    float* scores = (float*)alloc(7680 * 4);
    float* sArr = (float*)alloc(7680 * 4);
    float* eArr = (float*)alloc(7680 * 4);
    float* ssS  = (float*)alloc(1024 * 4);
    float* eeS  = (float*)alloc(1024 * 4);
    unsigned long long* runs = (unsigned long long*)alloc((size_t)8192 * 8);
    unsigned long long* mask = (unsigned long long*)alloc((size_t)16384 * 8);
    int* topI = (int*)alloc(1024 * 4);
    int* stA = (int*)alloc(128 * 4);
    int* enA = (int*)alloc(128 * 4);

    dim3 blk(256);
    dim3 blk512(512);

    // ---- conv1: feature -> slab -> G -> slab ----
    zeroXt_kernel<<<16, blk, 0, stream>>>(Xt, 2048);
    decomp_kernel<<<dim3(24, 64), blk, 0, stream>>>(feature, Xt, 2048);
    convmm_kernel<3, 0><<<dim3(32, 6, 4), blk512, 0, stream>>>(w1f, Xt, G, 2048, 2048, 4, 768, 770 * 2048);
    finsum_x_kernel<<<dim3(32, 12), blk, 0, stream>>>(G, b1f, Xt, 2048, 4);
    // ---- conv2: slab -> G -> fbuf + slab ----
    convmm_kernel<3, 0><<<dim3(32, 6, 4), blk512, 0, stream>>>(w2f, Xt, G, 2048, 2048, 4, 768, 770 * 2048);
    finsum_xf_kernel<<<dim3(32, 12), blk, 0, stream>>>(G, b2f, Xt, fbuf, 2048, 4);

    // ---- wc1 via MFMA (TAPS=1 on conv2 slab) -> 512-slab ----
    convmm_kernel<1, 0><<<dim3(8, 6, 8), blk512, 0, stream>>>(wc1, Xt, G, 512, 2048, 8, 768, 770 * 2048);
    zeroXt_kernel<<<4, blk, 0, stream>>>(Xt, 512);
    finsum_x_kernel<<<dim3(8, 12), blk, 0, stream>>>(G, bc1, Xt, 512, 8);

    // ---- sp1..sp4 via MFMA ----
    convmm_kernel<3, 0><<<dim3(8, 6, 8), blk512, 0, stream>>>(sp1w, Xt, G, 512, 512, 8, 768, 770 * 512);
    finsum_x_kernel<<<dim3(8, 12), blk, 0, stream>>>(G, sp1b, Xt, 512, 8);
    convmm_kernel<3, 0><<<dim3(8, 6, 8), blk512, 0, stream>>>(sp2w, Xt, G, 512, 512, 8, 768, 770 * 512);
    finsum_x_kernel<<<dim3(8, 12), blk, 0, stream>>>(G, sp2b, Xt, 512, 8);
    convmm_kernel<3, 0><<<dim3(8, 6, 8), blk512, 0, stream>>>(sp3w, Xt, G, 512, 512, 8, 768, 770 * 512);
    finsum_x_kernel<<<dim3(8, 12), blk, 0, stream>>>(G, sp3b, Xt, 512, 8);
    convmm_kernel<3, 0><<<dim3(8, 6, 8), blk512, 0, stream>>>(sp4w, Xt, G, 512, 512, 8, 768, 770 * 512);
    finsum_f_kernel<<<1536, blk, 0, stream>>>(G, sp4b, hB, 512, 8, 768, 1);  // relu

    // ---- heads ----
    gemm_kernel<0, 0><<<dim3(1, 12, 1), blk, 0, stream>>>(spcw, hB, spcb, clsS, 20, 512, 768, 768, 1, 0);
    gemm_kernel<0, 0><<<dim3(1, 12, 1), blk, 0, stream>>>(spsw, hB, spsb, segS, 20, 512, 768, 768, 1, 0);

    // ---- proposal decode / top-k / NMS ----
    proposal_kernel<<<30, blk, 0, stream>>>(clsS, segS, cls2, off2, scores, sArr, eArr);
    sortA_kernel<<<8, 1024, 0, stream>>>(scores, runs);
    sortB_kernel<<<1, 1024, 0, stream>>>(runs, sArr, eArr, topI, ssS, eeS);
    nms_mask_kernel<<<64, blk, 0, stream>>>(ssS, eeS, mask);
    nms_select_kernel<<<1, 64, 0, stream>>>(mask, topI, ssS, eeS, cls2, off2, stA, enA, out);

    // ---- ROI pool -> wc2 slab (Xt reused, 898 rows x 2048) ----
    zrow_wc2_kernel<<<8, blk, 0, stream>>>(Xt);
    roi_slab_kernel<<<896, blk, 0, stream>>>(fbuf, stA, enA, Xt);
    // zero segmented slabs (pads)
    zseg_kernel<<<1160, blk, 0, stream>>>((uint4*)segSA, 296960);

    // ---- classifier tower via MFMA ----
    // wc2 (1x1, K=2048) on 898-row slab -> segSA
    convmm_kernel<1, 0><<<dim3(8, 7, 8), blk512, 0, stream>>>(wc2, Xt, G, 512, 2048, 8, 896, 898 * 2048);
    finsum_seg_kernel<<<dim3(8, 14), blk, 0, stream>>>(G, bc2, segSA, 8, 0);
    // w3..w6 segmented convs
    convmm_kernel<3, 1><<<dim3(8, 7, 8), blk512, 0, stream>>>(w3w, segSA, G, 512, 512, 8, 896, 1160 * 512);
    finsum_seg_kernel<<<dim3(8, 14), blk, 0, stream>>>(G, b3, segSB, 8, 0);
    convmm_kernel<3, 1><<<dim3(8, 7, 8), blk512, 0, stream>>>(w4w, segSB, G, 512, 512, 8, 896, 1160 * 512);
    finsum_seg_kernel<<<dim3(8, 14), blk, 0, stream>>>(G, b4, segSA, 8, 1);  // relu
    convmm_kernel<3, 1><<<dim3(8, 7, 8), blk512, 0, stream>>>(w5w, segSA, G, 512, 512, 8, 896, 1160 * 512);
    finsum_seg_kernel<<<dim3(8, 14), blk, 0, stream>>>(G, b5, segSB, 8, 0);
    convmm_kernel<3, 1><<<dim3(8, 7, 8), blk512, 0, stream>>>(w6w, segSB, G, 512, 512, 8, 896, 1160 * 512);
    finsum_f_kernel<<<1792, blk, 0, stream>>>(G, b6, yA, 512, 8, 896, 1);  // relu -> fp32 [512][896]

    // ---- fc1 (relu), fc2, fc3, output heads (fp32) ----
    gemm_kernel<1, 0><<<dim3(8, 2, 28), blk, 0, stream>>>(fc1w, yA, fc1b, part, 512, 3584, 128, 128, 28, 0);
    finalize_kernel<<<256, blk, 0, stream>>>(part, g1, fc1b, 512, 512, 128, 28, 1);

    gemm_kernel<0, 0><<<dim3(4, 2, 4), blk, 0, stream>>>(fc2w, g1, fc2b, part, 256, 512, 128, 128, 4, 0);
    finalize_kernel<<<128, blk, 0, stream>>>(part, g2, fc2b, 256, 256, 128, 4, 0);
    gemm_kernel<0, 0><<<dim3(2, 2, 2), blk, 0, stream>>>(fc3w, g2, fc3b, part, 128, 256, 128, 128, 2, 0);
    finalize_kernel<<<64, blk, 0, stream>>>(part, g3, fc3b, 128, 128, 128, 2, 0);

    gemm_kernel<0, 1><<<dim3(1, 2, 1), blk, 0, stream>>>(clsw, g3, clsb, out, 21, 128, 128, 128, 1, 0);
    gemm_kernel<0, 2><<<dim3(1, 2, 1), blk, 0, stream>>>(boxw, g3, boxb, out, 40, 128, 128, 128, 1, 0);
}